// Round 11
// baseline (1013.817 us; speedup 1.0000x reference)
//
#include <hip/hip_runtime.h>
#include <math.h>

typedef __attribute__((ext_vector_type(8))) short short8;
typedef __attribute__((ext_vector_type(4))) float floatx4;

static __device__ __forceinline__ short f2bf(float f) {
    union { float f; unsigned u; } c; c.f = f;
    unsigned r = c.u + 0x7FFF + ((c.u >> 16) & 1);   // RNE
    return (short)(r >> 16);
}

// ---------------------------------------------------------------------------
// fp32 GEMM: C[b] = alpha * A[b](M,K) x B[b](N,K)^T. 64x64 tile, 4x4 micro.
// fp32-exact path (logits feed exact top-k; read-phase attention logits).
// ---------------------------------------------------------------------------
__launch_bounds__(256)
__global__ void gemm_f32_nt_kernel(const float* __restrict__ A, const float* __restrict__ B,
                                   float* __restrict__ C, int M, int N, int K,
                                   long sA, long sB, long sC, float alpha)
{
    __shared__ float As[32][68];   // [k][m]
    __shared__ float Bs[32][68];   // [k][n]
    const float* Ab = A + (long)blockIdx.z * sA;
    const float* Bb = B + (long)blockIdx.z * sB;
    float* Cb = C + (long)blockIdx.z * sC;
    int m0 = blockIdx.x * 64, n0 = blockIdx.y * 64;
    int t = threadIdx.x;
    int tx = t & 15, ty = t >> 4;
    float acc[4][4] = {};

    for (int k0 = 0; k0 < K; k0 += 32) {
        {
            int m = t >> 3;
            int kk = (t & 7) * 4;
#pragma unroll
            for (int h = 0; h < 2; ++h) {
                float4 v = *(const float4*)&Ab[(long)(m0 + m + 32 * h) * K + k0 + kk];
                As[kk + 0][m + 32 * h] = v.x; As[kk + 1][m + 32 * h] = v.y;
                As[kk + 2][m + 32 * h] = v.z; As[kk + 3][m + 32 * h] = v.w;
            }
        }
        {
            int n = t >> 3;
            int kk = (t & 7) * 4;
#pragma unroll
            for (int h = 0; h < 2; ++h) {
                float4 v = *(const float4*)&Bb[(long)(n0 + n + 32 * h) * K + k0 + kk];
                Bs[kk + 0][n + 32 * h] = v.x; Bs[kk + 1][n + 32 * h] = v.y;
                Bs[kk + 2][n + 32 * h] = v.z; Bs[kk + 3][n + 32 * h] = v.w;
            }
        }
        __syncthreads();
#pragma unroll 4
        for (int k = 0; k < 32; ++k) {
            float4 a = *(const float4*)&As[k][ty * 4];
            float4 b = *(const float4*)&Bs[k][tx * 4];
            float av[4] = { a.x, a.y, a.z, a.w };
            float bv[4] = { b.x, b.y, b.z, b.w };
#pragma unroll
            for (int i = 0; i < 4; ++i)
#pragma unroll
                for (int j = 0; j < 4; ++j) acc[i][j] += av[i] * bv[j];
        }
        __syncthreads();
    }
#pragma unroll
    for (int i = 0; i < 4; ++i) {
        float4 r;
        r.x = alpha * acc[i][0]; r.y = alpha * acc[i][1];
        r.z = alpha * acc[i][2]; r.w = alpha * acc[i][3];
        *(float4*)&Cb[(long)(m0 + ty * 4 + i) * N + n0 + tx * 4] = r;
    }
}

// ---------------------------------------------------------------------------
// Multi-segment split-K projection. Each segment s projects A_s(M_s,512) x
// W_s(512,64) into rows [rowOff_s, rowOff_s+M_s) of a combined output.
// grid: (total row-tiles, 8 K-slices, Bn). Partials reduced by proj_reduce.
// ---------------------------------------------------------------------------
struct ProjDesc {
    const float* A[6];
    const float* W[6];
    long  sA[6];
    int   tileOff[7];   // tile prefix; entries beyond nseg = total
    int   rowOff[6];
    int   Mtot;
};

__launch_bounds__(256)
__global__ void proj_splitk_kernel(ProjDesc d, float* __restrict__ part, int Bn)
{
    __shared__ float As[32][68];
    __shared__ float Bs[32][68];
    int xt = blockIdx.x, s = blockIdx.y, b = blockIdx.z;
    int seg = 0;
    while (xt >= d.tileOff[seg + 1]) ++seg;
    int row0 = (xt - d.tileOff[seg]) * 64;
    const float* A = d.A[seg] + (long)b * d.sA[seg];
    const float* W = d.W[seg];
    int orow = d.rowOff[seg] + row0;
    int t = threadIdx.x, tx = t & 15, ty = t >> 4;
    float acc[4][4] = {};
    int kbase = s * 64;

    for (int k0 = kbase; k0 < kbase + 64; k0 += 32) {
        {
            int m = t >> 3;
            int kk = (t & 7) * 4;
#pragma unroll
            for (int h = 0; h < 2; ++h) {
                float4 v = *(const float4*)&A[(long)(row0 + m + 32 * h) * 512 + k0 + kk];
                As[kk + 0][m + 32 * h] = v.x; As[kk + 1][m + 32 * h] = v.y;
                As[kk + 2][m + 32 * h] = v.z; As[kk + 3][m + 32 * h] = v.w;
            }
        }
        {
            int kk = t >> 3;
            int nn = (t & 7) * 8;
            float4 v0 = *(const float4*)&W[(long)(k0 + kk) * 64 + nn];
            float4 v1 = *(const float4*)&W[(long)(k0 + kk) * 64 + nn + 4];
            *(float4*)&Bs[kk][nn] = v0;
            *(float4*)&Bs[kk][nn + 4] = v1;
        }
        __syncthreads();
#pragma unroll 4
        for (int k = 0; k < 32; ++k) {
            float4 a = *(const float4*)&As[k][ty * 4];
            float4 b2 = *(const float4*)&Bs[k][tx * 4];
            float av[4] = { a.x, a.y, a.z, a.w };
            float bv[4] = { b2.x, b2.y, b2.z, b2.w };
#pragma unroll
            for (int i = 0; i < 4; ++i)
#pragma unroll
                for (int j = 0; j < 4; ++j) acc[i][j] += av[i] * bv[j];
        }
        __syncthreads();
    }
    long base = ((long)(s * Bn + b) * d.Mtot + orow) * 64;
#pragma unroll
    for (int i = 0; i < 4; ++i)
        *(float4*)&part[base + (long)(ty * 4 + i) * 64 + tx * 4] =
            make_float4(acc[i][0], acc[i][1], acc[i][2], acc[i][3]);
}

// Generic reduce of 8 split-K slices -> out[(b*Mtot+r)*64+c], contiguous.
__launch_bounds__(256)
__global__ void proj_reduce_kernel(const float* __restrict__ part, float* __restrict__ outp,
                                   int total4)
{
    int idx = blockIdx.x * 256 + threadIdx.x;
    if (idx >= total4) return;
    const float4* p4 = (const float4*)part;
    float4 s = p4[idx];
#pragma unroll
    for (int ss = 1; ss < 8; ++ss) {
        float4 v = p4[(long)ss * total4 + idx];
        s.x += v.x; s.y += v.y; s.z += v.z; s.w += v.w;
    }
    ((float4*)outp)[idx] = s;
}

// ---------------------------------------------------------------------------
// bf16 MFMA GEMM: C[b](M,N) = alpha' * A[b](M,K,fp32) x Bt[b](N,K,bf16) (+ C | + initC)
// ---------------------------------------------------------------------------
__launch_bounds__(256)
__global__ void gemm_mfma_kernel(const float* __restrict__ A, const unsigned short* __restrict__ Bt,
                                 float* __restrict__ C, int M, int N, int K,
                                 long sA, long sBt, long sC,
                                 float alpha, const float* __restrict__ gate, int gateIdx,
                                 float beta, const float* __restrict__ initC)
{
    __shared__ short As[2048];
    __shared__ short Bs[2048];
    const float* Ab = A + (long)blockIdx.z * sA;
    const unsigned short* Bb = Bt + (long)blockIdx.z * sBt;
    float* Cb = C + (long)blockIdx.z * sC;
    const float* Ib = initC ? initC + (long)blockIdx.z * sC : nullptr;
    int m0 = blockIdx.x * 64, n0 = blockIdx.y * 64;
    int t = threadIdx.x, wave = t >> 6, lane = t & 63;
    int sr = wave * 16 + (lane & 15);
    int sk = (lane >> 4) * 8;
    floatx4 acc[4] = {};

    for (int k0 = 0; k0 < K; k0 += 32) {
        const float* ap = &Ab[(long)(m0 + sr) * K + k0 + sk];
        float4 f0 = *(const float4*)ap;
        float4 f1 = *(const float4*)(ap + 4);
        short8 av;
        av[0] = f2bf(f0.x); av[1] = f2bf(f0.y); av[2] = f2bf(f0.z); av[3] = f2bf(f0.w);
        av[4] = f2bf(f1.x); av[5] = f2bf(f1.y); av[6] = f2bf(f1.z); av[7] = f2bf(f1.w);
        short8 bv = *(const short8*)&Bb[(long)(n0 + sr) * K + k0 + sk];
        ((short8*)As)[t] = av;
        ((short8*)Bs)[t] = bv;
        __syncthreads();
        short8 bf = ((short8*)Bs)[wave * 64 + lane];
#pragma unroll
        for (int mt = 0; mt < 4; ++mt) {
            short8 af = ((short8*)As)[mt * 64 + lane];
            acc[mt] = __builtin_amdgcn_mfma_f32_16x16x32_bf16(af, bf, acc[mt], 0, 0, 0);
        }
        __syncthreads();
    }
    float a = alpha;
    if (gate) a *= 1.f / (1.f + expf(-gate[gateIdx]));
    int col = n0 + wave * 16 + (lane & 15);
#pragma unroll
    for (int mt = 0; mt < 4; ++mt) {
#pragma unroll
        for (int r = 0; r < 4; ++r) {
            int row = m0 + mt * 16 + (lane >> 4) * 4 + r;
            long off = (long)row * N + col;
            float v = a * acc[mt][r];
            if (Ib) v += Ib[off];
            else if (beta != 0.f) v += Cb[off];
            Cb[off] = v;
        }
    }
}

// ---------------------------------------------------------------------------
// Transpose + bf16 convert: out[c][r] = bf16(in[r][c]). (read_proj, 3 levels)
// ---------------------------------------------------------------------------
__global__ void transpose_bf16_kernel(const float* __restrict__ in, unsigned short* __restrict__ out,
                                      int Rr, int Cc, long sIn, long sOut)
{
    __shared__ float tile[32][33];
    const float* I = in + (long)blockIdx.z * sIn;
    unsigned short* O = out + (long)blockIdx.z * sOut;
    int c0 = blockIdx.x * 32, r0 = blockIdx.y * 32;
    int tx = threadIdx.x, ty = threadIdx.y;
#pragma unroll
    for (int i = 0; i < 32; i += 8)
        tile[ty + i][tx] = I[(long)(r0 + ty + i) * Cc + c0 + tx];
    __syncthreads();
#pragma unroll
    for (int i = 0; i < 32; i += 8)
        O[(long)(c0 + ty + i) * Rr + r0 + tx] = (unsigned short)f2bf(tile[tx][ty + i]);
}

// Batched transpose of the 3 mv levels in one launch. y-tiles: 32|8|2.
__global__ void transpose_mv_kernel(const float* __restrict__ mv0, const float* __restrict__ mv1,
                                    const float* __restrict__ mv2,
                                    unsigned short* __restrict__ o0, unsigned short* __restrict__ o1,
                                    unsigned short* __restrict__ o2)
{
    __shared__ float tile[32][33];
    int yt = blockIdx.y;
    const float* in; unsigned short* out; int Nd, r0t;
    if (yt < 32)      { in = mv0; out = o0; Nd = 1024; r0t = yt; }
    else if (yt < 40) { in = mv1; out = o1; Nd = 256;  r0t = yt - 32; }
    else              { in = mv2; out = o2; Nd = 64;   r0t = yt - 40; }
    const float* I = in + (long)blockIdx.z * Nd * 512;
    unsigned short* O = out + (long)blockIdx.z * 512 * Nd;
    int c0 = blockIdx.x * 32, r0 = r0t * 32;
    int tx = threadIdx.x, ty = threadIdx.y;
#pragma unroll
    for (int i = 0; i < 32; i += 8)
        tile[ty + i][tx] = I[(long)(r0 + ty + i) * 512 + c0 + tx];
    __syncthreads();
#pragma unroll
    for (int i = 0; i < 32; i += 8)
        O[(long)(c0 + ty + i) * Nd + r0 + tx] = (unsigned short)f2bf(tile[tx][ty + i]);
}

// ---------------------------------------------------------------------------
// Exact top-16 per row + fused CSR count. 4 rows/block (one wave per row),
// lane owns contiguous slice of the logits row (float4 loads from lb).
// ---------------------------------------------------------------------------
template<int CNT>
__launch_bounds__(256)
__global__ void topk_coeff_kernel(const float* __restrict__ logits,
                                  const float* __restrict__ state,
                                  int* __restrict__ idx_out, float* __restrict__ c_out,
                                  int* __restrict__ cnt, int nsLog, int Nd)
{
    int wave = threadIdx.x >> 6, lane = threadIdx.x & 63;
    long row = (long)blockIdx.x * 4 + wave;
    const float* L = logits + row * Nd;
    float vreg[CNT];
    if (CNT >= 4) {
#pragma unroll
        for (int q = 0; q < CNT / 4; ++q) {
            float4 v = *(const float4*)&L[lane * CNT + q * 4];
            vreg[q * 4 + 0] = v.x; vreg[q * 4 + 1] = v.y;
            vreg[q * 4 + 2] = v.z; vreg[q * 4 + 3] = v.w;
        }
    } else {
#pragma unroll
        for (int tt = 0; tt < CNT; ++tt) vreg[tt] = L[lane * CNT + tt];
    }

    float m = 0.f, sum = 0.f;
    float myv = 0.f; int myi = 0;
#pragma unroll
    for (int it = 0; it < 16; ++it) {
        float best = -INFINITY; int bidx = 0x7fffffff;
#pragma unroll
        for (int tt = 0; tt < CNT; ++tt) {
            if (vreg[tt] > best) { best = vreg[tt]; bidx = lane * CNT + tt; }
        }
#pragma unroll
        for (int off = 32; off; off >>= 1) {
            float ov = __shfl_down(best, off);
            int   oi = __shfl_down(bidx, off);
            if (ov > best || (ov == best && oi < bidx)) { best = ov; bidx = oi; }
        }
        best = __shfl(best, 0);
        bidx = __shfl(bidx, 0);
        if (it == lane) { myv = best; myi = bidx; }
        float ab = fabsf(best);
        float nm = fmaxf(m, ab);
        sum = sum * expf(m - nm) + expf(ab - nm);
        m = nm;
#pragma unroll
        for (int tt = 0; tt < CNT; ++tt)
            if (lane * CNT + tt == bidx) vreg[tt] = -INFINITY;
    }
    if (lane < 16) {
        float st = state[row];
        float sp = fmaxf(st, 0.f) + log1pf(expf(-fabsf(st)));
        float sgn = (myv > 0.f) ? 1.f : ((myv < 0.f) ? -1.f : 0.f);
        float w = expf(fabsf(myv) - m) / sum;
        c_out[row * 16 + lane] = sgn * w * sp;
        idx_out[row * 16 + lane] = myi;
        int b = (int)(row >> nsLog);
        atomicAdd(&cnt[b * Nd + myi], 1);
    }
}

// Single-block exclusive scan; self-zeroes cnt (next Nd <= current Nd).
__launch_bounds__(256)
__global__ void scan_kernel(int* __restrict__ cnt, int* __restrict__ offs, int N)
{
    __shared__ int sums[256];
    int t = threadIdx.x;
    int chunk = N >> 8;
    int base = t * chunk;
    int lc[16];
    int s = 0;
    for (int i = 0; i < chunk; ++i) { lc[i] = cnt[base + i]; s += lc[i]; }
    sums[t] = s;
    __syncthreads();
    for (int off = 1; off < 256; off <<= 1) {
        int v = (t >= off) ? sums[t - off] : 0;
        __syncthreads();
        sums[t] += v;
        __syncthreads();
    }
    int run = sums[t] - s;
    for (int i = 0; i < chunk; ++i) {
        offs[base + i] = run;
        run += lc[i];
        cnt[base + i] = 0;
    }
    if (t == 255) offs[N] = run;
}

__launch_bounds__(256)
__global__ void fill_edges_kernel(const int* __restrict__ idx, const int* __restrict__ offs,
                                  int* __restrict__ cursor, int* __restrict__ elist,
                                  int nsShift, int Nd, int E)
{
    int e = blockIdx.x * 256 + threadIdx.x;
    if (e >= E) return;
    int b = e >> nsShift;
    int d = b * Nd + idx[e];
    int pos = offs[d] + atomicAdd(&cursor[d], 1);
    elist[pos] = e;
}

// ---------------------------------------------------------------------------
// FUSED gather + LayerNorm + state softmax.
// Blocks [0, Bn*Nd): gather dv[row] in registers -> LN(v_in + gate*dv) -> v_out;
//                    zero cursor[row] for next transition.
// Blocks [Bn*Nd, Bn*Nd+Bn): rebuild ds for batch b from (ib, cbuf) via an LDS
//                    histogram, then state' = sign(x)*softmax(|x|).
// v_out must not alias src_val (host ping-pongs for prop transitions).
// ---------------------------------------------------------------------------
#define ECHUNK 512
__launch_bounds__(256)
__global__ void gather_ln_state_kernel(const float* __restrict__ src_val, const float* __restrict__ c,
                                       const int* __restrict__ eidx, const int* __restrict__ elist,
                                       const int* __restrict__ offs,
                                       const float* __restrict__ v_in, float* __restrict__ v_out,
                                       const float* __restrict__ s_in, float* __restrict__ s_out,
                                       int* __restrict__ cursor,
                                       const float* __restrict__ gamma, const float* __restrict__ beta,
                                       const float* __restrict__ gatePtr, int gateIdx,
                                       int nsShift, int Nd, int Ns, int Bn)
{
    __shared__ float sc[ECHUNK];
    __shared__ int   srow[ECHUNK];
    __shared__ float part[4][512];
    __shared__ float red[4];
    int t = threadIdx.x;
    float gate = 1.f;
    if (gatePtr) gate = 1.f / (1.f + expf(-gatePtr[gateIdx]));
    int nLN = gridDim.x - Bn;

    if ((int)blockIdx.x < nLN) {
        long row = blockIdx.x;
        int w = t >> 6, lane = t & 63;
        int e0 = offs[row], e1 = offs[row + 1];
        int mask = (1 << nsShift) - 1;
        int cb = lane * 8;
        float a[8] = {};

        for (int cstart = e0; cstart < e1; cstart += ECHUNK) {
            int cnt = min(e1 - cstart, ECHUNK);
            for (int i = t; i < cnt; i += 256) {
                int e = elist[cstart + i];
                sc[i] = c[e];
                int b = e >> nsShift;
                int s = (e & mask) >> 4;
                srow[i] = (b << (nsShift - 4)) + s;
            }
            __syncthreads();
            int j = w;
            for (; j + 12 < cnt; j += 16) {
                float c0 = sc[j], c1 = sc[j + 4], c2 = sc[j + 8], c3 = sc[j + 12];
                const float* p0 = src_val + ((long)srow[j]      << 9) + cb;
                const float* p1 = src_val + ((long)srow[j + 4]  << 9) + cb;
                const float* p2 = src_val + ((long)srow[j + 8]  << 9) + cb;
                const float* p3 = src_val + ((long)srow[j + 12] << 9) + cb;
                float4 x00 = *(const float4*)p0,       x01 = *(const float4*)(p0 + 4);
                float4 x10 = *(const float4*)p1,       x11 = *(const float4*)(p1 + 4);
                float4 x20 = *(const float4*)p2,       x21 = *(const float4*)(p2 + 4);
                float4 x30 = *(const float4*)p3,       x31 = *(const float4*)(p3 + 4);
                a[0] += c0 * x00.x + c1 * x10.x + c2 * x20.x + c3 * x30.x;
                a[1] += c0 * x00.y + c1 * x10.y + c2 * x20.y + c3 * x30.y;
                a[2] += c0 * x00.z + c1 * x10.z + c2 * x20.z + c3 * x30.z;
                a[3] += c0 * x00.w + c1 * x10.w + c2 * x20.w + c3 * x30.w;
                a[4] += c0 * x01.x + c1 * x11.x + c2 * x21.x + c3 * x31.x;
                a[5] += c0 * x01.y + c1 * x11.y + c2 * x21.y + c3 * x31.y;
                a[6] += c0 * x01.z + c1 * x11.z + c2 * x21.z + c3 * x31.z;
                a[7] += c0 * x01.w + c1 * x11.w + c2 * x21.w + c3 * x31.w;
            }
            for (; j < cnt; j += 4) {
                float cv = sc[j];
                const float* p = src_val + ((long)srow[j] << 9) + cb;
                float4 x0 = *(const float4*)p, x1 = *(const float4*)(p + 4);
                a[0] += cv * x0.x; a[1] += cv * x0.y; a[2] += cv * x0.z; a[3] += cv * x0.w;
                a[4] += cv * x1.x; a[5] += cv * x1.y; a[6] += cv * x1.z; a[7] += cv * x1.w;
            }
            __syncthreads();
        }
#pragma unroll
        for (int i = 0; i < 8; ++i) part[w][cb + i] = a[i];
        __syncthreads();
        float r0 = part[0][t] + part[1][t] + part[2][t] + part[3][t];
        float r1 = part[0][t + 256] + part[1][t + 256] + part[2][t + 256] + part[3][t + 256];
        if (t == 0) cursor[row] = 0;

        const float* vi = v_in + (row << 9);
        float x0 = vi[t]       + gate * r0;
        float x1 = vi[t + 256] + gate * r1;
        float s = x0 + x1;
        for (int off = 32; off; off >>= 1) s += __shfl_down(s, off);
        if ((t & 63) == 0) red[t >> 6] = s;
        __syncthreads();
        float mean = (red[0] + red[1] + red[2] + red[3]) * (1.f / 512.f);
        float d0 = x0 - mean, d1 = x1 - mean;
        float ss = d0 * d0 + d1 * d1;
        for (int off = 32; off; off >>= 1) ss += __shfl_down(ss, off);
        __syncthreads();
        if ((t & 63) == 0) red[t >> 6] = ss;
        __syncthreads();
        float var = (red[0] + red[1] + red[2] + red[3]) * (1.f / 512.f);
        float rstd = rsqrtf(var + 1e-5f);
        float* vo = v_out + (row << 9);
        vo[t]       = d0 * rstd * gamma[t]       + beta[t];
        vo[t + 256] = d1 * rstd * gamma[t + 256] + beta[t + 256];
    } else {
        // ---- state path: rebuild ds via LDS histogram, then signed softmax ----
        __shared__ float dsl[1024];
        int b = (int)blockIdx.x - nLN;
        for (int i = t; i < Nd; i += 256) dsl[i] = 0.f;
        __syncthreads();
        int Eb = Ns * 16;
        int ebase = b * Eb;
        for (int e = t; e < Eb; e += 256)
            atomicAdd(&dsl[eidx[ebase + e]], c[ebase + e]);
        __syncthreads();
        float lmax = 0.f;
        for (int i = t; i < Nd; i += 256) {
            float x = s_in[b * Nd + i] + gate * dsl[i];
            dsl[i] = x;
            lmax = fmaxf(lmax, fabsf(x));
        }
        for (int off = 32; off; off >>= 1) lmax = fmaxf(lmax, __shfl_down(lmax, off));
        if ((t & 63) == 0) red[t >> 6] = lmax;
        __syncthreads();
        float bmax = fmaxf(fmaxf(red[0], red[1]), fmaxf(red[2], red[3]));
        float lsum = 0.f;
        for (int i = t; i < Nd; i += 256) lsum += expf(fabsf(dsl[i]) - bmax);
        for (int off = 32; off; off >>= 1) lsum += __shfl_down(lsum, off);
        __syncthreads();
        if ((t & 63) == 0) red[t >> 6] = lsum;
        __syncthreads();
        float inv = 1.f / (red[0] + red[1] + red[2] + red[3]);
        for (int i = t; i < Nd; i += 256) {
            float x = dsl[i];
            float sgn = (x > 0.f) ? 1.f : ((x < 0.f) ? -1.f : 0.f);
            s_out[b * Nd + i] = sgn * expf(fabsf(x) - bmax) * inv;
        }
    }
}

// ---------------------------------------------------------------------------
// Plain softmax over rows, in place (read phase).
// ---------------------------------------------------------------------------
__launch_bounds__(256)
__global__ void softmax_rows_kernel(float* __restrict__ logits, int Nd)
{
    __shared__ float red[4];
    long row = blockIdx.x;
    int t = threadIdx.x;
    float* L = logits + row * (long)Nd;
    float lmax = -INFINITY;
    for (int i = t; i < Nd; i += 256) lmax = fmaxf(lmax, L[i]);
    for (int off = 32; off; off >>= 1) lmax = fmaxf(lmax, __shfl_down(lmax, off));
    if ((t & 63) == 0) red[t >> 6] = lmax;
    __syncthreads();
    float bmax = fmaxf(fmaxf(red[0], red[1]), fmaxf(red[2], red[3]));
    float lsum = 0.f;
    for (int i = t; i < Nd; i += 256) lsum += expf(L[i] - bmax);
    for (int off = 32; off; off >>= 1) lsum += __shfl_down(lsum, off);
    __syncthreads();
    if ((t & 63) == 0) red[t >> 6] = lsum;
    __syncthreads();
    float inv = 1.f / (red[0] + red[1] + red[2] + red[3]);
    for (int i = t; i < Nd; i += 256) L[i] = expf(L[i] - bmax) * inv;
}

// ---------------------------------------------------------------------------
extern "C" void kernel_launch(void* const* d_in, const int* in_sizes, int n_in,
                              void* d_out, int out_size, void* d_ws, size_t ws_size,
                              hipStream_t stream)
{
    const int Bn = 4, T = 1024, D = 512, R = 64;
    const int S0 = 1024, S1 = 256, S2 = 64;
    const long RT = (long)D * R;
    const int MR = 3 * T + S0 + S1 + S2;   // read-phase combined rows = 4416

    const float* tok_val    = (const float*)d_in[0];
    const float* tok_state  = (const float*)d_in[1];
    const float* mem_state0 = (const float*)d_in[2];
    const float* mem_val0   = (const float*)d_in[3];
    const float* mem_state1 = (const float*)d_in[4];
    const float* mem_val1   = (const float*)d_in[5];
    const float* mem_state2 = (const float*)d_in[6];
    const float* mem_val2   = (const float*)d_in[7];
    const float* write_route= (const float*)d_in[8];
    const float* prop_route = (const float*)d_in[9];
    const float* level_route= (const float*)d_in[10];
    const float* skip_route = (const float*)d_in[11];
    const float* skip_gates = (const float*)d_in[12];
    const float* ln_gamma   = (const float*)d_in[13];
    const float* ln_beta    = (const float*)d_in[14];
    const float* read_route = (const float*)d_in[15];
    const float* read_proj  = (const float*)d_in[16];
    const float* read_gates = (const float*)d_in[17];
    float* out = (float*)d_out;

    // workspace carve
    float* p = (float*)d_ws;
    float* v0  = p; p += (long)Bn * S0 * D;
    float* v0b = p; p += (long)Bn * S0 * D;
    float* s0  = p; p += Bn * S0;
    float* v1  = p; p += (long)Bn * S1 * D;
    float* v1b = p; p += (long)Bn * S1 * D;
    float* s1  = p; p += Bn * S1;
    float* v2  = p; p += (long)Bn * S2 * D;
    float* v2b = p; p += (long)Bn * S2 * D;
    float* s2  = p; p += Bn * S2;
    float* qk  = p; p += (long)Bn * (T + S0) * R;   // transition q|k combined
    float* rqk = p; p += (long)Bn * MR * R;         // read-phase combined
    float* lb  = p; p += (long)Bn * T * S0;
    float* cbuf= p; p += (long)Bn * T * 16;
    int*   ib  = (int*)p; p += (long)Bn * T * 16;
    float* rb  = p; p += (long)Bn * T * D;
    int* cntb  = (int*)p; p += Bn * S0;
    int* curb  = (int*)p; p += Bn * S0;
    int* offsb = (int*)p; p += Bn * S0 + 1;
    int* elistb= (int*)p; p += (long)Bn * T * 16;
    unsigned short* projT = (unsigned short*)p; p += (3 * (long)D * D) / 2 + 4;
    unsigned short* mvT0  = (unsigned short*)p; p += ((long)Bn * D * S0) / 2 + 4;
    unsigned short* mvT1  = (unsigned short*)p; p += ((long)Bn * D * S1) / 2 + 4;
    unsigned short* mvT2  = (unsigned short*)p; p += ((long)Bn * D * S2) / 2 + 4;
    float* partb = p; p += 8L * Bn * MR * R;        // split-K partials (36 MB)

    // one-time zero of cnt + cursor (workspace is re-poisoned before every call)
    hipMemsetAsync(cntb, 0, (size_t)2 * Bn * S0 * sizeof(int), stream);

    auto trans = [&](const float* sv, const float* ss, const float* dval,
                     const float* W, int Ns, int Nd,
                     const float* v_in, float* v_out, const float* sin, float* sout,
                     int lvl, const float* gptr, int gidx) {
        int Mtot = Ns + Nd;
        ProjDesc d = {};
        d.A[0] = sv;   d.W[0] = W;      d.sA[0] = (long)Ns * D; d.rowOff[0] = 0;
        d.A[1] = dval; d.W[1] = W + RT; d.sA[1] = (long)Nd * D; d.rowOff[1] = Ns;
        int tot = Mtot / 64;
        d.tileOff[0] = 0; d.tileOff[1] = Ns / 64;
        for (int i = 2; i <= 6; ++i) d.tileOff[i] = tot;
        d.Mtot = Mtot;
        proj_splitk_kernel<<<dim3(tot, 8, Bn), 256, 0, stream>>>(d, partb, Bn);
        int total4 = Bn * Mtot * 16;
        proj_reduce_kernel<<<(total4 + 255) / 256, 256, 0, stream>>>(partb, qk, total4);
        gemm_f32_nt_kernel<<<dim3(Ns / 64, Nd / 64, Bn), 256, 0, stream>>>(
            qk, qk + (long)Ns * R, lb, Ns, Nd, R,
            (long)Mtot * R, (long)Mtot * R, (long)Ns * Nd, 0.125f);
        int nsLog = 31 - __builtin_clz((unsigned)Ns);
        int nsShift = nsLog + 4;
        int rowBlocks = Bn * Ns / 4;
        if (Nd == 1024)
            topk_coeff_kernel<16><<<rowBlocks, 256, 0, stream>>>(lb, ss, ib, cbuf, cntb, nsLog, Nd);
        else if (Nd == 256)
            topk_coeff_kernel<4><<<rowBlocks, 256, 0, stream>>>(lb, ss, ib, cbuf, cntb, nsLog, Nd);
        else
            topk_coeff_kernel<1><<<rowBlocks, 256, 0, stream>>>(lb, ss, ib, cbuf, cntb, nsLog, Nd);
        int E = Bn * Ns * 16;
        scan_kernel<<<1, 256, 0, stream>>>(cntb, offsb, Bn * Nd);
        fill_edges_kernel<<<(E + 255) / 256, 256, 0, stream>>>(ib, offsb, curb, elistb,
                                                               nsShift, Nd, E);
        gather_ln_state_kernel<<<Bn * Nd + Bn, 256, 0, stream>>>(
            sv, cbuf, ib, elistb, offsb, v_in, v_out, sin, sout, curb,
            ln_gamma + lvl * D, ln_beta + lvl * D, gptr, gidx, nsShift, Nd, Ns, Bn);
    };

    // ---- level 0 ----
    trans(tok_val, tok_state, mem_val0, write_route, T, S0,
          mem_val0, v0, mem_state0, s0, 0, nullptr, 0);
    trans(v0, s0, v0, prop_route + 0 * 2 * RT, S0, S0,
          v0, v0b, s0, s0, 0, nullptr, 0);                    // out = v0b

    // ---- level 1 ----
    trans(v0b, s0, mem_val1, level_route + 0 * 2 * RT, S0, S1,
          mem_val1, v1, mem_state1, s1, 1, nullptr, 0);
    trans(tok_val, tok_state, v1, skip_route + 0 * 2 * RT, T, S1,
          v1, v1, s1, s1, 1, skip_gates, 0);                  // in-place ok (sv=tok_val)
    trans(v1, s1, v1, prop_route + 1 * 2 * RT, S1, S1,
          v1, v1b, s1, s1, 1, nullptr, 0);                    // out = v1b

    // ---- level 2 ----
    trans(v1b, s1, mem_val2, level_route + 1 * 2 * RT, S1, S2,
          mem_val2, v2, mem_state2, s2, 2, nullptr, 0);
    trans(v0b, s0, v2, skip_route + 1 * 2 * RT, S0, S2,
          v2, v2, s2, s2, 2, skip_gates, 1);                  // in-place ok (sv=v0b)
    trans(v2, s2, v2, prop_route + 2 * 2 * RT, S2, S2,
          v2, v2b, s2, s2, 2, nullptr, 0);                    // out = v2b

    // ---- read phase ----
    transpose_bf16_kernel<<<dim3(D / 32, D / 32, 3), dim3(32, 8), 0, stream>>>(
        read_proj, projT, D, D, (long)D * D, (long)D * D);
    transpose_mv_kernel<<<dim3(D / 32, (S0 + S1 + S2) / 32, Bn), dim3(32, 8), 0, stream>>>(
        v0b, v1b, v2b, mvT0, mvT1, mvT2);

    // all 6 read projections in one split-K launch
    {
        ProjDesc d = {};
        const float* mvs[3] = { v0b, v1b, v2b };
        const int nds[3] = { S0, S1, S2 };
        int tiles = 0, roff = 0;
        for (int l = 0; l < 3; ++l) {        // q segments
            d.A[l] = tok_val; d.W[l] = read_route + (long)l * 2 * RT;
            d.sA[l] = (long)T * D; d.rowOff[l] = roff;
            d.tileOff[l] = tiles; tiles += T / 64; roff += T;
        }
        for (int l = 0; l < 3; ++l) {        // k segments
            d.A[3 + l] = mvs[l]; d.W[3 + l] = read_route + (long)l * 2 * RT + RT;
            d.sA[3 + l] = (long)nds[l] * D; d.rowOff[3 + l] = roff;
            d.tileOff[3 + l] = tiles; tiles += nds[l] / 64; roff += nds[l];
        }
        d.tileOff[6] = tiles;
        d.Mtot = MR;
        proj_splitk_kernel<<<dim3(tiles, 8, Bn), 256, 0, stream>>>(d, partb, Bn);
        int total4 = Bn * MR * 16;
        proj_reduce_kernel<<<(total4 + 255) / 256, 256, 0, stream>>>(partb, rqk, total4);
    }

    const unsigned short* mvTs[3] = { mvT0, mvT1, mvT2 };
    const int nds[3] = { S0, S1, S2 };
    int koff = 3 * T;
    for (int l = 0; l < 3; ++l) {
        int Nd = nds[l];
        gemm_f32_nt_kernel<<<dim3(T / 64, Nd / 64, Bn), 256, 0, stream>>>(
            rqk + (long)l * T * R, rqk + (long)koff * R, lb, T, Nd, R,
            (long)MR * R, (long)MR * R, (long)T * Nd, 0.125f);
        koff += Nd;
        softmax_rows_kernel<<<Bn * T, 256, 0, stream>>>(lb, Nd);
        gemm_mfma_kernel<<<dim3(T / 64, D / 64, Bn), 256, 0, stream>>>(
            lb, mvTs[l], rb, T, D, Nd, (long)T * Nd, (long)D * Nd, (long)T * D,
            1.f, nullptr, 0, 0.f, nullptr);
        // out = (l==0 ? tok_val : out) + sigmoid(gate_l) * r x proj_l
        gemm_mfma_kernel<<<dim3(T / 64, D / 64, Bn), 256, 0, stream>>>(
            rb, projT + (long)l * D * D, out, T, D, D,
            (long)T * D, 0, (long)T * D, 1.f, read_gates, l,
            1.f, (l == 0) ? tok_val : nullptr);
    }
}

// Round 12
// 908.955 us; speedup vs baseline: 1.1154x; 1.1154x over previous
//
#include <hip/hip_runtime.h>
#include <math.h>

typedef __attribute__((ext_vector_type(8))) short short8;
typedef __attribute__((ext_vector_type(4))) float floatx4;

static __device__ __forceinline__ short f2bf(float f) {
    union { float f; unsigned u; } c; c.f = f;
    unsigned r = c.u + 0x7FFF + ((c.u >> 16) & 1);   // RNE
    return (short)(r >> 16);
}

// ---------------------------------------------------------------------------
// fp32 GEMM: C[b] = alpha * A[b](M,K) x B[b](N,K)^T. 64x64 tile, 4x4 micro.
// fp32-exact path (logits feed exact top-k; read-phase attention logits).
// ---------------------------------------------------------------------------
__launch_bounds__(256)
__global__ void gemm_f32_nt_kernel(const float* __restrict__ A, const float* __restrict__ B,
                                   float* __restrict__ C, int M, int N, int K,
                                   long sA, long sB, long sC, float alpha)
{
    __shared__ float As[32][68];   // [k][m]
    __shared__ float Bs[32][68];   // [k][n]
    const float* Ab = A + (long)blockIdx.z * sA;
    const float* Bb = B + (long)blockIdx.z * sB;
    float* Cb = C + (long)blockIdx.z * sC;
    int m0 = blockIdx.x * 64, n0 = blockIdx.y * 64;
    int t = threadIdx.x;
    int tx = t & 15, ty = t >> 4;
    float acc[4][4] = {};

    for (int k0 = 0; k0 < K; k0 += 32) {
        {
            int m = t >> 3;
            int kk = (t & 7) * 4;
#pragma unroll
            for (int h = 0; h < 2; ++h) {
                float4 v = *(const float4*)&Ab[(long)(m0 + m + 32 * h) * K + k0 + kk];
                As[kk + 0][m + 32 * h] = v.x; As[kk + 1][m + 32 * h] = v.y;
                As[kk + 2][m + 32 * h] = v.z; As[kk + 3][m + 32 * h] = v.w;
            }
        }
        {
            int n = t >> 3;
            int kk = (t & 7) * 4;
#pragma unroll
            for (int h = 0; h < 2; ++h) {
                float4 v = *(const float4*)&Bb[(long)(n0 + n + 32 * h) * K + k0 + kk];
                Bs[kk + 0][n + 32 * h] = v.x; Bs[kk + 1][n + 32 * h] = v.y;
                Bs[kk + 2][n + 32 * h] = v.z; Bs[kk + 3][n + 32 * h] = v.w;
            }
        }
        __syncthreads();
#pragma unroll 4
        for (int k = 0; k < 32; ++k) {
            float4 a = *(const float4*)&As[k][ty * 4];
            float4 b = *(const float4*)&Bs[k][tx * 4];
            float av[4] = { a.x, a.y, a.z, a.w };
            float bv[4] = { b.x, b.y, b.z, b.w };
#pragma unroll
            for (int i = 0; i < 4; ++i)
#pragma unroll
                for (int j = 0; j < 4; ++j) acc[i][j] += av[i] * bv[j];
        }
        __syncthreads();
    }
#pragma unroll
    for (int i = 0; i < 4; ++i) {
        float4 r;
        r.x = alpha * acc[i][0]; r.y = alpha * acc[i][1];
        r.z = alpha * acc[i][2]; r.w = alpha * acc[i][3];
        *(float4*)&Cb[(long)(m0 + ty * 4 + i) * N + n0 + tx * 4] = r;
    }
}

// ---------------------------------------------------------------------------
// Split-K q/k projection for transitions (round-9 proven path):
// q = Aq(Mq,512) x Wq(512,64) and k = Ak(Mk,512) x Wk(512,64) in one launch.
// ---------------------------------------------------------------------------
__launch_bounds__(256)
__global__ void proj_splitk_kernel(const float* __restrict__ Aq, const float* __restrict__ Ak,
                                   const float* __restrict__ Wq, const float* __restrict__ Wk,
                                   float* __restrict__ part,
                                   int Mq, int Mk, long sAq, long sAk, int Bn)
{
    __shared__ float As[32][68];
    __shared__ float Bs[32][68];
    int mqT = Mq >> 6;
    int xt = blockIdx.x, s = blockIdx.y, b = blockIdx.z;
    const float* A; const float* W; int row0, orow;
    if (xt < mqT) { A = Aq + (long)b * sAq; W = Wq; row0 = xt * 64; orow = row0; }
    else { A = Ak + (long)b * sAk; W = Wk; row0 = (xt - mqT) * 64; orow = Mq + row0; }
    int t = threadIdx.x, tx = t & 15, ty = t >> 4;
    float acc[4][4] = {};
    int kbase = s * 64;

    for (int k0 = kbase; k0 < kbase + 64; k0 += 32) {
        {
            int m = t >> 3;
            int kk = (t & 7) * 4;
#pragma unroll
            for (int h = 0; h < 2; ++h) {
                float4 v = *(const float4*)&A[(long)(row0 + m + 32 * h) * 512 + k0 + kk];
                As[kk + 0][m + 32 * h] = v.x; As[kk + 1][m + 32 * h] = v.y;
                As[kk + 2][m + 32 * h] = v.z; As[kk + 3][m + 32 * h] = v.w;
            }
        }
        {
            int kk = t >> 3;
            int nn = (t & 7) * 8;
            float4 v0 = *(const float4*)&W[(long)(k0 + kk) * 64 + nn];
            float4 v1 = *(const float4*)&W[(long)(k0 + kk) * 64 + nn + 4];
            *(float4*)&Bs[kk][nn] = v0;
            *(float4*)&Bs[kk][nn + 4] = v1;
        }
        __syncthreads();
#pragma unroll 4
        for (int k = 0; k < 32; ++k) {
            float4 a = *(const float4*)&As[k][ty * 4];
            float4 b2 = *(const float4*)&Bs[k][tx * 4];
            float av[4] = { a.x, a.y, a.z, a.w };
            float bv[4] = { b2.x, b2.y, b2.z, b2.w };
#pragma unroll
            for (int i = 0; i < 4; ++i)
#pragma unroll
                for (int j = 0; j < 4; ++j) acc[i][j] += av[i] * bv[j];
        }
        __syncthreads();
    }
    long base = ((long)(s * Bn + b) * (Mq + Mk) + orow) * 64;
#pragma unroll
    for (int i = 0; i < 4; ++i)
        *(float4*)&part[base + (long)(ty * 4 + i) * 64 + tx * 4] =
            make_float4(acc[i][0], acc[i][1], acc[i][2], acc[i][3]);
}

__launch_bounds__(256)
__global__ void proj_reduce_kernel(const float* __restrict__ part,
                                   float* __restrict__ qout, float* __restrict__ kout,
                                   int Mq, int Mk, int Bn)
{
    int idx = blockIdx.x * 256 + threadIdx.x;
    int size4b = (Mq + Mk) * 16;
    int total4 = Bn * size4b;
    if (idx >= total4) return;
    const float4* p4 = (const float4*)part;
    long stride4 = (long)total4;
    float4 s = p4[idx];
#pragma unroll
    for (int ss = 1; ss < 8; ++ss) {
        float4 v = p4[ss * stride4 + idx];
        s.x += v.x; s.y += v.y; s.z += v.z; s.w += v.w;
    }
    int b = idx / size4b;
    int rem = idx - b * size4b;
    int r = rem >> 4;
    int c4 = rem & 15;
    if (r < Mq) ((float4*)qout)[((long)b * Mq + r) * 16 + c4] = s;
    else        ((float4*)kout)[((long)b * Mk + (r - Mq)) * 16 + c4] = s;
}

// ---------------------------------------------------------------------------
// Multi-segment split-K projection (read phase only): 6 segments in one launch.
// ---------------------------------------------------------------------------
struct ProjDesc {
    const float* A[6];
    const float* W[6];
    long  sA[6];
    int   tileOff[7];
    int   rowOff[6];
    int   Mtot;
};

__launch_bounds__(256)
__global__ void proj_splitk_multi_kernel(ProjDesc d, float* __restrict__ part, int Bn)
{
    __shared__ float As[32][68];
    __shared__ float Bs[32][68];
    int xt = blockIdx.x, s = blockIdx.y, b = blockIdx.z;
    int seg = 0;
    while (xt >= d.tileOff[seg + 1]) ++seg;
    int row0 = (xt - d.tileOff[seg]) * 64;
    const float* A = d.A[seg] + (long)b * d.sA[seg];
    const float* W = d.W[seg];
    int orow = d.rowOff[seg] + row0;
    int t = threadIdx.x, tx = t & 15, ty = t >> 4;
    float acc[4][4] = {};
    int kbase = s * 64;

    for (int k0 = kbase; k0 < kbase + 64; k0 += 32) {
        {
            int m = t >> 3;
            int kk = (t & 7) * 4;
#pragma unroll
            for (int h = 0; h < 2; ++h) {
                float4 v = *(const float4*)&A[(long)(row0 + m + 32 * h) * 512 + k0 + kk];
                As[kk + 0][m + 32 * h] = v.x; As[kk + 1][m + 32 * h] = v.y;
                As[kk + 2][m + 32 * h] = v.z; As[kk + 3][m + 32 * h] = v.w;
            }
        }
        {
            int kk = t >> 3;
            int nn = (t & 7) * 8;
            float4 v0 = *(const float4*)&W[(long)(k0 + kk) * 64 + nn];
            float4 v1 = *(const float4*)&W[(long)(k0 + kk) * 64 + nn + 4];
            *(float4*)&Bs[kk][nn] = v0;
            *(float4*)&Bs[kk][nn + 4] = v1;
        }
        __syncthreads();
#pragma unroll 4
        for (int k = 0; k < 32; ++k) {
            float4 a = *(const float4*)&As[k][ty * 4];
            float4 b2 = *(const float4*)&Bs[k][tx * 4];
            float av[4] = { a.x, a.y, a.z, a.w };
            float bv[4] = { b2.x, b2.y, b2.z, b2.w };
#pragma unroll
            for (int i = 0; i < 4; ++i)
#pragma unroll
                for (int j = 0; j < 4; ++j) acc[i][j] += av[i] * bv[j];
        }
        __syncthreads();
    }
    long base = ((long)(s * Bn + b) * d.Mtot + orow) * 64;
#pragma unroll
    for (int i = 0; i < 4; ++i)
        *(float4*)&part[base + (long)(ty * 4 + i) * 64 + tx * 4] =
            make_float4(acc[i][0], acc[i][1], acc[i][2], acc[i][3]);
}

// Flat reduce of 8 split-K slices -> out[(b*Mtot+r)*64+c], contiguous.
__launch_bounds__(256)
__global__ void proj_reduce_flat_kernel(const float* __restrict__ part, float* __restrict__ outp,
                                        int total4)
{
    int idx = blockIdx.x * 256 + threadIdx.x;
    if (idx >= total4) return;
    const float4* p4 = (const float4*)part;
    float4 s = p4[idx];
#pragma unroll
    for (int ss = 1; ss < 8; ++ss) {
        float4 v = p4[(long)ss * total4 + idx];
        s.x += v.x; s.y += v.y; s.z += v.z; s.w += v.w;
    }
    ((float4*)outp)[idx] = s;
}

// ---------------------------------------------------------------------------
// bf16 MFMA GEMM: C[b](M,N) = alpha' * A[b](M,K,fp32) x Bt[b](N,K,bf16) (+ C | + initC)
// ---------------------------------------------------------------------------
__launch_bounds__(256)
__global__ void gemm_mfma_kernel(const float* __restrict__ A, const unsigned short* __restrict__ Bt,
                                 float* __restrict__ C, int M, int N, int K,
                                 long sA, long sBt, long sC,
                                 float alpha, const float* __restrict__ gate, int gateIdx,
                                 float beta, const float* __restrict__ initC)
{
    __shared__ short As[2048];
    __shared__ short Bs[2048];
    const float* Ab = A + (long)blockIdx.z * sA;
    const unsigned short* Bb = Bt + (long)blockIdx.z * sBt;
    float* Cb = C + (long)blockIdx.z * sC;
    const float* Ib = initC ? initC + (long)blockIdx.z * sC : nullptr;
    int m0 = blockIdx.x * 64, n0 = blockIdx.y * 64;
    int t = threadIdx.x, wave = t >> 6, lane = t & 63;
    int sr = wave * 16 + (lane & 15);
    int sk = (lane >> 4) * 8;
    floatx4 acc[4] = {};

    for (int k0 = 0; k0 < K; k0 += 32) {
        const float* ap = &Ab[(long)(m0 + sr) * K + k0 + sk];
        float4 f0 = *(const float4*)ap;
        float4 f1 = *(const float4*)(ap + 4);
        short8 av;
        av[0] = f2bf(f0.x); av[1] = f2bf(f0.y); av[2] = f2bf(f0.z); av[3] = f2bf(f0.w);
        av[4] = f2bf(f1.x); av[5] = f2bf(f1.y); av[6] = f2bf(f1.z); av[7] = f2bf(f1.w);
        short8 bv = *(const short8*)&Bb[(long)(n0 + sr) * K + k0 + sk];
        ((short8*)As)[t] = av;
        ((short8*)Bs)[t] = bv;
        __syncthreads();
        short8 bf = ((short8*)Bs)[wave * 64 + lane];
#pragma unroll
        for (int mt = 0; mt < 4; ++mt) {
            short8 af = ((short8*)As)[mt * 64 + lane];
            acc[mt] = __builtin_amdgcn_mfma_f32_16x16x32_bf16(af, bf, acc[mt], 0, 0, 0);
        }
        __syncthreads();
    }
    float a = alpha;
    if (gate) a *= 1.f / (1.f + expf(-gate[gateIdx]));
    int col = n0 + wave * 16 + (lane & 15);
#pragma unroll
    for (int mt = 0; mt < 4; ++mt) {
#pragma unroll
        for (int r = 0; r < 4; ++r) {
            int row = m0 + mt * 16 + (lane >> 4) * 4 + r;
            long off = (long)row * N + col;
            float v = a * acc[mt][r];
            if (Ib) v += Ib[off];
            else if (beta != 0.f) v += Cb[off];
            Cb[off] = v;
        }
    }
}

// ---------------------------------------------------------------------------
// Transpose + bf16 convert: out[c][r] = bf16(in[r][c]). (read_proj)
// ---------------------------------------------------------------------------
__global__ void transpose_bf16_kernel(const float* __restrict__ in, unsigned short* __restrict__ out,
                                      int Rr, int Cc, long sIn, long sOut)
{
    __shared__ float tile[32][33];
    const float* I = in + (long)blockIdx.z * sIn;
    unsigned short* O = out + (long)blockIdx.z * sOut;
    int c0 = blockIdx.x * 32, r0 = blockIdx.y * 32;
    int tx = threadIdx.x, ty = threadIdx.y;
#pragma unroll
    for (int i = 0; i < 32; i += 8)
        tile[ty + i][tx] = I[(long)(r0 + ty + i) * Cc + c0 + tx];
    __syncthreads();
#pragma unroll
    for (int i = 0; i < 32; i += 8)
        O[(long)(c0 + ty + i) * Rr + r0 + tx] = (unsigned short)f2bf(tile[tx][ty + i]);
}

// Batched transpose of the 3 mv levels in one launch. y-tiles: 32|8|2.
__global__ void transpose_mv_kernel(const float* __restrict__ mv0, const float* __restrict__ mv1,
                                    const float* __restrict__ mv2,
                                    unsigned short* __restrict__ o0, unsigned short* __restrict__ o1,
                                    unsigned short* __restrict__ o2)
{
    __shared__ float tile[32][33];
    int yt = blockIdx.y;
    const float* in; unsigned short* out; int Nd, r0t;
    if (yt < 32)      { in = mv0; out = o0; Nd = 1024; r0t = yt; }
    else if (yt < 40) { in = mv1; out = o1; Nd = 256;  r0t = yt - 32; }
    else              { in = mv2; out = o2; Nd = 64;   r0t = yt - 40; }
    const float* I = in + (long)blockIdx.z * Nd * 512;
    unsigned short* O = out + (long)blockIdx.z * 512 * Nd;
    int c0 = blockIdx.x * 32, r0 = r0t * 32;
    int tx = threadIdx.x, ty = threadIdx.y;
#pragma unroll
    for (int i = 0; i < 32; i += 8)
        tile[ty + i][tx] = I[(long)(r0 + ty + i) * 512 + c0 + tx];
    __syncthreads();
#pragma unroll
    for (int i = 0; i < 32; i += 8)
        O[(long)(c0 + ty + i) * Nd + r0 + tx] = (unsigned short)f2bf(tile[tx][ty + i]);
}

// ---------------------------------------------------------------------------
// Exact top-16 per row + fused CSR count. 4 rows/block (one wave per row),
// lane owns contiguous slice of the logits row (float4 loads from lb).
// ---------------------------------------------------------------------------
template<int CNT>
__launch_bounds__(256)
__global__ void topk_coeff_kernel(const float* __restrict__ logits,
                                  const float* __restrict__ state,
                                  int* __restrict__ idx_out, float* __restrict__ c_out,
                                  int* __restrict__ cnt, int nsLog, int Nd)
{
    int wave = threadIdx.x >> 6, lane = threadIdx.x & 63;
    long row = (long)blockIdx.x * 4 + wave;
    const float* L = logits + row * Nd;
    float vreg[CNT];
    if (CNT >= 4) {
#pragma unroll
        for (int q = 0; q < CNT / 4; ++q) {
            float4 v = *(const float4*)&L[lane * CNT + q * 4];
            vreg[q * 4 + 0] = v.x; vreg[q * 4 + 1] = v.y;
            vreg[q * 4 + 2] = v.z; vreg[q * 4 + 3] = v.w;
        }
    } else {
#pragma unroll
        for (int tt = 0; tt < CNT; ++tt) vreg[tt] = L[lane * CNT + tt];
    }

    float m = 0.f, sum = 0.f;
    float myv = 0.f; int myi = 0;
#pragma unroll
    for (int it = 0; it < 16; ++it) {
        float best = -INFINITY; int bidx = 0x7fffffff;
#pragma unroll
        for (int tt = 0; tt < CNT; ++tt) {
            if (vreg[tt] > best) { best = vreg[tt]; bidx = lane * CNT + tt; }
        }
#pragma unroll
        for (int off = 32; off; off >>= 1) {
            float ov = __shfl_down(best, off);
            int   oi = __shfl_down(bidx, off);
            if (ov > best || (ov == best && oi < bidx)) { best = ov; bidx = oi; }
        }
        best = __shfl(best, 0);
        bidx = __shfl(bidx, 0);
        if (it == lane) { myv = best; myi = bidx; }
        float ab = fabsf(best);
        float nm = fmaxf(m, ab);
        sum = sum * expf(m - nm) + expf(ab - nm);
        m = nm;
#pragma unroll
        for (int tt = 0; tt < CNT; ++tt)
            if (lane * CNT + tt == bidx) vreg[tt] = -INFINITY;
    }
    if (lane < 16) {
        float st = state[row];
        float sp = fmaxf(st, 0.f) + log1pf(expf(-fabsf(st)));
        float sgn = (myv > 0.f) ? 1.f : ((myv < 0.f) ? -1.f : 0.f);
        float w = expf(fabsf(myv) - m) / sum;
        c_out[row * 16 + lane] = sgn * w * sp;
        idx_out[row * 16 + lane] = myi;
        int b = (int)(row >> nsLog);
        atomicAdd(&cnt[b * Nd + myi], 1);
    }
}

// Single-block exclusive scan; self-zeroes cnt (next Nd <= current Nd).
__launch_bounds__(256)
__global__ void scan_kernel(int* __restrict__ cnt, int* __restrict__ offs, int N)
{
    __shared__ int sums[256];
    int t = threadIdx.x;
    int chunk = N >> 8;
    int base = t * chunk;
    int lc[16];
    int s = 0;
    for (int i = 0; i < chunk; ++i) { lc[i] = cnt[base + i]; s += lc[i]; }
    sums[t] = s;
    __syncthreads();
    for (int off = 1; off < 256; off <<= 1) {
        int v = (t >= off) ? sums[t - off] : 0;
        __syncthreads();
        sums[t] += v;
        __syncthreads();
    }
    int run = sums[t] - s;
    for (int i = 0; i < chunk; ++i) {
        offs[base + i] = run;
        run += lc[i];
        cnt[base + i] = 0;
    }
    if (t == 255) offs[N] = run;
}

__launch_bounds__(256)
__global__ void fill_edges_kernel(const int* __restrict__ idx, const int* __restrict__ offs,
                                  int* __restrict__ cursor, int* __restrict__ elist,
                                  int nsShift, int Nd, int E)
{
    int e = blockIdx.x * 256 + threadIdx.x;
    if (e >= E) return;
    int b = e >> nsShift;
    int d = b * Nd + idx[e];
    int pos = offs[d] + atomicAdd(&cursor[d], 1);
    elist[pos] = e;
}

// ---------------------------------------------------------------------------
// FUSED gather + LayerNorm: dv[row] accumulated in registers, then
// v_out[row] = LN(v_in[row] + gate*dv) * gamma + beta written directly.
// Also: ds[row] = sum c[e]; cursor[row] = 0 for next transition.
// v_out must not alias src_val (host ping-pongs buffers for prop transitions).
// ---------------------------------------------------------------------------
#define ECHUNK 512
__launch_bounds__(256)
__global__ void gather_ln_kernel(const float* __restrict__ src_val, const float* __restrict__ c,
                                 const int* __restrict__ elist, const int* __restrict__ offs,
                                 const float* __restrict__ v_in, float* __restrict__ v_out,
                                 float* __restrict__ ds, int* __restrict__ cursor,
                                 const float* __restrict__ gamma, const float* __restrict__ beta,
                                 const float* __restrict__ gatePtr, int gateIdx, int nsShift)
{
    __shared__ float sc[ECHUNK];
    __shared__ int   srow[ECHUNK];
    __shared__ float part[4][512];
    __shared__ float pcs[4];
    __shared__ float red[4];
    long row = blockIdx.x;
    int t = threadIdx.x, w = t >> 6, lane = t & 63;
    int e0 = offs[row], e1 = offs[row + 1];
    int mask = (1 << nsShift) - 1;
    int cb = lane * 8;
    float a[8] = {};
    float cs = 0.f;
    float gate = 1.f;
    if (gatePtr) gate = 1.f / (1.f + expf(-gatePtr[gateIdx]));

    for (int cstart = e0; cstart < e1; cstart += ECHUNK) {
        int cnt = min(e1 - cstart, ECHUNK);
        for (int i = t; i < cnt; i += 256) {
            int e = elist[cstart + i];
            sc[i] = c[e];
            int b = e >> nsShift;
            int s = (e & mask) >> 4;
            srow[i] = (b << (nsShift - 4)) + s;
        }
        __syncthreads();
        int j = w;
        for (; j + 12 < cnt; j += 16) {
            float c0 = sc[j], c1 = sc[j + 4], c2 = sc[j + 8], c3 = sc[j + 12];
            const float* p0 = src_val + ((long)srow[j]      << 9) + cb;
            const float* p1 = src_val + ((long)srow[j + 4]  << 9) + cb;
            const float* p2 = src_val + ((long)srow[j + 8]  << 9) + cb;
            const float* p3 = src_val + ((long)srow[j + 12] << 9) + cb;
            float4 x00 = *(const float4*)p0,       x01 = *(const float4*)(p0 + 4);
            float4 x10 = *(const float4*)p1,       x11 = *(const float4*)(p1 + 4);
            float4 x20 = *(const float4*)p2,       x21 = *(const float4*)(p2 + 4);
            float4 x30 = *(const float4*)p3,       x31 = *(const float4*)(p3 + 4);
            a[0] += c0 * x00.x + c1 * x10.x + c2 * x20.x + c3 * x30.x;
            a[1] += c0 * x00.y + c1 * x10.y + c2 * x20.y + c3 * x30.y;
            a[2] += c0 * x00.z + c1 * x10.z + c2 * x20.z + c3 * x30.z;
            a[3] += c0 * x00.w + c1 * x10.w + c2 * x20.w + c3 * x30.w;
            a[4] += c0 * x01.x + c1 * x11.x + c2 * x21.x + c3 * x31.x;
            a[5] += c0 * x01.y + c1 * x11.y + c2 * x21.y + c3 * x31.y;
            a[6] += c0 * x01.z + c1 * x11.z + c2 * x21.z + c3 * x31.z;
            a[7] += c0 * x01.w + c1 * x11.w + c2 * x21.w + c3 * x31.w;
            cs += c0 + c1 + c2 + c3;
        }
        for (; j < cnt; j += 4) {
            float cv = sc[j];
            const float* p = src_val + ((long)srow[j] << 9) + cb;
            float4 x0 = *(const float4*)p, x1 = *(const float4*)(p + 4);
            a[0] += cv * x0.x; a[1] += cv * x0.y; a[2] += cv * x0.z; a[3] += cv * x0.w;
            a[4] += cv * x1.x; a[5] += cv * x1.y; a[6] += cv * x1.z; a[7] += cv * x1.w;
            cs += cv;
        }
        __syncthreads();
    }
#pragma unroll
    for (int i = 0; i < 8; ++i) part[w][cb + i] = a[i];
    if (lane == 0) pcs[w] = cs;
    __syncthreads();
    float r0 = part[0][t] + part[1][t] + part[2][t] + part[3][t];
    float r1 = part[0][t + 256] + part[1][t + 256] + part[2][t + 256] + part[3][t + 256];
    if (t == 0) { ds[row] = pcs[0] + pcs[1] + pcs[2] + pcs[3]; cursor[row] = 0; }

    // ---- LayerNorm on x = v_in + gate*dv ----
    const float* vi = v_in + (row << 9);
    float x0 = vi[t]       + gate * r0;
    float x1 = vi[t + 256] + gate * r1;
    float s = x0 + x1;
    for (int off = 32; off; off >>= 1) s += __shfl_down(s, off);
    if ((t & 63) == 0) red[t >> 6] = s;
    __syncthreads();
    float mean = (red[0] + red[1] + red[2] + red[3]) * (1.f / 512.f);
    float d0 = x0 - mean, d1 = x1 - mean;
    float ss = d0 * d0 + d1 * d1;
    for (int off = 32; off; off >>= 1) ss += __shfl_down(ss, off);
    __syncthreads();
    if ((t & 63) == 0) red[t >> 6] = ss;
    __syncthreads();
    float var = (red[0] + red[1] + red[2] + red[3]) * (1.f / 512.f);
    float rstd = rsqrtf(var + 1e-5f);
    float* vo = v_out + (row << 9);
    vo[t]       = d0 * rstd * gamma[t]       + beta[t];
    vo[t + 256] = d1 * rstd * gamma[t + 256] + beta[t + 256];
}

// ---------------------------------------------------------------------------
// state' = sign(x)*softmax(|x|), x = s + gate*ds. One block per batch.
// ---------------------------------------------------------------------------
__launch_bounds__(256)
__global__ void apply_state_kernel(const float* __restrict__ s_in, const float* __restrict__ ds,
                                   float* __restrict__ s_out, int Nd,
                                   const float* __restrict__ gatePtr, int gateIdx)
{
    __shared__ float sh[1024];
    __shared__ float red[4];
    int b = blockIdx.x, t = threadIdx.x;
    float gate = 1.f;
    if (gatePtr) gate = 1.f / (1.f + expf(-gatePtr[gateIdx]));
    float lmax = 0.f;
    for (int i = t; i < Nd; i += 256) {
        float x = s_in[b * Nd + i] + gate * ds[b * Nd + i];
        sh[i] = x;
        lmax = fmaxf(lmax, fabsf(x));
    }
    for (int off = 32; off; off >>= 1) lmax = fmaxf(lmax, __shfl_down(lmax, off));
    if ((t & 63) == 0) red[t >> 6] = lmax;
    __syncthreads();
    float bmax = fmaxf(fmaxf(red[0], red[1]), fmaxf(red[2], red[3]));
    float lsum = 0.f;
    for (int i = t; i < Nd; i += 256) lsum += expf(fabsf(sh[i]) - bmax);
    for (int off = 32; off; off >>= 1) lsum += __shfl_down(lsum, off);
    __syncthreads();
    if ((t & 63) == 0) red[t >> 6] = lsum;
    __syncthreads();
    float inv = 1.f / (red[0] + red[1] + red[2] + red[3]);
    for (int i = t; i < Nd; i += 256) {
        float x = sh[i];
        float sgn = (x > 0.f) ? 1.f : ((x < 0.f) ? -1.f : 0.f);
        s_out[b * Nd + i] = sgn * expf(fabsf(x) - bmax) * inv;
    }
}

// ---------------------------------------------------------------------------
// Plain softmax over rows, in place (read phase).
// ---------------------------------------------------------------------------
__launch_bounds__(256)
__global__ void softmax_rows_kernel(float* __restrict__ logits, int Nd)
{
    __shared__ float red[4];
    long row = blockIdx.x;
    int t = threadIdx.x;
    float* L = logits + row * (long)Nd;
    float lmax = -INFINITY;
    for (int i = t; i < Nd; i += 256) lmax = fmaxf(lmax, L[i]);
    for (int off = 32; off; off >>= 1) lmax = fmaxf(lmax, __shfl_down(lmax, off));
    if ((t & 63) == 0) red[t >> 6] = lmax;
    __syncthreads();
    float bmax = fmaxf(fmaxf(red[0], red[1]), fmaxf(red[2], red[3]));
    float lsum = 0.f;
    for (int i = t; i < Nd; i += 256) lsum += expf(L[i] - bmax);
    for (int off = 32; off; off >>= 1) lsum += __shfl_down(lsum, off);
    __syncthreads();
    if ((t & 63) == 0) red[t >> 6] = lsum;
    __syncthreads();
    float inv = 1.f / (red[0] + red[1] + red[2] + red[3]);
    for (int i = t; i < Nd; i += 256) L[i] = expf(L[i] - bmax) * inv;
}

// ---------------------------------------------------------------------------
extern "C" void kernel_launch(void* const* d_in, const int* in_sizes, int n_in,
                              void* d_out, int out_size, void* d_ws, size_t ws_size,
                              hipStream_t stream)
{
    const int Bn = 4, T = 1024, D = 512, R = 64;
    const int S0 = 1024, S1 = 256, S2 = 64;
    const long RT = (long)D * R;
    const int MR = 3 * T + S0 + S1 + S2;   // read-phase combined rows = 4416

    const float* tok_val    = (const float*)d_in[0];
    const float* tok_state  = (const float*)d_in[1];
    const float* mem_state0 = (const float*)d_in[2];
    const float* mem_val0   = (const float*)d_in[3];
    const float* mem_state1 = (const float*)d_in[4];
    const float* mem_val1   = (const float*)d_in[5];
    const float* mem_state2 = (const float*)d_in[6];
    const float* mem_val2   = (const float*)d_in[7];
    const float* write_route= (const float*)d_in[8];
    const float* prop_route = (const float*)d_in[9];
    const float* level_route= (const float*)d_in[10];
    const float* skip_route = (const float*)d_in[11];
    const float* skip_gates = (const float*)d_in[12];
    const float* ln_gamma   = (const float*)d_in[13];
    const float* ln_beta    = (const float*)d_in[14];
    const float* read_route = (const float*)d_in[15];
    const float* read_proj  = (const float*)d_in[16];
    const float* read_gates = (const float*)d_in[17];
    float* out = (float*)d_out;

    // workspace carve
    float* p = (float*)d_ws;
    float* v0  = p; p += (long)Bn * S0 * D;
    float* v0b = p; p += (long)Bn * S0 * D;
    float* s0  = p; p += Bn * S0;
    float* v1  = p; p += (long)Bn * S1 * D;
    float* v1b = p; p += (long)Bn * S1 * D;
    float* s1  = p; p += Bn * S1;
    float* v2  = p; p += (long)Bn * S2 * D;
    float* v2b = p; p += (long)Bn * S2 * D;
    float* s2  = p; p += Bn * S2;
    float* qb  = p; p += (long)Bn * T * R;
    float* kb  = p; p += (long)Bn * S0 * R;
    float* rqk = p; p += (long)Bn * MR * R;         // read-phase combined q|k
    float* lb  = p; p += (long)Bn * T * S0;
    float* cbuf= p; p += (long)Bn * T * 16;
    int*   ib  = (int*)p; p += (long)Bn * T * 16;
    float* dsb = p; p += Bn * S0;
    float* rb  = p; p += (long)Bn * T * D;
    int* cntb  = (int*)p; p += Bn * S0;
    int* curb  = (int*)p; p += Bn * S0;
    int* offsb = (int*)p; p += Bn * S0 + 1;
    int* elistb= (int*)p; p += (long)Bn * T * 16;
    unsigned short* projT = (unsigned short*)p; p += (3 * (long)D * D) / 2 + 4;
    unsigned short* mvT0  = (unsigned short*)p; p += ((long)Bn * D * S0) / 2 + 4;
    unsigned short* mvT1  = (unsigned short*)p; p += ((long)Bn * D * S1) / 2 + 4;
    unsigned short* mvT2  = (unsigned short*)p; p += ((long)Bn * D * S2) / 2 + 4;
    float* partb = p; p += 8L * Bn * MR * R;        // split-K partials (36 MB)

    auto proj = [&](const float* Aq, const float* Ak, const float* Wq, const float* Wk,
                    int Mq, int Mk, long sAq, long sAk, float* qout, float* kout) {
        proj_splitk_kernel<<<dim3((Mq + Mk) / 64, 8, Bn), 256, 0, stream>>>(
            Aq, Ak, Wq, Wk, partb, Mq, Mk, sAq, sAk, Bn);
        int total4 = Bn * (Mq + Mk) * 16;
        proj_reduce_kernel<<<(total4 + 255) / 256, 256, 0, stream>>>(
            partb, qout, kout, Mq, Mk, Bn);
    };

    // one-time zero of cnt + cursor (workspace is re-poisoned before every call)
    hipMemsetAsync(cntb, 0, (size_t)2 * Bn * S0 * sizeof(int), stream);

    auto trans = [&](const float* sv, const float* ss, const float* dval,
                     const float* W, int Ns, int Nd,
                     const float* v_in, float* v_out, const float* sin, float* sout,
                     int lvl, const float* gptr, int gidx) {
        proj(sv, dval, W, W + RT, Ns, Nd, (long)Ns * D, (long)Nd * D, qb, kb);
        gemm_f32_nt_kernel<<<dim3(Ns / 64, Nd / 64, Bn), 256, 0, stream>>>(
            qb, kb, lb, Ns, Nd, R, (long)Ns * R, (long)Nd * R, (long)Ns * Nd, 0.125f);
        int nsLog = 31 - __builtin_clz((unsigned)Ns);
        int nsShift = nsLog + 4;
        int rowBlocks = Bn * Ns / 4;
        if (Nd == 1024)
            topk_coeff_kernel<16><<<rowBlocks, 256, 0, stream>>>(lb, ss, ib, cbuf, cntb, nsLog, Nd);
        else if (Nd == 256)
            topk_coeff_kernel<4><<<rowBlocks, 256, 0, stream>>>(lb, ss, ib, cbuf, cntb, nsLog, Nd);
        else
            topk_coeff_kernel<1><<<rowBlocks, 256, 0, stream>>>(lb, ss, ib, cbuf, cntb, nsLog, Nd);
        int E = Bn * Ns * 16;
        scan_kernel<<<1, 256, 0, stream>>>(cntb, offsb, Bn * Nd);
        fill_edges_kernel<<<(E + 255) / 256, 256, 0, stream>>>(ib, offsb, curb, elistb,
                                                               nsShift, Nd, E);
        gather_ln_kernel<<<Bn * Nd, 256, 0, stream>>>(sv, cbuf, elistb, offsb,
                                                      v_in, v_out, dsb, curb,
                                                      ln_gamma + lvl * D, ln_beta + lvl * D,
                                                      gptr, gidx, nsShift);
        apply_state_kernel<<<Bn, 256, 0, stream>>>(sin, dsb, sout, Nd, gptr, gidx);
    };

    // ---- level 0 ----
    trans(tok_val, tok_state, mem_val0, write_route, T, S0,
          mem_val0, v0, mem_state0, s0, 0, nullptr, 0);
    trans(v0, s0, v0, prop_route + 0 * 2 * RT, S0, S0,
          v0, v0b, s0, s0, 0, nullptr, 0);                    // out = v0b

    // ---- level 1 ----
    trans(v0b, s0, mem_val1, level_route + 0 * 2 * RT, S0, S1,
          mem_val1, v1, mem_state1, s1, 1, nullptr, 0);
    trans(tok_val, tok_state, v1, skip_route + 0 * 2 * RT, T, S1,
          v1, v1, s1, s1, 1, skip_gates, 0);                  // in-place ok (sv=tok_val)
    trans(v1, s1, v1, prop_route + 1 * 2 * RT, S1, S1,
          v1, v1b, s1, s1, 1, nullptr, 0);                    // out = v1b

    // ---- level 2 ----
    trans(v1b, s1, mem_val2, level_route + 1 * 2 * RT, S1, S2,
          mem_val2, v2, mem_state2, s2, 2, nullptr, 0);
    trans(v0b, s0, v2, skip_route + 1 * 2 * RT, S0, S2,
          v2, v2, s2, s2, 2, skip_gates, 1);                  // in-place ok (sv=v0b)
    trans(v2, s2, v2, prop_route + 2 * 2 * RT, S2, S2,
          v2, v2b, s2, s2, 2, nullptr, 0);                    // out = v2b

    // ---- read phase ----
    transpose_bf16_kernel<<<dim3(D / 32, D / 32, 3), dim3(32, 8), 0, stream>>>(
        read_proj, projT, D, D, (long)D * D, (long)D * D);
    transpose_mv_kernel<<<dim3(D / 32, (S0 + S1 + S2) / 32, Bn), dim3(32, 8), 0, stream>>>(
        v0b, v1b, v2b, mvT0, mvT1, mvT2);

    // all 6 read projections in one split-K launch + one flat reduce
    {
        ProjDesc d = {};
        const float* mvs[3] = { v0b, v1b, v2b };
        const int nds[3] = { S0, S1, S2 };
        int tiles = 0, roff = 0;
        for (int l = 0; l < 3; ++l) {        // q segments
            d.A[l] = tok_val; d.W[l] = read_route + (long)l * 2 * RT;
            d.sA[l] = (long)T * D; d.rowOff[l] = roff;
            d.tileOff[l] = tiles; tiles += T / 64; roff += T;
        }
        for (int l = 0; l < 3; ++l) {        // k segments
            d.A[3 + l] = mvs[l]; d.W[3 + l] = read_route + (long)l * 2 * RT + RT;
            d.sA[3 + l] = (long)nds[l] * D; d.rowOff[3 + l] = roff;
            d.tileOff[3 + l] = tiles; tiles += nds[l] / 64; roff += nds[l];
        }
        d.tileOff[6] = tiles;
        d.Mtot = MR;
        proj_splitk_multi_kernel<<<dim3(tiles, 8, Bn), 256, 0, stream>>>(d, partb, Bn);
        int total4 = Bn * MR * 16;
        proj_reduce_flat_kernel<<<(total4 + 255) / 256, 256, 0, stream>>>(partb, rqk, total4);
    }

    const unsigned short* mvTs[3] = { mvT0, mvT1, mvT2 };
    const int nds[3] = { S0, S1, S2 };
    int koff = 3 * T;
    for (int l = 0; l < 3; ++l) {
        int Nd = nds[l];
        gemm_f32_nt_kernel<<<dim3(T / 64, Nd / 64, Bn), 256, 0, stream>>>(
            rqk + (long)l * T * R, rqk + (long)koff * R, lb, T, Nd, R,
            (long)MR * R, (long)MR * R, (long)T * Nd, 0.125f);
        koff += Nd;
        softmax_rows_kernel<<<Bn * T, 256, 0, stream>>>(lb, Nd);
        gemm_mfma_kernel<<<dim3(T / 64, D / 64, Bn), 256, 0, stream>>>(
            lb, mvTs[l], rb, T, D, Nd, (long)T * Nd, (long)D * Nd, (long)T * D,
            1.f, nullptr, 0, 0.f, nullptr);
        // out = (l==0 ? tok_val : out) + sigmoid(gate_l) * r x proj_l
        gemm_mfma_kernel<<<dim3(T / 64, D / 64, Bn), 256, 0, stream>>>(
            rb, projT + (long)l * D * D, out, T, D, D,
            (long)T * D, 0, (long)T * D, 1.f, read_gates, l,
            1.f, (l == 0) ? tok_val : nullptr);
    }
}

// Round 13
// 868.435 us; speedup vs baseline: 1.1674x; 1.0467x over previous
//
#include <hip/hip_runtime.h>
#include <math.h>

typedef __attribute__((ext_vector_type(8))) short short8;
typedef __attribute__((ext_vector_type(4))) float floatx4;

static __device__ __forceinline__ short f2bf(float f) {
    union { float f; unsigned u; } c; c.f = f;
    unsigned r = c.u + 0x7FFF + ((c.u >> 16) & 1);   // RNE
    return (short)(r >> 16);
}

// ---------------------------------------------------------------------------
// fp32 GEMM: C[b] = alpha * A[b](M,K) x B[b](N,K)^T. 64x64 tile, 4x4 micro.
// (transition logits path — fp32-exact for top-k)
// ---------------------------------------------------------------------------
__launch_bounds__(256)
__global__ void gemm_f32_nt_kernel(const float* __restrict__ A, const float* __restrict__ B,
                                   float* __restrict__ C, int M, int N, int K,
                                   long sA, long sB, long sC, float alpha)
{
    __shared__ float As[32][68];   // [k][m]
    __shared__ float Bs[32][68];   // [k][n]
    const float* Ab = A + (long)blockIdx.z * sA;
    const float* Bb = B + (long)blockIdx.z * sB;
    float* Cb = C + (long)blockIdx.z * sC;
    int m0 = blockIdx.x * 64, n0 = blockIdx.y * 64;
    int t = threadIdx.x;
    int tx = t & 15, ty = t >> 4;
    float acc[4][4] = {};

    for (int k0 = 0; k0 < K; k0 += 32) {
        {
            int m = t >> 3;
            int kk = (t & 7) * 4;
#pragma unroll
            for (int h = 0; h < 2; ++h) {
                float4 v = *(const float4*)&Ab[(long)(m0 + m + 32 * h) * K + k0 + kk];
                As[kk + 0][m + 32 * h] = v.x; As[kk + 1][m + 32 * h] = v.y;
                As[kk + 2][m + 32 * h] = v.z; As[kk + 3][m + 32 * h] = v.w;
            }
        }
        {
            int n = t >> 3;
            int kk = (t & 7) * 4;
#pragma unroll
            for (int h = 0; h < 2; ++h) {
                float4 v = *(const float4*)&Bb[(long)(n0 + n + 32 * h) * K + k0 + kk];
                Bs[kk + 0][n + 32 * h] = v.x; Bs[kk + 1][n + 32 * h] = v.y;
                Bs[kk + 2][n + 32 * h] = v.z; Bs[kk + 3][n + 32 * h] = v.w;
            }
        }
        __syncthreads();
#pragma unroll 4
        for (int k = 0; k < 32; ++k) {
            float4 a = *(const float4*)&As[k][ty * 4];
            float4 b = *(const float4*)&Bs[k][tx * 4];
            float av[4] = { a.x, a.y, a.z, a.w };
            float bv[4] = { b.x, b.y, b.z, b.w };
#pragma unroll
            for (int i = 0; i < 4; ++i)
#pragma unroll
                for (int j = 0; j < 4; ++j) acc[i][j] += av[i] * bv[j];
        }
        __syncthreads();
    }
#pragma unroll
    for (int i = 0; i < 4; ++i) {
        float4 r;
        r.x = alpha * acc[i][0]; r.y = alpha * acc[i][1];
        r.z = alpha * acc[i][2]; r.w = alpha * acc[i][3];
        *(float4*)&Cb[(long)(m0 + ty * 4 + i) * N + n0 + tx * 4] = r;
    }
}

// ---------------------------------------------------------------------------
// Segmented read-phase logits GEMM: 3 levels in one launch (y-tiles 16|4|1).
// C_l = 0.125 * q(T,64) x k_l(Nd_l,64)^T, all operands in rqk.
// ---------------------------------------------------------------------------
struct LogitsSeg {
    const float* A[3];
    const float* B[3];
    float* C[3];
    long sC[3];
    int Nd[3];
    int yOff[4];
    long sAB;
};

__launch_bounds__(256)
__global__ void gemm_logits_seg_kernel(LogitsSeg d)
{
    __shared__ float As[32][68];
    __shared__ float Bs[32][68];
    int yt = blockIdx.y;
    int seg = 0;
    while (yt >= d.yOff[seg + 1]) ++seg;
    int n0 = (yt - d.yOff[seg]) * 64;
    const float* Ab = d.A[seg] + (long)blockIdx.z * d.sAB;
    const float* Bb = d.B[seg] + (long)blockIdx.z * d.sAB;
    float* Cb = d.C[seg] + (long)blockIdx.z * d.sC[seg];
    int N = d.Nd[seg];
    int m0 = blockIdx.x * 64;
    int t = threadIdx.x, tx = t & 15, ty = t >> 4;
    float acc[4][4] = {};
    const int K = 64;

    for (int k0 = 0; k0 < K; k0 += 32) {
        {
            int m = t >> 3;
            int kk = (t & 7) * 4;
#pragma unroll
            for (int h = 0; h < 2; ++h) {
                float4 v = *(const float4*)&Ab[(long)(m0 + m + 32 * h) * K + k0 + kk];
                As[kk + 0][m + 32 * h] = v.x; As[kk + 1][m + 32 * h] = v.y;
                As[kk + 2][m + 32 * h] = v.z; As[kk + 3][m + 32 * h] = v.w;
            }
        }
        {
            int n = t >> 3;
            int kk = (t & 7) * 4;
#pragma unroll
            for (int h = 0; h < 2; ++h) {
                float4 v = *(const float4*)&Bb[(long)(n0 + n + 32 * h) * K + k0 + kk];
                Bs[kk + 0][n + 32 * h] = v.x; Bs[kk + 1][n + 32 * h] = v.y;
                Bs[kk + 2][n + 32 * h] = v.z; Bs[kk + 3][n + 32 * h] = v.w;
            }
        }
        __syncthreads();
#pragma unroll 4
        for (int k = 0; k < 32; ++k) {
            float4 a = *(const float4*)&As[k][ty * 4];
            float4 b = *(const float4*)&Bs[k][tx * 4];
            float av[4] = { a.x, a.y, a.z, a.w };
            float bv[4] = { b.x, b.y, b.z, b.w };
#pragma unroll
            for (int i = 0; i < 4; ++i)
#pragma unroll
                for (int j = 0; j < 4; ++j) acc[i][j] += av[i] * bv[j];
        }
        __syncthreads();
    }
#pragma unroll
    for (int i = 0; i < 4; ++i) {
        float4 r;
        r.x = 0.125f * acc[i][0]; r.y = 0.125f * acc[i][1];
        r.z = 0.125f * acc[i][2]; r.w = 0.125f * acc[i][3];
        *(float4*)&Cb[(long)(m0 + ty * 4 + i) * N + n0 + tx * 4] = r;
    }
}

// ---------------------------------------------------------------------------
// Split-K q/k projection for transitions (proven round-9 path).
// ---------------------------------------------------------------------------
__launch_bounds__(256)
__global__ void proj_splitk_kernel(const float* __restrict__ Aq, const float* __restrict__ Ak,
                                   const float* __restrict__ Wq, const float* __restrict__ Wk,
                                   float* __restrict__ part,
                                   int Mq, int Mk, long sAq, long sAk, int Bn)
{
    __shared__ float As[32][68];
    __shared__ float Bs[32][68];
    int mqT = Mq >> 6;
    int xt = blockIdx.x, s = blockIdx.y, b = blockIdx.z;
    const float* A; const float* W; int row0, orow;
    if (xt < mqT) { A = Aq + (long)b * sAq; W = Wq; row0 = xt * 64; orow = row0; }
    else { A = Ak + (long)b * sAk; W = Wk; row0 = (xt - mqT) * 64; orow = Mq + row0; }
    int t = threadIdx.x, tx = t & 15, ty = t >> 4;
    float acc[4][4] = {};
    int kbase = s * 64;

    for (int k0 = kbase; k0 < kbase + 64; k0 += 32) {
        {
            int m = t >> 3;
            int kk = (t & 7) * 4;
#pragma unroll
            for (int h = 0; h < 2; ++h) {
                float4 v = *(const float4*)&A[(long)(row0 + m + 32 * h) * 512 + k0 + kk];
                As[kk + 0][m + 32 * h] = v.x; As[kk + 1][m + 32 * h] = v.y;
                As[kk + 2][m + 32 * h] = v.z; As[kk + 3][m + 32 * h] = v.w;
            }
        }
        {
            int kk = t >> 3;
            int nn = (t & 7) * 8;
            float4 v0 = *(const float4*)&W[(long)(k0 + kk) * 64 + nn];
            float4 v1 = *(const float4*)&W[(long)(k0 + kk) * 64 + nn + 4];
            *(float4*)&Bs[kk][nn] = v0;
            *(float4*)&Bs[kk][nn + 4] = v1;
        }
        __syncthreads();
#pragma unroll 4
        for (int k = 0; k < 32; ++k) {
            float4 a = *(const float4*)&As[k][ty * 4];
            float4 b2 = *(const float4*)&Bs[k][tx * 4];
            float av[4] = { a.x, a.y, a.z, a.w };
            float bv[4] = { b2.x, b2.y, b2.z, b2.w };
#pragma unroll
            for (int i = 0; i < 4; ++i)
#pragma unroll
                for (int j = 0; j < 4; ++j) acc[i][j] += av[i] * bv[j];
        }
        __syncthreads();
    }
    long base = ((long)(s * Bn + b) * (Mq + Mk) + orow) * 64;
#pragma unroll
    for (int i = 0; i < 4; ++i)
        *(float4*)&part[base + (long)(ty * 4 + i) * 64 + tx * 4] =
            make_float4(acc[i][0], acc[i][1], acc[i][2], acc[i][3]);
}

__launch_bounds__(256)
__global__ void proj_reduce_kernel(const float* __restrict__ part,
                                   float* __restrict__ qout, float* __restrict__ kout,
                                   int Mq, int Mk, int Bn)
{
    int idx = blockIdx.x * 256 + threadIdx.x;
    int size4b = (Mq + Mk) * 16;
    int total4 = Bn * size4b;
    if (idx >= total4) return;
    const float4* p4 = (const float4*)part;
    long stride4 = (long)total4;
    float4 s = p4[idx];
#pragma unroll
    for (int ss = 1; ss < 8; ++ss) {
        float4 v = p4[ss * stride4 + idx];
        s.x += v.x; s.y += v.y; s.z += v.z; s.w += v.w;
    }
    int b = idx / size4b;
    int rem = idx - b * size4b;
    int r = rem >> 4;
    int c4 = rem & 15;
    if (r < Mq) ((float4*)qout)[((long)b * Mq + r) * 16 + c4] = s;
    else        ((float4*)kout)[((long)b * Mk + (r - Mq)) * 16 + c4] = s;
}

// ---------------------------------------------------------------------------
// Multi-segment split-K projection (read phase): 6 segments in one launch.
// ---------------------------------------------------------------------------
struct ProjDesc {
    const float* A[6];
    const float* W[6];
    long  sA[6];
    int   tileOff[7];
    int   rowOff[6];
    int   Mtot;
};

__launch_bounds__(256)
__global__ void proj_splitk_multi_kernel(ProjDesc d, float* __restrict__ part, int Bn)
{
    __shared__ float As[32][68];
    __shared__ float Bs[32][68];
    int xt = blockIdx.x, s = blockIdx.y, b = blockIdx.z;
    int seg = 0;
    while (xt >= d.tileOff[seg + 1]) ++seg;
    int row0 = (xt - d.tileOff[seg]) * 64;
    const float* A = d.A[seg] + (long)b * d.sA[seg];
    const float* W = d.W[seg];
    int orow = d.rowOff[seg] + row0;
    int t = threadIdx.x, tx = t & 15, ty = t >> 4;
    float acc[4][4] = {};
    int kbase = s * 64;

    for (int k0 = kbase; k0 < kbase + 64; k0 += 32) {
        {
            int m = t >> 3;
            int kk = (t & 7) * 4;
#pragma unroll
            for (int h = 0; h < 2; ++h) {
                float4 v = *(const float4*)&A[(long)(row0 + m + 32 * h) * 512 + k0 + kk];
                As[kk + 0][m + 32 * h] = v.x; As[kk + 1][m + 32 * h] = v.y;
                As[kk + 2][m + 32 * h] = v.z; As[kk + 3][m + 32 * h] = v.w;
            }
        }
        {
            int kk = t >> 3;
            int nn = (t & 7) * 8;
            float4 v0 = *(const float4*)&W[(long)(k0 + kk) * 64 + nn];
            float4 v1 = *(const float4*)&W[(long)(k0 + kk) * 64 + nn + 4];
            *(float4*)&Bs[kk][nn] = v0;
            *(float4*)&Bs[kk][nn + 4] = v1;
        }
        __syncthreads();
#pragma unroll 4
        for (int k = 0; k < 32; ++k) {
            float4 a = *(const float4*)&As[k][ty * 4];
            float4 b2 = *(const float4*)&Bs[k][tx * 4];
            float av[4] = { a.x, a.y, a.z, a.w };
            float bv[4] = { b2.x, b2.y, b2.z, b2.w };
#pragma unroll
            for (int i = 0; i < 4; ++i)
#pragma unroll
                for (int j = 0; j < 4; ++j) acc[i][j] += av[i] * bv[j];
        }
        __syncthreads();
    }
    long base = ((long)(s * Bn + b) * d.Mtot + orow) * 64;
#pragma unroll
    for (int i = 0; i < 4; ++i)
        *(float4*)&part[base + (long)(ty * 4 + i) * 64 + tx * 4] =
            make_float4(acc[i][0], acc[i][1], acc[i][2], acc[i][3]);
}

__launch_bounds__(256)
__global__ void proj_reduce_flat_kernel(const float* __restrict__ part, float* __restrict__ outp,
                                        int total4)
{
    int idx = blockIdx.x * 256 + threadIdx.x;
    if (idx >= total4) return;
    const float4* p4 = (const float4*)part;
    float4 s = p4[idx];
#pragma unroll
    for (int ss = 1; ss < 8; ++ss) {
        float4 v = p4[(long)ss * total4 + idx];
        s.x += v.x; s.y += v.y; s.z += v.z; s.w += v.w;
    }
    ((float4*)outp)[idx] = s;
}

// ---------------------------------------------------------------------------
// bf16 MFMA GEMM: C[b](M,N) = alpha * A[b](M,K,fp32) x Bt[b](N,K,bf16) (+ initC)
// ---------------------------------------------------------------------------
__launch_bounds__(256)
__global__ void gemm_mfma_kernel(const float* __restrict__ A, const unsigned short* __restrict__ Bt,
                                 float* __restrict__ C, int M, int N, int K,
                                 long sA, long sBt, long sC,
                                 float alpha, const float* __restrict__ initC)
{
    __shared__ short As[2048];
    __shared__ short Bs[2048];
    const float* Ab = A + (long)blockIdx.z * sA;
    const unsigned short* Bb = Bt + (long)blockIdx.z * sBt;
    float* Cb = C + (long)blockIdx.z * sC;
    const float* Ib = initC ? initC + (long)blockIdx.z * sC : nullptr;
    int m0 = blockIdx.x * 64, n0 = blockIdx.y * 64;
    int t = threadIdx.x, wave = t >> 6, lane = t & 63;
    int sr = wave * 16 + (lane & 15);
    int sk = (lane >> 4) * 8;
    floatx4 acc[4] = {};

    for (int k0 = 0; k0 < K; k0 += 32) {
        const float* ap = &Ab[(long)(m0 + sr) * K + k0 + sk];
        float4 f0 = *(const float4*)ap;
        float4 f1 = *(const float4*)(ap + 4);
        short8 av;
        av[0] = f2bf(f0.x); av[1] = f2bf(f0.y); av[2] = f2bf(f0.z); av[3] = f2bf(f0.w);
        av[4] = f2bf(f1.x); av[5] = f2bf(f1.y); av[6] = f2bf(f1.z); av[7] = f2bf(f1.w);
        short8 bv = *(const short8*)&Bb[(long)(n0 + sr) * K + k0 + sk];
        ((short8*)As)[t] = av;
        ((short8*)Bs)[t] = bv;
        __syncthreads();
        short8 bf = ((short8*)Bs)[wave * 64 + lane];
#pragma unroll
        for (int mt = 0; mt < 4; ++mt) {
            short8 af = ((short8*)As)[mt * 64 + lane];
            acc[mt] = __builtin_amdgcn_mfma_f32_16x16x32_bf16(af, bf, acc[mt], 0, 0, 0);
        }
        __syncthreads();
    }
    int col = n0 + wave * 16 + (lane & 15);
#pragma unroll
    for (int mt = 0; mt < 4; ++mt) {
#pragma unroll
        for (int r = 0; r < 4; ++r) {
            int row = m0 + mt * 16 + (lane >> 4) * 4 + r;
            long off = (long)row * N + col;
            float v = alpha * acc[mt][r];
            if (Ib) v += Ib[off];
            Cb[off] = v;
        }
    }
}

// ---------------------------------------------------------------------------
// Segmented attn x mv MFMA (read phase): 3 levels in one launch.
// r_cat[:, l*512 + :] = attn_l(T,Nd_l) x mv_l(Nd_l,512). ldc = 1536.
// ---------------------------------------------------------------------------
struct AttnSeg {
    const float* A[3];            // lb_l
    const unsigned short* Bt[3];  // mvT_l (512, Nd_l)
    int K[3];                     // Nd_l
    long sA[3], sBt[3];
};

__launch_bounds__(256)
__global__ void gemm_mfma_attn_seg_kernel(AttnSeg d, float* __restrict__ rcat, long sC)
{
    __shared__ short As[2048];
    __shared__ short Bs[2048];
    int lvl = blockIdx.x >> 4;
    int m0 = (blockIdx.x & 15) * 64;
    int n0 = blockIdx.y * 64;
    int K = d.K[lvl];
    const float* Ab = d.A[lvl] + (long)blockIdx.z * d.sA[lvl];
    const unsigned short* Bb = d.Bt[lvl] + (long)blockIdx.z * d.sBt[lvl];
    float* Cb = rcat + (long)blockIdx.z * sC + lvl * 512;
    int t = threadIdx.x, wave = t >> 6, lane = t & 63;
    int sr = wave * 16 + (lane & 15);
    int sk = (lane >> 4) * 8;
    floatx4 acc[4] = {};

    for (int k0 = 0; k0 < K; k0 += 32) {
        const float* ap = &Ab[(long)(m0 + sr) * K + k0 + sk];
        float4 f0 = *(const float4*)ap;
        float4 f1 = *(const float4*)(ap + 4);
        short8 av;
        av[0] = f2bf(f0.x); av[1] = f2bf(f0.y); av[2] = f2bf(f0.z); av[3] = f2bf(f0.w);
        av[4] = f2bf(f1.x); av[5] = f2bf(f1.y); av[6] = f2bf(f1.z); av[7] = f2bf(f1.w);
        short8 bv = *(const short8*)&Bb[(long)(n0 + sr) * K + k0 + sk];
        ((short8*)As)[t] = av;
        ((short8*)Bs)[t] = bv;
        __syncthreads();
        short8 bf = ((short8*)Bs)[wave * 64 + lane];
#pragma unroll
        for (int mt = 0; mt < 4; ++mt) {
            short8 af = ((short8*)As)[mt * 64 + lane];
            acc[mt] = __builtin_amdgcn_mfma_f32_16x16x32_bf16(af, bf, acc[mt], 0, 0, 0);
        }
        __syncthreads();
    }
    int col = n0 + wave * 16 + (lane & 15);
#pragma unroll
    for (int mt = 0; mt < 4; ++mt) {
#pragma unroll
        for (int r = 0; r < 4; ++r) {
            int row = m0 + mt * 16 + (lane >> 4) * 4 + r;
            Cb[(long)row * 1536 + col] = acc[mt][r];
        }
    }
}

// ---------------------------------------------------------------------------
// Gated concat transpose of read_proj: Pcat^T[n][l*512+d'] = bf16(g_l*P_l[d'][n]).
// ---------------------------------------------------------------------------
__global__ void transpose_proj_gated_kernel(const float* __restrict__ proj,
                                            const float* __restrict__ gates,
                                            unsigned short* __restrict__ outp)
{
    __shared__ float tile[32][33];
    int l = blockIdx.z;
    float g = 1.f / (1.f + expf(-gates[l]));
    const float* I = proj + (long)l * 512 * 512;
    int n0 = blockIdx.x * 32, d0 = blockIdx.y * 32;
    int tx = threadIdx.x, ty = threadIdx.y;
#pragma unroll
    for (int i = 0; i < 32; i += 8)
        tile[ty + i][tx] = I[(long)(d0 + ty + i) * 512 + n0 + tx];
    __syncthreads();
#pragma unroll
    for (int i = 0; i < 32; i += 8)
        outp[(long)(n0 + ty + i) * 1536 + l * 512 + d0 + tx] =
            (unsigned short)f2bf(g * tile[tx][ty + i]);
}

// Batched transpose of the 3 mv levels in one launch. y-tiles: 32|8|2.
__global__ void transpose_mv_kernel(const float* __restrict__ mv0, const float* __restrict__ mv1,
                                    const float* __restrict__ mv2,
                                    unsigned short* __restrict__ o0, unsigned short* __restrict__ o1,
                                    unsigned short* __restrict__ o2)
{
    __shared__ float tile[32][33];
    int yt = blockIdx.y;
    const float* in; unsigned short* out; int Nd, r0t;
    if (yt < 32)      { in = mv0; out = o0; Nd = 1024; r0t = yt; }
    else if (yt < 40) { in = mv1; out = o1; Nd = 256;  r0t = yt - 32; }
    else              { in = mv2; out = o2; Nd = 64;   r0t = yt - 40; }
    const float* I = in + (long)blockIdx.z * Nd * 512;
    unsigned short* O = out + (long)blockIdx.z * 512 * Nd;
    int c0 = blockIdx.x * 32, r0 = r0t * 32;
    int tx = threadIdx.x, ty = threadIdx.y;
#pragma unroll
    for (int i = 0; i < 32; i += 8)
        tile[ty + i][tx] = I[(long)(r0 + ty + i) * 512 + c0 + tx];
    __syncthreads();
#pragma unroll
    for (int i = 0; i < 32; i += 8)
        O[(long)(c0 + ty + i) * Nd + r0 + tx] = (unsigned short)f2bf(tile[tx][ty + i]);
}

// ---------------------------------------------------------------------------
// Exact top-16 per row + fused CSR count. 4 rows/block (one wave per row).
// ---------------------------------------------------------------------------
template<int CNT>
__launch_bounds__(256)
__global__ void topk_coeff_kernel(const float* __restrict__ logits,
                                  const float* __restrict__ state,
                                  int* __restrict__ idx_out, float* __restrict__ c_out,
                                  int* __restrict__ cnt, int nsLog, int Nd)
{
    int wave = threadIdx.x >> 6, lane = threadIdx.x & 63;
    long row = (long)blockIdx.x * 4 + wave;
    const float* L = logits + row * Nd;
    float vreg[CNT];
    if (CNT >= 4) {
#pragma unroll
        for (int q = 0; q < CNT / 4; ++q) {
            float4 v = *(const float4*)&L[lane * CNT + q * 4];
            vreg[q * 4 + 0] = v.x; vreg[q * 4 + 1] = v.y;
            vreg[q * 4 + 2] = v.z; vreg[q * 4 + 3] = v.w;
        }
    } else {
#pragma unroll
        for (int tt = 0; tt < CNT; ++tt) vreg[tt] = L[lane * CNT + tt];
    }

    float m = 0.f, sum = 0.f;
    float myv = 0.f; int myi = 0;
#pragma unroll
    for (int it = 0; it < 16; ++it) {
        float best = -INFINITY; int bidx = 0x7fffffff;
#pragma unroll
        for (int tt = 0; tt < CNT; ++tt) {
            if (vreg[tt] > best) { best = vreg[tt]; bidx = lane * CNT + tt; }
        }
#pragma unroll
        for (int off = 32; off; off >>= 1) {
            float ov = __shfl_down(best, off);
            int   oi = __shfl_down(bidx, off);
            if (ov > best || (ov == best && oi < bidx)) { best = ov; bidx = oi; }
        }
        best = __shfl(best, 0);
        bidx = __shfl(bidx, 0);
        if (it == lane) { myv = best; myi = bidx; }
        float ab = fabsf(best);
        float nm = fmaxf(m, ab);
        sum = sum * expf(m - nm) + expf(ab - nm);
        m = nm;
#pragma unroll
        for (int tt = 0; tt < CNT; ++tt)
            if (lane * CNT + tt == bidx) vreg[tt] = -INFINITY;
    }
    if (lane < 16) {
        float st = state[row];
        float sp = fmaxf(st, 0.f) + log1pf(expf(-fabsf(st)));
        float sgn = (myv > 0.f) ? 1.f : ((myv < 0.f) ? -1.f : 0.f);
        float w = expf(fabsf(myv) - m) / sum;
        c_out[row * 16 + lane] = sgn * w * sp;
        idx_out[row * 16 + lane] = myi;
        int b = (int)(row >> nsLog);
        atomicAdd(&cnt[b * Nd + myi], 1);
    }
}

// Single-block exclusive scan; self-zeroes cnt (next Nd <= current Nd).
__launch_bounds__(256)
__global__ void scan_kernel(int* __restrict__ cnt, int* __restrict__ offs, int N)
{
    __shared__ int sums[256];
    int t = threadIdx.x;
    int chunk = N >> 8;
    int base = t * chunk;
    int lc[16];
    int s = 0;
    for (int i = 0; i < chunk; ++i) { lc[i] = cnt[base + i]; s += lc[i]; }
    sums[t] = s;
    __syncthreads();
    for (int off = 1; off < 256; off <<= 1) {
        int v = (t >= off) ? sums[t - off] : 0;
        __syncthreads();
        sums[t] += v;
        __syncthreads();
    }
    int run = sums[t] - s;
    for (int i = 0; i < chunk; ++i) {
        offs[base + i] = run;
        run += lc[i];
        cnt[base + i] = 0;
    }
    if (t == 255) offs[N] = run;
}

__launch_bounds__(256)
__global__ void fill_edges_kernel(const int* __restrict__ idx, const int* __restrict__ offs,
                                  int* __restrict__ cursor, int* __restrict__ elist,
                                  int nsShift, int Nd, int E)
{
    int e = blockIdx.x * 256 + threadIdx.x;
    if (e >= E) return;
    int b = e >> nsShift;
    int d = b * Nd + idx[e];
    int pos = offs[d] + atomicAdd(&cursor[d], 1);
    elist[pos] = e;
}

// ---------------------------------------------------------------------------
// FUSED gather + LayerNorm (proven): ds by-product, cursor self-clean.
// ---------------------------------------------------------------------------
#define ECHUNK 512
__launch_bounds__(256)
__global__ void gather_ln_kernel(const float* __restrict__ src_val, const float* __restrict__ c,
                                 const int* __restrict__ elist, const int* __restrict__ offs,
                                 const float* __restrict__ v_in, float* __restrict__ v_out,
                                 float* __restrict__ ds, int* __restrict__ cursor,
                                 const float* __restrict__ gamma, const float* __restrict__ beta,
                                 const float* __restrict__ gatePtr, int gateIdx, int nsShift)
{
    __shared__ float sc[ECHUNK];
    __shared__ int   srow[ECHUNK];
    __shared__ float part[4][512];
    __shared__ float pcs[4];
    __shared__ float red[4];
    long row = blockIdx.x;
    int t = threadIdx.x, w = t >> 6, lane = t & 63;
    int e0 = offs[row], e1 = offs[row + 1];
    int mask = (1 << nsShift) - 1;
    int cb = lane * 8;
    float a[8] = {};
    float cs = 0.f;
    float gate = 1.f;
    if (gatePtr) gate = 1.f / (1.f + expf(-gatePtr[gateIdx]));

    for (int cstart = e0; cstart < e1; cstart += ECHUNK) {
        int cnt = min(e1 - cstart, ECHUNK);
        for (int i = t; i < cnt; i += 256) {
            int e = elist[cstart + i];
            sc[i] = c[e];
            int b = e >> nsShift;
            int s = (e & mask) >> 4;
            srow[i] = (b << (nsShift - 4)) + s;
        }
        __syncthreads();
        int j = w;
        for (; j + 12 < cnt; j += 16) {
            float c0 = sc[j], c1 = sc[j + 4], c2 = sc[j + 8], c3 = sc[j + 12];
            const float* p0 = src_val + ((long)srow[j]      << 9) + cb;
            const float* p1 = src_val + ((long)srow[j + 4]  << 9) + cb;
            const float* p2 = src_val + ((long)srow[j + 8]  << 9) + cb;
            const float* p3 = src_val + ((long)srow[j + 12] << 9) + cb;
            float4 x00 = *(const float4*)p0,       x01 = *(const float4*)(p0 + 4);
            float4 x10 = *(const float4*)p1,       x11 = *(const float4*)(p1 + 4);
            float4 x20 = *(const float4*)p2,       x21 = *(const float4*)(p2 + 4);
            float4 x30 = *(const float4*)p3,       x31 = *(const float4*)(p3 + 4);
            a[0] += c0 * x00.x + c1 * x10.x + c2 * x20.x + c3 * x30.x;
            a[1] += c0 * x00.y + c1 * x10.y + c2 * x20.y + c3 * x30.y;
            a[2] += c0 * x00.z + c1 * x10.z + c2 * x20.z + c3 * x30.z;
            a[3] += c0 * x00.w + c1 * x10.w + c2 * x20.w + c3 * x30.w;
            a[4] += c0 * x01.x + c1 * x11.x + c2 * x21.x + c3 * x31.x;
            a[5] += c0 * x01.y + c1 * x11.y + c2 * x21.y + c3 * x31.y;
            a[6] += c0 * x01.z + c1 * x11.z + c2 * x21.z + c3 * x31.z;
            a[7] += c0 * x01.w + c1 * x11.w + c2 * x21.w + c3 * x31.w;
            cs += c0 + c1 + c2 + c3;
        }
        for (; j < cnt; j += 4) {
            float cv = sc[j];
            const float* p = src_val + ((long)srow[j] << 9) + cb;
            float4 x0 = *(const float4*)p, x1 = *(const float4*)(p + 4);
            a[0] += cv * x0.x; a[1] += cv * x0.y; a[2] += cv * x0.z; a[3] += cv * x0.w;
            a[4] += cv * x1.x; a[5] += cv * x1.y; a[6] += cv * x1.z; a[7] += cv * x1.w;
            cs += cv;
        }
        __syncthreads();
    }
#pragma unroll
    for (int i = 0; i < 8; ++i) part[w][cb + i] = a[i];
    if (lane == 0) pcs[w] = cs;
    __syncthreads();
    float r0 = part[0][t] + part[1][t] + part[2][t] + part[3][t];
    float r1 = part[0][t + 256] + part[1][t + 256] + part[2][t + 256] + part[3][t + 256];
    if (t == 0) { ds[row] = pcs[0] + pcs[1] + pcs[2] + pcs[3]; cursor[row] = 0; }

    const float* vi = v_in + (row << 9);
    float x0 = vi[t]       + gate * r0;
    float x1 = vi[t + 256] + gate * r1;
    float s = x0 + x1;
    for (int off = 32; off; off >>= 1) s += __shfl_down(s, off);
    if ((t & 63) == 0) red[t >> 6] = s;
    __syncthreads();
    float mean = (red[0] + red[1] + red[2] + red[3]) * (1.f / 512.f);
    float d0 = x0 - mean, d1 = x1 - mean;
    float ss = d0 * d0 + d1 * d1;
    for (int off = 32; off; off >>= 1) ss += __shfl_down(ss, off);
    __syncthreads();
    if ((t & 63) == 0) red[t >> 6] = ss;
    __syncthreads();
    float var = (red[0] + red[1] + red[2] + red[3]) * (1.f / 512.f);
    float rstd = rsqrtf(var + 1e-5f);
    float* vo = v_out + (row << 9);
    vo[t]       = d0 * rstd * gamma[t]       + beta[t];
    vo[t + 256] = d1 * rstd * gamma[t + 256] + beta[t + 256];
}

// ---------------------------------------------------------------------------
// state' = sign(x)*softmax(|x|), x = s + gate*ds. One block per batch.
// ---------------------------------------------------------------------------
__launch_bounds__(256)
__global__ void apply_state_kernel(const float* __restrict__ s_in, const float* __restrict__ ds,
                                   float* __restrict__ s_out, int Nd,
                                   const float* __restrict__ gatePtr, int gateIdx)
{
    __shared__ float sh[1024];
    __shared__ float red[4];
    int b = blockIdx.x, t = threadIdx.x;
    float gate = 1.f;
    if (gatePtr) gate = 1.f / (1.f + expf(-gatePtr[gateIdx]));
    float lmax = 0.f;
    for (int i = t; i < Nd; i += 256) {
        float x = s_in[b * Nd + i] + gate * ds[b * Nd + i];
        sh[i] = x;
        lmax = fmaxf(lmax, fabsf(x));
    }
    for (int off = 32; off; off >>= 1) lmax = fmaxf(lmax, __shfl_down(lmax, off));
    if ((t & 63) == 0) red[t >> 6] = lmax;
    __syncthreads();
    float bmax = fmaxf(fmaxf(red[0], red[1]), fmaxf(red[2], red[3]));
    float lsum = 0.f;
    for (int i = t; i < Nd; i += 256) lsum += expf(fabsf(sh[i]) - bmax);
    for (int off = 32; off; off >>= 1) lsum += __shfl_down(lsum, off);
    __syncthreads();
    if ((t & 63) == 0) red[t >> 6] = lsum;
    __syncthreads();
    float inv = 1.f / (red[0] + red[1] + red[2] + red[3]);
    for (int i = t; i < Nd; i += 256) {
        float x = sh[i];
        float sgn = (x > 0.f) ? 1.f : ((x < 0.f) ? -1.f : 0.f);
        s_out[b * Nd + i] = sgn * expf(fabsf(x) - bmax) * inv;
    }
}

// ---------------------------------------------------------------------------
// Segmented softmax over rows (read phase): grid (Bn*T, 3).
// ---------------------------------------------------------------------------
__launch_bounds__(256)
__global__ void softmax_seg_kernel(float* __restrict__ lb0, float* __restrict__ lb1,
                                   float* __restrict__ lb2)
{
    __shared__ float red[4];
    int lvl = blockIdx.y;
    int Nd = (lvl == 0) ? 1024 : (lvl == 1) ? 256 : 64;
    float* base = (lvl == 0) ? lb0 : (lvl == 1) ? lb1 : lb2;
    long row = blockIdx.x;
    int t = threadIdx.x;
    float* L = base + row * (long)Nd;
    float lmax = -INFINITY;
    for (int i = t; i < Nd; i += 256) lmax = fmaxf(lmax, L[i]);
    for (int off = 32; off; off >>= 1) lmax = fmaxf(lmax, __shfl_down(lmax, off));
    if ((t & 63) == 0) red[t >> 6] = lmax;
    __syncthreads();
    float bmax = fmaxf(fmaxf(red[0], red[1]), fmaxf(red[2], red[3]));
    float lsum = 0.f;
    for (int i = t; i < Nd; i += 256) lsum += expf(L[i] - bmax);
    for (int off = 32; off; off >>= 1) lsum += __shfl_down(lsum, off);
    __syncthreads();
    if ((t & 63) == 0) red[t >> 6] = lsum;
    __syncthreads();
    float inv = 1.f / (red[0] + red[1] + red[2] + red[3]);
    for (int i = t; i < Nd; i += 256) L[i] = expf(L[i] - bmax) * inv;
}

// ---------------------------------------------------------------------------
extern "C" void kernel_launch(void* const* d_in, const int* in_sizes, int n_in,
                              void* d_out, int out_size, void* d_ws, size_t ws_size,
                              hipStream_t stream)
{
    const int Bn = 4, T = 1024, D = 512, R = 64;
    const int S0 = 1024, S1 = 256, S2 = 64;
    const long RT = (long)D * R;
    const int MR = 3 * T + S0 + S1 + S2;   // 4416

    const float* tok_val    = (const float*)d_in[0];
    const float* tok_state  = (const float*)d_in[1];
    const float* mem_state0 = (const float*)d_in[2];
    const float* mem_val0   = (const float*)d_in[3];
    const float* mem_state1 = (const float*)d_in[4];
    const float* mem_val1   = (const float*)d_in[5];
    const float* mem_state2 = (const float*)d_in[6];
    const float* mem_val2   = (const float*)d_in[7];
    const float* write_route= (const float*)d_in[8];
    const float* prop_route = (const float*)d_in[9];
    const float* level_route= (const float*)d_in[10];
    const float* skip_route = (const float*)d_in[11];
    const float* skip_gates = (const float*)d_in[12];
    const float* ln_gamma   = (const float*)d_in[13];
    const float* ln_beta    = (const float*)d_in[14];
    const float* read_route = (const float*)d_in[15];
    const float* read_proj  = (const float*)d_in[16];
    const float* read_gates = (const float*)d_in[17];
    float* out = (float*)d_out;

    // workspace carve
    float* p = (float*)d_ws;
    float* v0  = p; p += (long)Bn * S0 * D;
    float* v0b = p; p += (long)Bn * S0 * D;
    float* s0  = p; p += Bn * S0;
    float* v1  = p; p += (long)Bn * S1 * D;
    float* v1b = p; p += (long)Bn * S1 * D;
    float* s1  = p; p += Bn * S1;
    float* v2  = p; p += (long)Bn * S2 * D;
    float* v2b = p; p += (long)Bn * S2 * D;
    float* s2  = p; p += Bn * S2;
    float* qb  = p; p += (long)Bn * T * R;
    float* kb  = p; p += (long)Bn * S0 * R;
    float* rqk = p; p += (long)Bn * MR * R;
    float* lb0 = p; p += (long)Bn * T * S0;      // also transition lb
    float* lb1 = p; p += (long)Bn * T * S1;
    float* lb2 = p; p += (long)Bn * T * S2;
    float* cbuf= p; p += (long)Bn * T * 16;
    int*   ib  = (int*)p; p += (long)Bn * T * 16;
    float* dsb = p; p += Bn * S0;
    float* rcat= p; p += (long)Bn * T * 1536;    // concat r
    int* cntb  = (int*)p; p += Bn * S0;
    int* curb  = (int*)p; p += Bn * S0;
    int* offsb = (int*)p; p += Bn * S0 + 1;
    int* elistb= (int*)p; p += (long)Bn * T * 16;
    unsigned short* pcatT = (unsigned short*)p; p += (512L * 1536) / 2 + 4;  // (512,1536) bf16
    unsigned short* mvT0  = (unsigned short*)p; p += ((long)Bn * D * S0) / 2 + 4;
    unsigned short* mvT1  = (unsigned short*)p; p += ((long)Bn * D * S1) / 2 + 4;
    unsigned short* mvT2  = (unsigned short*)p; p += ((long)Bn * D * S2) / 2 + 4;
    float* partb = p; p += 8L * Bn * MR * R;

    auto proj = [&](const float* Aq, const float* Ak, const float* Wq, const float* Wk,
                    int Mq, int Mk, long sAq, long sAk, float* qout, float* kout) {
        proj_splitk_kernel<<<dim3((Mq + Mk) / 64, 8, Bn), 256, 0, stream>>>(
            Aq, Ak, Wq, Wk, partb, Mq, Mk, sAq, sAk, Bn);
        int total4 = Bn * (Mq + Mk) * 16;
        proj_reduce_kernel<<<(total4 + 255) / 256, 256, 0, stream>>>(
            partb, qout, kout, Mq, Mk, Bn);
    };

    hipMemsetAsync(cntb, 0, (size_t)2 * Bn * S0 * sizeof(int), stream);

    auto trans = [&](const float* sv, const float* ss, const float* dval,
                     const float* W, int Ns, int Nd,
                     const float* v_in, float* v_out, const float* sin, float* sout,
                     int lvl, const float* gptr, int gidx) {
        proj(sv, dval, W, W + RT, Ns, Nd, (long)Ns * D, (long)Nd * D, qb, kb);
        gemm_f32_nt_kernel<<<dim3(Ns / 64, Nd / 64, Bn), 256, 0, stream>>>(
            qb, kb, lb0, Ns, Nd, R, (long)Ns * R, (long)Nd * R, (long)Ns * Nd, 0.125f);
        int nsLog = 31 - __builtin_clz((unsigned)Ns);
        int nsShift = nsLog + 4;
        int rowBlocks = Bn * Ns / 4;
        if (Nd == 1024)
            topk_coeff_kernel<16><<<rowBlocks, 256, 0, stream>>>(lb0, ss, ib, cbuf, cntb, nsLog, Nd);
        else if (Nd == 256)
            topk_coeff_kernel<4><<<rowBlocks, 256, 0, stream>>>(lb0, ss, ib, cbuf, cntb, nsLog, Nd);
        else
            topk_coeff_kernel<1><<<rowBlocks, 256, 0, stream>>>(lb0, ss, ib, cbuf, cntb, nsLog, Nd);
        int E = Bn * Ns * 16;
        scan_kernel<<<1, 256, 0, stream>>>(cntb, offsb, Bn * Nd);
        fill_edges_kernel<<<(E + 255) / 256, 256, 0, stream>>>(ib, offsb, curb, elistb,
                                                               nsShift, Nd, E);
        gather_ln_kernel<<<Bn * Nd, 256, 0, stream>>>(sv, cbuf, elistb, offsb,
                                                      v_in, v_out, dsb, curb,
                                                      ln_gamma + lvl * D, ln_beta + lvl * D,
                                                      gptr, gidx, nsShift);
        apply_state_kernel<<<Bn, 256, 0, stream>>>(sin, dsb, sout, Nd, gptr, gidx);
    };

    // ---- level 0 ----
    trans(tok_val, tok_state, mem_val0, write_route, T, S0,
          mem_val0, v0, mem_state0, s0, 0, nullptr, 0);
    trans(v0, s0, v0, prop_route + 0 * 2 * RT, S0, S0,
          v0, v0b, s0, s0, 0, nullptr, 0);

    // ---- level 1 ----
    trans(v0b, s0, mem_val1, level_route + 0 * 2 * RT, S0, S1,
          mem_val1, v1, mem_state1, s1, 1, nullptr, 0);
    trans(tok_val, tok_state, v1, skip_route + 0 * 2 * RT, T, S1,
          v1, v1, s1, s1, 1, skip_gates, 0);
    trans(v1, s1, v1, prop_route + 1 * 2 * RT, S1, S1,
          v1, v1b, s1, s1, 1, nullptr, 0);

    // ---- level 2 ----
    trans(v1b, s1, mem_val2, level_route + 1 * 2 * RT, S1, S2,
          mem_val2, v2, mem_state2, s2, 2, nullptr, 0);
    trans(v0b, s0, v2, skip_route + 1 * 2 * RT, S0, S2,
          v2, v2, s2, s2, 2, skip_gates, 1);
    trans(v2, s2, v2, prop_route + 2 * 2 * RT, S2, S2,
          v2, v2b, s2, s2, 2, nullptr, 0);

    // ---- read phase (8 launches) ----
    transpose_proj_gated_kernel<<<dim3(D / 32, D / 32, 3), dim3(32, 8), 0, stream>>>(
        read_proj, read_gates, pcatT);
    transpose_mv_kernel<<<dim3(D / 32, (S0 + S1 + S2) / 32, Bn), dim3(32, 8), 0, stream>>>(
        v0b, v1b, v2b, mvT0, mvT1, mvT2);

    {
        ProjDesc d = {};
        const float* mvs[3] = { v0b, v1b, v2b };
        const int nds[3] = { S0, S1, S2 };
        int tiles = 0, roff = 0;
        for (int l = 0; l < 3; ++l) {
            d.A[l] = tok_val; d.W[l] = read_route + (long)l * 2 * RT;
            d.sA[l] = (long)T * D; d.rowOff[l] = roff;
            d.tileOff[l] = tiles; tiles += T / 64; roff += T;
        }
        for (int l = 0; l < 3; ++l) {
            d.A[3 + l] = mvs[l]; d.W[3 + l] = read_route + (long)l * 2 * RT + RT;
            d.sA[3 + l] = (long)nds[l] * D; d.rowOff[3 + l] = roff;
            d.tileOff[3 + l] = tiles; tiles += nds[l] / 64; roff += nds[l];
        }
        d.tileOff[6] = tiles;
        d.Mtot = MR;
        proj_splitk_multi_kernel<<<dim3(tiles, 8, Bn), 256, 0, stream>>>(d, partb, Bn);
        int total4 = Bn * MR * 16;
        proj_reduce_flat_kernel<<<(total4 + 255) / 256, 256, 0, stream>>>(partb, rqk, total4);
    }

    {   // segmented logits GEMM: q_l x k_l^T -> lb_l (one launch)
        LogitsSeg d = {};
        float* lbs[3] = { lb0, lb1, lb2 };
        const int nds[3] = { S0, S1, S2 };
        int koff = 3 * T, yo = 0;
        for (int l = 0; l < 3; ++l) {
            d.A[l] = rqk + (long)l * T * R;
            d.B[l] = rqk + (long)koff * R;
            d.C[l] = lbs[l];
            d.sC[l] = (long)T * nds[l];
            d.Nd[l] = nds[l];
            d.yOff[l] = yo;
            yo += nds[l] / 64;
            koff += nds[l];
        }
        d.yOff[3] = yo;
        d.sAB = (long)MR * R;
        gemm_logits_seg_kernel<<<dim3(T / 64, yo, Bn), 256, 0, stream>>>(d);
    }

    softmax_seg_kernel<<<dim3(Bn * T, 3), 256, 0, stream>>>(lb0, lb1, lb2);

    {   // segmented attn x mv -> r_cat (one launch)
        AttnSeg d = {};
        float* lbs[3] = { lb0, lb1, lb2 };
        const unsigned short* mvTs[3] = { mvT0, mvT1, mvT2 };
        const int nds[3] = { S0, S1, S2 };
        for (int l = 0; l < 3; ++l) {
            d.A[l] = lbs[l];
            d.Bt[l] = mvTs[l];
            d.K[l] = nds[l];
            d.sA[l] = (long)T * nds[l];
            d.sBt[l] = (long)D * nds[l];
        }
        gemm_mfma_attn_seg_kernel<<<dim3(48, D / 64, Bn), 256, 0, stream>>>(
            d, rcat, (long)T * 1536);
    }

    // out = tok_val + r_cat(T,1536) x Pcat^T(512,1536) (gates folded into Pcat)
    gemm_mfma_kernel<<<dim3(T / 64, D / 64, Bn), 256, 0, stream>>>(
        rcat, pcatT, out, T, D, 1536,
        (long)T * 1536, 0, (long)T * D, 1.f, tok_val);
}

// Round 14
// 846.972 us; speedup vs baseline: 1.1970x; 1.0253x over previous
//
#include <hip/hip_runtime.h>
#include <math.h>

typedef __attribute__((ext_vector_type(8))) short short8;
typedef __attribute__((ext_vector_type(4))) float floatx4;

static __device__ __forceinline__ short f2bf(float f) {
    union { float f; unsigned u; } c; c.f = f;
    unsigned r = c.u + 0x7FFF + ((c.u >> 16) & 1);   // RNE
    return (short)(r >> 16);
}

// ---------------------------------------------------------------------------
// fp32 GEMM: C[b] = alpha * A[b](M,K) x B[b](N,K)^T. 64x64 tile, 4x4 micro.
// (transition logits path — fp32-exact for top-k)
// ---------------------------------------------------------------------------
__launch_bounds__(256)
__global__ void gemm_f32_nt_kernel(const float* __restrict__ A, const float* __restrict__ B,
                                   float* __restrict__ C, int M, int N, int K,
                                   long sA, long sB, long sC, float alpha)
{
    __shared__ float As[32][68];   // [k][m]
    __shared__ float Bs[32][68];   // [k][n]
    const float* Ab = A + (long)blockIdx.z * sA;
    const float* Bb = B + (long)blockIdx.z * sB;
    float* Cb = C + (long)blockIdx.z * sC;
    int m0 = blockIdx.x * 64, n0 = blockIdx.y * 64;
    int t = threadIdx.x;
    int tx = t & 15, ty = t >> 4;
    float acc[4][4] = {};

    for (int k0 = 0; k0 < K; k0 += 32) {
        {
            int m = t >> 3;
            int kk = (t & 7) * 4;
#pragma unroll
            for (int h = 0; h < 2; ++h) {
                float4 v = *(const float4*)&Ab[(long)(m0 + m + 32 * h) * K + k0 + kk];
                As[kk + 0][m + 32 * h] = v.x; As[kk + 1][m + 32 * h] = v.y;
                As[kk + 2][m + 32 * h] = v.z; As[kk + 3][m + 32 * h] = v.w;
            }
        }
        {
            int n = t >> 3;
            int kk = (t & 7) * 4;
#pragma unroll
            for (int h = 0; h < 2; ++h) {
                float4 v = *(const float4*)&Bb[(long)(n0 + n + 32 * h) * K + k0 + kk];
                Bs[kk + 0][n + 32 * h] = v.x; Bs[kk + 1][n + 32 * h] = v.y;
                Bs[kk + 2][n + 32 * h] = v.z; Bs[kk + 3][n + 32 * h] = v.w;
            }
        }
        __syncthreads();
#pragma unroll 4
        for (int k = 0; k < 32; ++k) {
            float4 a = *(const float4*)&As[k][ty * 4];
            float4 b = *(const float4*)&Bs[k][tx * 4];
            float av[4] = { a.x, a.y, a.z, a.w };
            float bv[4] = { b.x, b.y, b.z, b.w };
#pragma unroll
            for (int i = 0; i < 4; ++i)
#pragma unroll
                for (int j = 0; j < 4; ++j) acc[i][j] += av[i] * bv[j];
        }
        __syncthreads();
    }
#pragma unroll
    for (int i = 0; i < 4; ++i) {
        float4 r;
        r.x = alpha * acc[i][0]; r.y = alpha * acc[i][1];
        r.z = alpha * acc[i][2]; r.w = alpha * acc[i][3];
        *(float4*)&Cb[(long)(m0 + ty * 4 + i) * N + n0 + tx * 4] = r;
    }
}

// ---------------------------------------------------------------------------
// Segmented read-phase logits GEMM: 3 levels in one launch (y-tiles 16|4|1).
// ---------------------------------------------------------------------------
struct LogitsSeg {
    const float* A[3];
    const float* B[3];
    float* C[3];
    long sC[3];
    int Nd[3];
    int yOff[4];
    long sAB;
};

__launch_bounds__(256)
__global__ void gemm_logits_seg_kernel(LogitsSeg d)
{
    __shared__ float As[32][68];
    __shared__ float Bs[32][68];
    int yt = blockIdx.y;
    int seg = 0;
    while (yt >= d.yOff[seg + 1]) ++seg;
    int n0 = (yt - d.yOff[seg]) * 64;
    const float* Ab = d.A[seg] + (long)blockIdx.z * d.sAB;
    const float* Bb = d.B[seg] + (long)blockIdx.z * d.sAB;
    float* Cb = d.C[seg] + (long)blockIdx.z * d.sC[seg];
    int N = d.Nd[seg];
    int m0 = blockIdx.x * 64;
    int t = threadIdx.x, tx = t & 15, ty = t >> 4;
    float acc[4][4] = {};
    const int K = 64;

    for (int k0 = 0; k0 < K; k0 += 32) {
        {
            int m = t >> 3;
            int kk = (t & 7) * 4;
#pragma unroll
            for (int h = 0; h < 2; ++h) {
                float4 v = *(const float4*)&Ab[(long)(m0 + m + 32 * h) * K + k0 + kk];
                As[kk + 0][m + 32 * h] = v.x; As[kk + 1][m + 32 * h] = v.y;
                As[kk + 2][m + 32 * h] = v.z; As[kk + 3][m + 32 * h] = v.w;
            }
        }
        {
            int n = t >> 3;
            int kk = (t & 7) * 4;
#pragma unroll
            for (int h = 0; h < 2; ++h) {
                float4 v = *(const float4*)&Bb[(long)(n0 + n + 32 * h) * K + k0 + kk];
                Bs[kk + 0][n + 32 * h] = v.x; Bs[kk + 1][n + 32 * h] = v.y;
                Bs[kk + 2][n + 32 * h] = v.z; Bs[kk + 3][n + 32 * h] = v.w;
            }
        }
        __syncthreads();
#pragma unroll 4
        for (int k = 0; k < 32; ++k) {
            float4 a = *(const float4*)&As[k][ty * 4];
            float4 b = *(const float4*)&Bs[k][tx * 4];
            float av[4] = { a.x, a.y, a.z, a.w };
            float bv[4] = { b.x, b.y, b.z, b.w };
#pragma unroll
            for (int i = 0; i < 4; ++i)
#pragma unroll
                for (int j = 0; j < 4; ++j) acc[i][j] += av[i] * bv[j];
        }
        __syncthreads();
    }
#pragma unroll
    for (int i = 0; i < 4; ++i) {
        float4 r;
        r.x = 0.125f * acc[i][0]; r.y = 0.125f * acc[i][1];
        r.z = 0.125f * acc[i][2]; r.w = 0.125f * acc[i][3];
        *(float4*)&Cb[(long)(m0 + ty * 4 + i) * N + n0 + tx * 4] = r;
    }
}

// ---------------------------------------------------------------------------
// Split-K q/k projection for transitions (proven round-9 path).
// ---------------------------------------------------------------------------
__launch_bounds__(256)
__global__ void proj_splitk_kernel(const float* __restrict__ Aq, const float* __restrict__ Ak,
                                   const float* __restrict__ Wq, const float* __restrict__ Wk,
                                   float* __restrict__ part,
                                   int Mq, int Mk, long sAq, long sAk, int Bn)
{
    __shared__ float As[32][68];
    __shared__ float Bs[32][68];
    int mqT = Mq >> 6;
    int xt = blockIdx.x, s = blockIdx.y, b = blockIdx.z;
    const float* A; const float* W; int row0, orow;
    if (xt < mqT) { A = Aq + (long)b * sAq; W = Wq; row0 = xt * 64; orow = row0; }
    else { A = Ak + (long)b * sAk; W = Wk; row0 = (xt - mqT) * 64; orow = Mq + row0; }
    int t = threadIdx.x, tx = t & 15, ty = t >> 4;
    float acc[4][4] = {};
    int kbase = s * 64;

    for (int k0 = kbase; k0 < kbase + 64; k0 += 32) {
        {
            int m = t >> 3;
            int kk = (t & 7) * 4;
#pragma unroll
            for (int h = 0; h < 2; ++h) {
                float4 v = *(const float4*)&A[(long)(row0 + m + 32 * h) * 512 + k0 + kk];
                As[kk + 0][m + 32 * h] = v.x; As[kk + 1][m + 32 * h] = v.y;
                As[kk + 2][m + 32 * h] = v.z; As[kk + 3][m + 32 * h] = v.w;
            }
        }
        {
            int kk = t >> 3;
            int nn = (t & 7) * 8;
            float4 v0 = *(const float4*)&W[(long)(k0 + kk) * 64 + nn];
            float4 v1 = *(const float4*)&W[(long)(k0 + kk) * 64 + nn + 4];
            *(float4*)&Bs[kk][nn] = v0;
            *(float4*)&Bs[kk][nn + 4] = v1;
        }
        __syncthreads();
#pragma unroll 4
        for (int k = 0; k < 32; ++k) {
            float4 a = *(const float4*)&As[k][ty * 4];
            float4 b2 = *(const float4*)&Bs[k][tx * 4];
            float av[4] = { a.x, a.y, a.z, a.w };
            float bv[4] = { b2.x, b2.y, b2.z, b2.w };
#pragma unroll
            for (int i = 0; i < 4; ++i)
#pragma unroll
                for (int j = 0; j < 4; ++j) acc[i][j] += av[i] * bv[j];
        }
        __syncthreads();
    }
    long base = ((long)(s * Bn + b) * (Mq + Mk) + orow) * 64;
#pragma unroll
    for (int i = 0; i < 4; ++i)
        *(float4*)&part[base + (long)(ty * 4 + i) * 64 + tx * 4] =
            make_float4(acc[i][0], acc[i][1], acc[i][2], acc[i][3]);
}

__launch_bounds__(256)
__global__ void proj_reduce_kernel(const float* __restrict__ part,
                                   float* __restrict__ qout, float* __restrict__ kout,
                                   int Mq, int Mk, int Bn)
{
    int idx = blockIdx.x * 256 + threadIdx.x;
    int size4b = (Mq + Mk) * 16;
    int total4 = Bn * size4b;
    if (idx >= total4) return;
    const float4* p4 = (const float4*)part;
    long stride4 = (long)total4;
    float4 s = p4[idx];
#pragma unroll
    for (int ss = 1; ss < 8; ++ss) {
        float4 v = p4[ss * stride4 + idx];
        s.x += v.x; s.y += v.y; s.z += v.z; s.w += v.w;
    }
    int b = idx / size4b;
    int rem = idx - b * size4b;
    int r = rem >> 4;
    int c4 = rem & 15;
    if (r < Mq) ((float4*)qout)[((long)b * Mq + r) * 16 + c4] = s;
    else        ((float4*)kout)[((long)b * Mk + (r - Mq)) * 16 + c4] = s;
}

// ---------------------------------------------------------------------------
// Multi-segment split-K projection (read phase): 6 segments in one launch.
// ---------------------------------------------------------------------------
struct ProjDesc {
    const float* A[6];
    const float* W[6];
    long  sA[6];
    int   tileOff[7];
    int   rowOff[6];
    int   Mtot;
};

__launch_bounds__(256)
__global__ void proj_splitk_multi_kernel(ProjDesc d, float* __restrict__ part, int Bn)
{
    __shared__ float As[32][68];
    __shared__ float Bs[32][68];
    int xt = blockIdx.x, s = blockIdx.y, b = blockIdx.z;
    int seg = 0;
    while (xt >= d.tileOff[seg + 1]) ++seg;
    int row0 = (xt - d.tileOff[seg]) * 64;
    const float* A = d.A[seg] + (long)b * d.sA[seg];
    const float* W = d.W[seg];
    int orow = d.rowOff[seg] + row0;
    int t = threadIdx.x, tx = t & 15, ty = t >> 4;
    float acc[4][4] = {};
    int kbase = s * 64;

    for (int k0 = kbase; k0 < kbase + 64; k0 += 32) {
        {
            int m = t >> 3;
            int kk = (t & 7) * 4;
#pragma unroll
            for (int h = 0; h < 2; ++h) {
                float4 v = *(const float4*)&A[(long)(row0 + m + 32 * h) * 512 + k0 + kk];
                As[kk + 0][m + 32 * h] = v.x; As[kk + 1][m + 32 * h] = v.y;
                As[kk + 2][m + 32 * h] = v.z; As[kk + 3][m + 32 * h] = v.w;
            }
        }
        {
            int kk = t >> 3;
            int nn = (t & 7) * 8;
            float4 v0 = *(const float4*)&W[(long)(k0 + kk) * 64 + nn];
            float4 v1 = *(const float4*)&W[(long)(k0 + kk) * 64 + nn + 4];
            *(float4*)&Bs[kk][nn] = v0;
            *(float4*)&Bs[kk][nn + 4] = v1;
        }
        __syncthreads();
#pragma unroll 4
        for (int k = 0; k < 32; ++k) {
            float4 a = *(const float4*)&As[k][ty * 4];
            float4 b2 = *(const float4*)&Bs[k][tx * 4];
            float av[4] = { a.x, a.y, a.z, a.w };
            float bv[4] = { b2.x, b2.y, b2.z, b2.w };
#pragma unroll
            for (int i = 0; i < 4; ++i)
#pragma unroll
                for (int j = 0; j < 4; ++j) acc[i][j] += av[i] * bv[j];
        }
        __syncthreads();
    }
    long base = ((long)(s * Bn + b) * d.Mtot + orow) * 64;
#pragma unroll
    for (int i = 0; i < 4; ++i)
        *(float4*)&part[base + (long)(ty * 4 + i) * 64 + tx * 4] =
            make_float4(acc[i][0], acc[i][1], acc[i][2], acc[i][3]);
}

__launch_bounds__(256)
__global__ void proj_reduce_flat_kernel(const float* __restrict__ part, float* __restrict__ outp,
                                        int total4)
{
    int idx = blockIdx.x * 256 + threadIdx.x;
    if (idx >= total4) return;
    const float4* p4 = (const float4*)part;
    float4 s = p4[idx];
#pragma unroll
    for (int ss = 1; ss < 8; ++ss) {
        float4 v = p4[(long)ss * total4 + idx];
        s.x += v.x; s.y += v.y; s.z += v.z; s.w += v.w;
    }
    ((float4*)outp)[idx] = s;
}

// ---------------------------------------------------------------------------
// bf16 x bf16 MFMA GEMM, BK=64: C[b](M,N) = A_bf16[b](M,K) x Bt_bf16(N,K)^T + initC.
// 8 MFMAs per barrier pair (half the barriers of the BK=32 variant).
// Frag-order LDS: half kc in {0,1}, slot = kc*256 + mt*64 + quad*16 + (row&15).
// ---------------------------------------------------------------------------
__launch_bounds__(256)
__global__ void gemm_mfma_bb_kernel(const unsigned short* __restrict__ A,
                                    const unsigned short* __restrict__ Bt,
                                    float* __restrict__ C, int M, int N, int K,
                                    long sA, long sBt, long sC,
                                    const float* __restrict__ initC)
{
    __shared__ short As[4096];
    __shared__ short Bs[4096];
    const unsigned short* Ab = A + (long)blockIdx.z * sA;
    const unsigned short* Bb = Bt + (long)blockIdx.z * sBt;
    float* Cb = C + (long)blockIdx.z * sC;
    const float* Ib = initC ? initC + (long)blockIdx.z * sC : nullptr;
    int m0 = blockIdx.x * 64, n0 = blockIdx.y * 64;
    int t = threadIdx.x, wave = t >> 6, lane = t & 63;
    int sr = wave * 16 + (lane & 15);        // staging row 0..63
    int sk = (lane >> 4) * 16;               // staging k offset 0,16,32,48
    int mt_s = sr >> 4, rr = sr & 15;
    int kc_s = sk >> 5;
    int q0 = (sk & 31) >> 3;                 // 0 or 2
    int slot0 = kc_s * 256 + mt_s * 64 + q0 * 16 + rr;
    floatx4 acc[4] = {};

    for (int k0 = 0; k0 < K; k0 += 64) {
        const unsigned short* ap = &Ab[(long)(m0 + sr) * K + k0 + sk];
        const unsigned short* bp = &Bb[(long)(n0 + sr) * K + k0 + sk];
        short8 a0 = *(const short8*)ap;
        short8 a1 = *(const short8*)(ap + 8);
        short8 b0 = *(const short8*)bp;
        short8 b1 = *(const short8*)(bp + 8);
        ((short8*)As)[slot0]      = a0;
        ((short8*)As)[slot0 + 16] = a1;
        ((short8*)Bs)[slot0]      = b0;
        ((short8*)Bs)[slot0 + 16] = b1;
        __syncthreads();
#pragma unroll
        for (int kc = 0; kc < 2; ++kc) {
            short8 bf = ((short8*)Bs)[kc * 256 + wave * 64 + lane];
#pragma unroll
            for (int mt = 0; mt < 4; ++mt) {
                short8 af = ((short8*)As)[kc * 256 + mt * 64 + lane];
                acc[mt] = __builtin_amdgcn_mfma_f32_16x16x32_bf16(af, bf, acc[mt], 0, 0, 0);
            }
        }
        __syncthreads();
    }
    int col = n0 + wave * 16 + (lane & 15);
#pragma unroll
    for (int mt = 0; mt < 4; ++mt) {
#pragma unroll
        for (int r = 0; r < 4; ++r) {
            int row = m0 + mt * 16 + (lane >> 4) * 4 + r;
            long off = (long)row * N + col;
            float v = acc[mt][r];
            if (Ib) v += Ib[off];
            Cb[off] = v;
        }
    }
}

// ---------------------------------------------------------------------------
// Segmented attn x mv MFMA (read phase): 3 levels in one launch.
// r_cat[:, l*512 + :] = bf16( attn_l(T,Nd_l) x mv_l(Nd_l,512) ). ldc = 1536.
// bf16 store is numerically free: the downstream GEMM rounds A to bf16 anyway.
// ---------------------------------------------------------------------------
struct AttnSeg {
    const float* A[3];            // lb_l
    const unsigned short* Bt[3];  // mvT_l (512, Nd_l)
    int K[3];                     // Nd_l
    long sA[3], sBt[3];
};

__launch_bounds__(256)
__global__ void gemm_mfma_attn_seg_kernel(AttnSeg d, unsigned short* __restrict__ rcat, long sC)
{
    __shared__ short As[2048];
    __shared__ short Bs[2048];
    int lvl = blockIdx.x >> 4;
    int m0 = (blockIdx.x & 15) * 64;
    int n0 = blockIdx.y * 64;
    int K = d.K[lvl];
    const float* Ab = d.A[lvl] + (long)blockIdx.z * d.sA[lvl];
    const unsigned short* Bb = d.Bt[lvl] + (long)blockIdx.z * d.sBt[lvl];
    unsigned short* Cb = rcat + (long)blockIdx.z * sC + lvl * 512;
    int t = threadIdx.x, wave = t >> 6, lane = t & 63;
    int sr = wave * 16 + (lane & 15);
    int sk = (lane >> 4) * 8;
    floatx4 acc[4] = {};

    for (int k0 = 0; k0 < K; k0 += 32) {
        const float* ap = &Ab[(long)(m0 + sr) * K + k0 + sk];
        float4 f0 = *(const float4*)ap;
        float4 f1 = *(const float4*)(ap + 4);
        short8 av;
        av[0] = f2bf(f0.x); av[1] = f2bf(f0.y); av[2] = f2bf(f0.z); av[3] = f2bf(f0.w);
        av[4] = f2bf(f1.x); av[5] = f2bf(f1.y); av[6] = f2bf(f1.z); av[7] = f2bf(f1.w);
        short8 bv = *(const short8*)&Bb[(long)(n0 + sr) * K + k0 + sk];
        ((short8*)As)[t] = av;
        ((short8*)Bs)[t] = bv;
        __syncthreads();
        short8 bf = ((short8*)Bs)[wave * 64 + lane];
#pragma unroll
        for (int mt = 0; mt < 4; ++mt) {
            short8 af = ((short8*)As)[mt * 64 + lane];
            acc[mt] = __builtin_amdgcn_mfma_f32_16x16x32_bf16(af, bf, acc[mt], 0, 0, 0);
        }
        __syncthreads();
    }
    int col = n0 + wave * 16 + (lane & 15);
#pragma unroll
    for (int mt = 0; mt < 4; ++mt) {
#pragma unroll
        for (int r = 0; r < 4; ++r) {
            int row = m0 + mt * 16 + (lane >> 4) * 4 + r;
            Cb[(long)row * 1536 + col] = (unsigned short)f2bf(acc[mt][r]);
        }
    }
}

// ---------------------------------------------------------------------------
// Gated concat transpose of read_proj: Pcat^T[n][l*512+d'] = bf16(g_l*P_l[d'][n]).
// ---------------------------------------------------------------------------
__global__ void transpose_proj_gated_kernel(const float* __restrict__ proj,
                                            const float* __restrict__ gates,
                                            unsigned short* __restrict__ outp)
{
    __shared__ float tile[32][33];
    int l = blockIdx.z;
    float g = 1.f / (1.f + expf(-gates[l]));
    const float* I = proj + (long)l * 512 * 512;
    int n0 = blockIdx.x * 32, d0 = blockIdx.y * 32;
    int tx = threadIdx.x, ty = threadIdx.y;
#pragma unroll
    for (int i = 0; i < 32; i += 8)
        tile[ty + i][tx] = I[(long)(d0 + ty + i) * 512 + n0 + tx];
    __syncthreads();
#pragma unroll
    for (int i = 0; i < 32; i += 8)
        outp[(long)(n0 + ty + i) * 1536 + l * 512 + d0 + tx] =
            (unsigned short)f2bf(g * tile[tx][ty + i]);
}

// Batched transpose of the 3 mv levels in one launch. y-tiles: 32|8|2.
__global__ void transpose_mv_kernel(const float* __restrict__ mv0, const float* __restrict__ mv1,
                                    const float* __restrict__ mv2,
                                    unsigned short* __restrict__ o0, unsigned short* __restrict__ o1,
                                    unsigned short* __restrict__ o2)
{
    __shared__ float tile[32][33];
    int yt = blockIdx.y;
    const float* in; unsigned short* out; int Nd, r0t;
    if (yt < 32)      { in = mv0; out = o0; Nd = 1024; r0t = yt; }
    else if (yt < 40) { in = mv1; out = o1; Nd = 256;  r0t = yt - 32; }
    else              { in = mv2; out = o2; Nd = 64;   r0t = yt - 40; }
    const float* I = in + (long)blockIdx.z * Nd * 512;
    unsigned short* O = out + (long)blockIdx.z * 512 * Nd;
    int c0 = blockIdx.x * 32, r0 = r0t * 32;
    int tx = threadIdx.x, ty = threadIdx.y;
#pragma unroll
    for (int i = 0; i < 32; i += 8)
        tile[ty + i][tx] = I[(long)(r0 + ty + i) * 512 + c0 + tx];
    __syncthreads();
#pragma unroll
    for (int i = 0; i < 32; i += 8)
        O[(long)(c0 + ty + i) * Nd + r0 + tx] = (unsigned short)f2bf(tile[tx][ty + i]);
}

// ---------------------------------------------------------------------------
// Exact top-16 per row + fused CSR count. 4 rows/block (one wave per row).
// ---------------------------------------------------------------------------
template<int CNT>
__launch_bounds__(256)
__global__ void topk_coeff_kernel(const float* __restrict__ logits,
                                  const float* __restrict__ state,
                                  int* __restrict__ idx_out, float* __restrict__ c_out,
                                  int* __restrict__ cnt, int nsLog, int Nd)
{
    int wave = threadIdx.x >> 6, lane = threadIdx.x & 63;
    long row = (long)blockIdx.x * 4 + wave;
    const float* L = logits + row * Nd;
    float vreg[CNT];
    if (CNT >= 4) {
#pragma unroll
        for (int q = 0; q < CNT / 4; ++q) {
            float4 v = *(const float4*)&L[lane * CNT + q * 4];
            vreg[q * 4 + 0] = v.x; vreg[q * 4 + 1] = v.y;
            vreg[q * 4 + 2] = v.z; vreg[q * 4 + 3] = v.w;
        }
    } else {
#pragma unroll
        for (int tt = 0; tt < CNT; ++tt) vreg[tt] = L[lane * CNT + tt];
    }

    float m = 0.f, sum = 0.f;
    float myv = 0.f; int myi = 0;
#pragma unroll
    for (int it = 0; it < 16; ++it) {
        float best = -INFINITY; int bidx = 0x7fffffff;
#pragma unroll
        for (int tt = 0; tt < CNT; ++tt) {
            if (vreg[tt] > best) { best = vreg[tt]; bidx = lane * CNT + tt; }
        }
#pragma unroll
        for (int off = 32; off; off >>= 1) {
            float ov = __shfl_down(best, off);
            int   oi = __shfl_down(bidx, off);
            if (ov > best || (ov == best && oi < bidx)) { best = ov; bidx = oi; }
        }
        best = __shfl(best, 0);
        bidx = __shfl(bidx, 0);
        if (it == lane) { myv = best; myi = bidx; }
        float ab = fabsf(best);
        float nm = fmaxf(m, ab);
        sum = sum * expf(m - nm) + expf(ab - nm);
        m = nm;
#pragma unroll
        for (int tt = 0; tt < CNT; ++tt)
            if (lane * CNT + tt == bidx) vreg[tt] = -INFINITY;
    }
    if (lane < 16) {
        float st = state[row];
        float sp = fmaxf(st, 0.f) + log1pf(expf(-fabsf(st)));
        float sgn = (myv > 0.f) ? 1.f : ((myv < 0.f) ? -1.f : 0.f);
        float w = expf(fabsf(myv) - m) / sum;
        c_out[row * 16 + lane] = sgn * w * sp;
        idx_out[row * 16 + lane] = myi;
        int b = (int)(row >> nsLog);
        atomicAdd(&cnt[b * Nd + myi], 1);
    }
}

// Single-block exclusive scan; self-zeroes cnt (next Nd <= current Nd).
__launch_bounds__(256)
__global__ void scan_kernel(int* __restrict__ cnt, int* __restrict__ offs, int N)
{
    __shared__ int sums[256];
    int t = threadIdx.x;
    int chunk = N >> 8;
    int base = t * chunk;
    int lc[16];
    int s = 0;
    for (int i = 0; i < chunk; ++i) { lc[i] = cnt[base + i]; s += lc[i]; }
    sums[t] = s;
    __syncthreads();
    for (int off = 1; off < 256; off <<= 1) {
        int v = (t >= off) ? sums[t - off] : 0;
        __syncthreads();
        sums[t] += v;
        __syncthreads();
    }
    int run = sums[t] - s;
    for (int i = 0; i < chunk; ++i) {
        offs[base + i] = run;
        run += lc[i];
        cnt[base + i] = 0;
    }
    if (t == 255) offs[N] = run;
}

__launch_bounds__(256)
__global__ void fill_edges_kernel(const int* __restrict__ idx, const int* __restrict__ offs,
                                  int* __restrict__ cursor, int* __restrict__ elist,
                                  int nsShift, int Nd, int E)
{
    int e = blockIdx.x * 256 + threadIdx.x;
    if (e >= E) return;
    int b = e >> nsShift;
    int d = b * Nd + idx[e];
    int pos = offs[d] + atomicAdd(&cursor[d], 1);
    elist[pos] = e;
}

// ---------------------------------------------------------------------------
// FUSED gather + LayerNorm (proven): ds by-product, cursor self-clean.
// ---------------------------------------------------------------------------
#define ECHUNK 512
__launch_bounds__(256)
__global__ void gather_ln_kernel(const float* __restrict__ src_val, const float* __restrict__ c,
                                 const int* __restrict__ elist, const int* __restrict__ offs,
                                 const float* __restrict__ v_in, float* __restrict__ v_out,
                                 float* __restrict__ ds, int* __restrict__ cursor,
                                 const float* __restrict__ gamma, const float* __restrict__ beta,
                                 const float* __restrict__ gatePtr, int gateIdx, int nsShift)
{
    __shared__ float sc[ECHUNK];
    __shared__ int   srow[ECHUNK];
    __shared__ float part[4][512];
    __shared__ float pcs[4];
    __shared__ float red[4];
    long row = blockIdx.x;
    int t = threadIdx.x, w = t >> 6, lane = t & 63;
    int e0 = offs[row], e1 = offs[row + 1];
    int mask = (1 << nsShift) - 1;
    int cb = lane * 8;
    float a[8] = {};
    float cs = 0.f;
    float gate = 1.f;
    if (gatePtr) gate = 1.f / (1.f + expf(-gatePtr[gateIdx]));

    for (int cstart = e0; cstart < e1; cstart += ECHUNK) {
        int cnt = min(e1 - cstart, ECHUNK);
        for (int i = t; i < cnt; i += 256) {
            int e = elist[cstart + i];
            sc[i] = c[e];
            int b = e >> nsShift;
            int s = (e & mask) >> 4;
            srow[i] = (b << (nsShift - 4)) + s;
        }
        __syncthreads();
        int j = w;
        for (; j + 12 < cnt; j += 16) {
            float c0 = sc[j], c1 = sc[j + 4], c2 = sc[j + 8], c3 = sc[j + 12];
            const float* p0 = src_val + ((long)srow[j]      << 9) + cb;
            const float* p1 = src_val + ((long)srow[j + 4]  << 9) + cb;
            const float* p2 = src_val + ((long)srow[j + 8]  << 9) + cb;
            const float* p3 = src_val + ((long)srow[j + 12] << 9) + cb;
            float4 x00 = *(const float4*)p0,       x01 = *(const float4*)(p0 + 4);
            float4 x10 = *(const float4*)p1,       x11 = *(const float4*)(p1 + 4);
            float4 x20 = *(const float4*)p2,       x21 = *(const float4*)(p2 + 4);
            float4 x30 = *(const float4*)p3,       x31 = *(const float4*)(p3 + 4);
            a[0] += c0 * x00.x + c1 * x10.x + c2 * x20.x + c3 * x30.x;
            a[1] += c0 * x00.y + c1 * x10.y + c2 * x20.y + c3 * x30.y;
            a[2] += c0 * x00.z + c1 * x10.z + c2 * x20.z + c3 * x30.z;
            a[3] += c0 * x00.w + c1 * x10.w + c2 * x20.w + c3 * x30.w;
            a[4] += c0 * x01.x + c1 * x11.x + c2 * x21.x + c3 * x31.x;
            a[5] += c0 * x01.y + c1 * x11.y + c2 * x21.y + c3 * x31.y;
            a[6] += c0 * x01.z + c1 * x11.z + c2 * x21.z + c3 * x31.z;
            a[7] += c0 * x01.w + c1 * x11.w + c2 * x21.w + c3 * x31.w;
            cs += c0 + c1 + c2 + c3;
        }
        for (; j < cnt; j += 4) {
            float cv = sc[j];
            const float* p = src_val + ((long)srow[j] << 9) + cb;
            float4 x0 = *(const float4*)p, x1 = *(const float4*)(p + 4);
            a[0] += cv * x0.x; a[1] += cv * x0.y; a[2] += cv * x0.z; a[3] += cv * x0.w;
            a[4] += cv * x1.x; a[5] += cv * x1.y; a[6] += cv * x1.z; a[7] += cv * x1.w;
            cs += cv;
        }
        __syncthreads();
    }
#pragma unroll
    for (int i = 0; i < 8; ++i) part[w][cb + i] = a[i];
    if (lane == 0) pcs[w] = cs;
    __syncthreads();
    float r0 = part[0][t] + part[1][t] + part[2][t] + part[3][t];
    float r1 = part[0][t + 256] + part[1][t + 256] + part[2][t + 256] + part[3][t + 256];
    if (t == 0) { ds[row] = pcs[0] + pcs[1] + pcs[2] + pcs[3]; cursor[row] = 0; }

    const float* vi = v_in + (row << 9);
    float x0 = vi[t]       + gate * r0;
    float x1 = vi[t + 256] + gate * r1;
    float s = x0 + x1;
    for (int off = 32; off; off >>= 1) s += __shfl_down(s, off);
    if ((t & 63) == 0) red[t >> 6] = s;
    __syncthreads();
    float mean = (red[0] + red[1] + red[2] + red[3]) * (1.f / 512.f);
    float d0 = x0 - mean, d1 = x1 - mean;
    float ss = d0 * d0 + d1 * d1;
    for (int off = 32; off; off >>= 1) ss += __shfl_down(ss, off);
    __syncthreads();
    if ((t & 63) == 0) red[t >> 6] = ss;
    __syncthreads();
    float var = (red[0] + red[1] + red[2] + red[3]) * (1.f / 512.f);
    float rstd = rsqrtf(var + 1e-5f);
    float* vo = v_out + (row << 9);
    vo[t]       = d0 * rstd * gamma[t]       + beta[t];
    vo[t + 256] = d1 * rstd * gamma[t + 256] + beta[t + 256];
}

// ---------------------------------------------------------------------------
// state' = sign(x)*softmax(|x|), x = s + gate*ds. One block per batch.
// ---------------------------------------------------------------------------
__launch_bounds__(256)
__global__ void apply_state_kernel(const float* __restrict__ s_in, const float* __restrict__ ds,
                                   float* __restrict__ s_out, int Nd,
                                   const float* __restrict__ gatePtr, int gateIdx)
{
    __shared__ float sh[1024];
    __shared__ float red[4];
    int b = blockIdx.x, t = threadIdx.x;
    float gate = 1.f;
    if (gatePtr) gate = 1.f / (1.f + expf(-gatePtr[gateIdx]));
    float lmax = 0.f;
    for (int i = t; i < Nd; i += 256) {
        float x = s_in[b * Nd + i] + gate * ds[b * Nd + i];
        sh[i] = x;
        lmax = fmaxf(lmax, fabsf(x));
    }
    for (int off = 32; off; off >>= 1) lmax = fmaxf(lmax, __shfl_down(lmax, off));
    if ((t & 63) == 0) red[t >> 6] = lmax;
    __syncthreads();
    float bmax = fmaxf(fmaxf(red[0], red[1]), fmaxf(red[2], red[3]));
    float lsum = 0.f;
    for (int i = t; i < Nd; i += 256) lsum += expf(fabsf(sh[i]) - bmax);
    for (int off = 32; off; off >>= 1) lsum += __shfl_down(lsum, off);
    __syncthreads();
    if ((t & 63) == 0) red[t >> 6] = lsum;
    __syncthreads();
    float inv = 1.f / (red[0] + red[1] + red[2] + red[3]);
    for (int i = t; i < Nd; i += 256) {
        float x = sh[i];
        float sgn = (x > 0.f) ? 1.f : ((x < 0.f) ? -1.f : 0.f);
        s_out[b * Nd + i] = sgn * expf(fabsf(x) - bmax) * inv;
    }
}

// ---------------------------------------------------------------------------
// Segmented softmax over rows (read phase): grid (Bn*T, 3).
// ---------------------------------------------------------------------------
__launch_bounds__(256)
__global__ void softmax_seg_kernel(float* __restrict__ lb0, float* __restrict__ lb1,
                                   float* __restrict__ lb2)
{
    __shared__ float red[4];
    int lvl = blockIdx.y;
    int Nd = (lvl == 0) ? 1024 : (lvl == 1) ? 256 : 64;
    float* base = (lvl == 0) ? lb0 : (lvl == 1) ? lb1 : lb2;
    long row = blockIdx.x;
    int t = threadIdx.x;
    float* L = base + row * (long)Nd;
    float lmax = -INFINITY;
    for (int i = t; i < Nd; i += 256) lmax = fmaxf(lmax, L[i]);
    for (int off = 32; off; off >>= 1) lmax = fmaxf(lmax, __shfl_down(lmax, off));
    if ((t & 63) == 0) red[t >> 6] = lmax;
    __syncthreads();
    float bmax = fmaxf(fmaxf(red[0], red[1]), fmaxf(red[2], red[3]));
    float lsum = 0.f;
    for (int i = t; i < Nd; i += 256) lsum += expf(L[i] - bmax);
    for (int off = 32; off; off >>= 1) lsum += __shfl_down(lsum, off);
    __syncthreads();
    if ((t & 63) == 0) red[t >> 6] = lsum;
    __syncthreads();
    float inv = 1.f / (red[0] + red[1] + red[2] + red[3]);
    for (int i = t; i < Nd; i += 256) L[i] = expf(L[i] - bmax) * inv;
}

// ---------------------------------------------------------------------------
extern "C" void kernel_launch(void* const* d_in, const int* in_sizes, int n_in,
                              void* d_out, int out_size, void* d_ws, size_t ws_size,
                              hipStream_t stream)
{
    const int Bn = 4, T = 1024, D = 512, R = 64;
    const int S0 = 1024, S1 = 256, S2 = 64;
    const long RT = (long)D * R;
    const int MR = 3 * T + S0 + S1 + S2;   // 4416

    const float* tok_val    = (const float*)d_in[0];
    const float* tok_state  = (const float*)d_in[1];
    const float* mem_state0 = (const float*)d_in[2];
    const float* mem_val0   = (const float*)d_in[3];
    const float* mem_state1 = (const float*)d_in[4];
    const float* mem_val1   = (const float*)d_in[5];
    const float* mem_state2 = (const float*)d_in[6];
    const float* mem_val2   = (const float*)d_in[7];
    const float* write_route= (const float*)d_in[8];
    const float* prop_route = (const float*)d_in[9];
    const float* level_route= (const float*)d_in[10];
    const float* skip_route = (const float*)d_in[11];
    const float* skip_gates = (const float*)d_in[12];
    const float* ln_gamma   = (const float*)d_in[13];
    const float* ln_beta    = (const float*)d_in[14];
    const float* read_route = (const float*)d_in[15];
    const float* read_proj  = (const float*)d_in[16];
    const float* read_gates = (const float*)d_in[17];
    float* out = (float*)d_out;

    // workspace carve
    float* p = (float*)d_ws;
    float* v0  = p; p += (long)Bn * S0 * D;
    float* v0b = p; p += (long)Bn * S0 * D;
    float* s0  = p; p += Bn * S0;
    float* v1  = p; p += (long)Bn * S1 * D;
    float* v1b = p; p += (long)Bn * S1 * D;
    float* s1  = p; p += Bn * S1;
    float* v2  = p; p += (long)Bn * S2 * D;
    float* v2b = p; p += (long)Bn * S2 * D;
    float* s2  = p; p += Bn * S2;
    float* qb  = p; p += (long)Bn * T * R;
    float* kb  = p; p += (long)Bn * S0 * R;
    float* rqk = p; p += (long)Bn * MR * R;
    float* lb0 = p; p += (long)Bn * T * S0;      // also transition lb
    float* lb1 = p; p += (long)Bn * T * S1;
    float* lb2 = p; p += (long)Bn * T * S2;
    float* cbuf= p; p += (long)Bn * T * 16;
    int*   ib  = (int*)p; p += (long)Bn * T * 16;
    float* dsb = p; p += Bn * S0;
    unsigned short* rcat = (unsigned short*)p; p += ((long)Bn * T * 1536) / 2 + 4;  // bf16 concat r
    int* cntb  = (int*)p; p += Bn * S0;
    int* curb  = (int*)p; p += Bn * S0;
    int* offsb = (int*)p; p += Bn * S0 + 1;
    int* elistb= (int*)p; p += (long)Bn * T * 16;
    unsigned short* pcatT = (unsigned short*)p; p += (512L * 1536) / 2 + 4;  // (512,1536) bf16
    unsigned short* mvT0  = (unsigned short*)p; p += ((long)Bn * D * S0) / 2 + 4;
    unsigned short* mvT1  = (unsigned short*)p; p += ((long)Bn * D * S1) / 2 + 4;
    unsigned short* mvT2  = (unsigned short*)p; p += ((long)Bn * D * S2) / 2 + 4;
    float* partb = p; p += 8L * Bn * MR * R;

    auto proj = [&](const float* Aq, const float* Ak, const float* Wq, const float* Wk,
                    int Mq, int Mk, long sAq, long sAk, float* qout, float* kout) {
        proj_splitk_kernel<<<dim3((Mq + Mk) / 64, 8, Bn), 256, 0, stream>>>(
            Aq, Ak, Wq, Wk, partb, Mq, Mk, sAq, sAk, Bn);
        int total4 = Bn * (Mq + Mk) * 16;
        proj_reduce_kernel<<<(total4 + 255) / 256, 256, 0, stream>>>(
            partb, qout, kout, Mq, Mk, Bn);
    };

    hipMemsetAsync(cntb, 0, (size_t)2 * Bn * S0 * sizeof(int), stream);

    auto trans = [&](const float* sv, const float* ss, const float* dval,
                     const float* W, int Ns, int Nd,
                     const float* v_in, float* v_out, const float* sin, float* sout,
                     int lvl, const float* gptr, int gidx) {
        proj(sv, dval, W, W + RT, Ns, Nd, (long)Ns * D, (long)Nd * D, qb, kb);
        gemm_f32_nt_kernel<<<dim3(Ns / 64, Nd / 64, Bn), 256, 0, stream>>>(
            qb, kb, lb0, Ns, Nd, R, (long)Ns * R, (long)Nd * R, (long)Ns * Nd, 0.125f);
        int nsLog = 31 - __builtin_clz((unsigned)Ns);
        int nsShift = nsLog + 4;
        int rowBlocks = Bn * Ns / 4;
        if (Nd == 1024)
            topk_coeff_kernel<16><<<rowBlocks, 256, 0, stream>>>(lb0, ss, ib, cbuf, cntb, nsLog, Nd);
        else if (Nd == 256)
            topk_coeff_kernel<4><<<rowBlocks, 256, 0, stream>>>(lb0, ss, ib, cbuf, cntb, nsLog, Nd);
        else
            topk_coeff_kernel<1><<<rowBlocks, 256, 0, stream>>>(lb0, ss, ib, cbuf, cntb, nsLog, Nd);
        int E = Bn * Ns * 16;
        scan_kernel<<<1, 256, 0, stream>>>(cntb, offsb, Bn * Nd);
        fill_edges_kernel<<<(E + 255) / 256, 256, 0, stream>>>(ib, offsb, curb, elistb,
                                                               nsShift, Nd, E);
        gather_ln_kernel<<<Bn * Nd, 256, 0, stream>>>(sv, cbuf, elistb, offsb,
                                                      v_in, v_out, dsb, curb,
                                                      ln_gamma + lvl * D, ln_beta + lvl * D,
                                                      gptr, gidx, nsShift);
        apply_state_kernel<<<Bn, 256, 0, stream>>>(sin, dsb, sout, Nd, gptr, gidx);
    };

    // ---- level 0 ----
    trans(tok_val, tok_state, mem_val0, write_route, T, S0,
          mem_val0, v0, mem_state0, s0, 0, nullptr, 0);
    trans(v0, s0, v0, prop_route + 0 * 2 * RT, S0, S0,
          v0, v0b, s0, s0, 0, nullptr, 0);

    // ---- level 1 ----
    trans(v0b, s0, mem_val1, level_route + 0 * 2 * RT, S0, S1,
          mem_val1, v1, mem_state1, s1, 1, nullptr, 0);
    trans(tok_val, tok_state, v1, skip_route + 0 * 2 * RT, T, S1,
          v1, v1, s1, s1, 1, skip_gates, 0);
    trans(v1, s1, v1, prop_route + 1 * 2 * RT, S1, S1,
          v1, v1b, s1, s1, 1, nullptr, 0);

    // ---- level 2 ----
    trans(v1b, s1, mem_val2, level_route + 1 * 2 * RT, S1, S2,
          mem_val2, v2, mem_state2, s2, 2, nullptr, 0);
    trans(v0b, s0, v2, skip_route + 1 * 2 * RT, S0, S2,
          v2, v2, s2, s2, 2, skip_gates, 1);
    trans(v2, s2, v2, prop_route + 2 * 2 * RT, S2, S2,
          v2, v2b, s2, s2, 2, nullptr, 0);

    // ---- read phase (8 launches) ----
    transpose_proj_gated_kernel<<<dim3(D / 32, D / 32, 3), dim3(32, 8), 0, stream>>>(
        read_proj, read_gates, pcatT);
    transpose_mv_kernel<<<dim3(D / 32, (S0 + S1 + S2) / 32, Bn), dim3(32, 8), 0, stream>>>(
        v0b, v1b, v2b, mvT0, mvT1, mvT2);

    {
        ProjDesc d = {};
        const float* mvs[3] = { v0b, v1b, v2b };
        const int nds[3] = { S0, S1, S2 };
        int tiles = 0, roff = 0;
        for (int l = 0; l < 3; ++l) {
            d.A[l] = tok_val; d.W[l] = read_route + (long)l * 2 * RT;
            d.sA[l] = (long)T * D; d.rowOff[l] = roff;
            d.tileOff[l] = tiles; tiles += T / 64; roff += T;
        }
        for (int l = 0; l < 3; ++l) {
            d.A[3 + l] = mvs[l]; d.W[3 + l] = read_route + (long)l * 2 * RT + RT;
            d.sA[3 + l] = (long)nds[l] * D; d.rowOff[3 + l] = roff;
            d.tileOff[3 + l] = tiles; tiles += nds[l] / 64; roff += nds[l];
        }
        d.tileOff[6] = tiles;
        d.Mtot = MR;
        proj_splitk_multi_kernel<<<dim3(tiles, 8, Bn), 256, 0, stream>>>(d, partb, Bn);
        int total4 = Bn * MR * 16;
        proj_reduce_flat_kernel<<<(total4 + 255) / 256, 256, 0, stream>>>(partb, rqk, total4);
    }

    {   // segmented logits GEMM: q_l x k_l^T -> lb_l (one launch)
        LogitsSeg d = {};
        float* lbs[3] = { lb0, lb1, lb2 };
        const int nds[3] = { S0, S1, S2 };
        int koff = 3 * T, yo = 0;
        for (int l = 0; l < 3; ++l) {
            d.A[l] = rqk + (long)l * T * R;
            d.B[l] = rqk + (long)koff * R;
            d.C[l] = lbs[l];
            d.sC[l] = (long)T * nds[l];
            d.Nd[l] = nds[l];
            d.yOff[l] = yo;
            yo += nds[l] / 64;
            koff += nds[l];
        }
        d.yOff[3] = yo;
        d.sAB = (long)MR * R;
        gemm_logits_seg_kernel<<<dim3(T / 64, yo, Bn), 256, 0, stream>>>(d);
    }

    softmax_seg_kernel<<<dim3(Bn * T, 3), 256, 0, stream>>>(lb0, lb1, lb2);

    {   // segmented attn x mv -> r_cat (bf16, one launch)
        AttnSeg d = {};
        float* lbs[3] = { lb0, lb1, lb2 };
        const unsigned short* mvTs[3] = { mvT0, mvT1, mvT2 };
        const int nds[3] = { S0, S1, S2 };
        for (int l = 0; l < 3; ++l) {
            d.A[l] = lbs[l];
            d.Bt[l] = mvTs[l];
            d.K[l] = nds[l];
            d.sA[l] = (long)T * nds[l];
            d.sBt[l] = (long)D * nds[l];
        }
        gemm_mfma_attn_seg_kernel<<<dim3(48, D / 64, Bn), 256, 0, stream>>>(
            d, rcat, (long)T * 1536);
    }

    // out = tok_val + r_cat(T,1536,bf16) x Pcat^T(512,1536,bf16) — BK=64, 24 iters
    gemm_mfma_bb_kernel<<<dim3(T / 64, D / 64, Bn), 256, 0, stream>>>(
        rcat, pcatT, out, T, D, 1536,
        (long)T * 1536, 0, (long)T * D, tok_val);
}

// Round 15
// 799.253 us; speedup vs baseline: 1.2685x; 1.0597x over previous
//
#include <hip/hip_runtime.h>
#include <math.h>

typedef __attribute__((ext_vector_type(8))) short short8;
typedef __attribute__((ext_vector_type(4))) float floatx4;

static __device__ __forceinline__ short f2bf(float f) {
    union { float f; unsigned u; } c; c.f = f;
    unsigned r = c.u + 0x7FFF + ((c.u >> 16) & 1);   // RNE
    return (short)(r >> 16);
}

// ---------------------------------------------------------------------------
// fp32 GEMM: C[b] = alpha * A[b](M,K) x B[b](N,K)^T. 64x64 tile, 4x4 micro.
// (transition logits path — fp32-exact for top-k)
// ---------------------------------------------------------------------------
__launch_bounds__(256)
__global__ void gemm_f32_nt_kernel(const float* __restrict__ A, const float* __restrict__ B,
                                   float* __restrict__ C, int M, int N, int K,
                                   long sA, long sB, long sC, float alpha)
{
    __shared__ float As[32][68];   // [k][m]
    __shared__ float Bs[32][68];   // [k][n]
    const float* Ab = A + (long)blockIdx.z * sA;
    const float* Bb = B + (long)blockIdx.z * sB;
    float* Cb = C + (long)blockIdx.z * sC;
    int m0 = blockIdx.x * 64, n0 = blockIdx.y * 64;
    int t = threadIdx.x;
    int tx = t & 15, ty = t >> 4;
    float acc[4][4] = {};

    for (int k0 = 0; k0 < K; k0 += 32) {
        {
            int m = t >> 3;
            int kk = (t & 7) * 4;
#pragma unroll
            for (int h = 0; h < 2; ++h) {
                float4 v = *(const float4*)&Ab[(long)(m0 + m + 32 * h) * K + k0 + kk];
                As[kk + 0][m + 32 * h] = v.x; As[kk + 1][m + 32 * h] = v.y;
                As[kk + 2][m + 32 * h] = v.z; As[kk + 3][m + 32 * h] = v.w;
            }
        }
        {
            int n = t >> 3;
            int kk = (t & 7) * 4;
#pragma unroll
            for (int h = 0; h < 2; ++h) {
                float4 v = *(const float4*)&Bb[(long)(n0 + n + 32 * h) * K + k0 + kk];
                Bs[kk + 0][n + 32 * h] = v.x; Bs[kk + 1][n + 32 * h] = v.y;
                Bs[kk + 2][n + 32 * h] = v.z; Bs[kk + 3][n + 32 * h] = v.w;
            }
        }
        __syncthreads();
#pragma unroll 4
        for (int k = 0; k < 32; ++k) {
            float4 a = *(const float4*)&As[k][ty * 4];
            float4 b = *(const float4*)&Bs[k][tx * 4];
            float av[4] = { a.x, a.y, a.z, a.w };
            float bv[4] = { b.x, b.y, b.z, b.w };
#pragma unroll
            for (int i = 0; i < 4; ++i)
#pragma unroll
                for (int j = 0; j < 4; ++j) acc[i][j] += av[i] * bv[j];
        }
        __syncthreads();
    }
#pragma unroll
    for (int i = 0; i < 4; ++i) {
        float4 r;
        r.x = alpha * acc[i][0]; r.y = alpha * acc[i][1];
        r.z = alpha * acc[i][2]; r.w = alpha * acc[i][3];
        *(float4*)&Cb[(long)(m0 + ty * 4 + i) * N + n0 + tx * 4] = r;
    }
}

// ---------------------------------------------------------------------------
// Segmented read-phase logits GEMM: 3 levels in one launch (y-tiles 16|4|1).
// ---------------------------------------------------------------------------
struct LogitsSeg {
    const float* A[3];
    const float* B[3];
    float* C[3];
    long sC[3];
    int Nd[3];
    int yOff[4];
    long sAB;
};

__launch_bounds__(256)
__global__ void gemm_logits_seg_kernel(LogitsSeg d)
{
    __shared__ float As[32][68];
    __shared__ float Bs[32][68];
    int yt = blockIdx.y;
    int seg = 0;
    while (yt >= d.yOff[seg + 1]) ++seg;
    int n0 = (yt - d.yOff[seg]) * 64;
    const float* Ab = d.A[seg] + (long)blockIdx.z * d.sAB;
    const float* Bb = d.B[seg] + (long)blockIdx.z * d.sAB;
    float* Cb = d.C[seg] + (long)blockIdx.z * d.sC[seg];
    int N = d.Nd[seg];
    int m0 = blockIdx.x * 64;
    int t = threadIdx.x, tx = t & 15, ty = t >> 4;
    float acc[4][4] = {};
    const int K = 64;

    for (int k0 = 0; k0 < K; k0 += 32) {
        {
            int m = t >> 3;
            int kk = (t & 7) * 4;
#pragma unroll
            for (int h = 0; h < 2; ++h) {
                float4 v = *(const float4*)&Ab[(long)(m0 + m + 32 * h) * K + k0 + kk];
                As[kk + 0][m + 32 * h] = v.x; As[kk + 1][m + 32 * h] = v.y;
                As[kk + 2][m + 32 * h] = v.z; As[kk + 3][m + 32 * h] = v.w;
            }
        }
        {
            int n = t >> 3;
            int kk = (t & 7) * 4;
#pragma unroll
            for (int h = 0; h < 2; ++h) {
                float4 v = *(const float4*)&Bb[(long)(n0 + n + 32 * h) * K + k0 + kk];
                Bs[kk + 0][n + 32 * h] = v.x; Bs[kk + 1][n + 32 * h] = v.y;
                Bs[kk + 2][n + 32 * h] = v.z; Bs[kk + 3][n + 32 * h] = v.w;
            }
        }
        __syncthreads();
#pragma unroll 4
        for (int k = 0; k < 32; ++k) {
            float4 a = *(const float4*)&As[k][ty * 4];
            float4 b = *(const float4*)&Bs[k][tx * 4];
            float av[4] = { a.x, a.y, a.z, a.w };
            float bv[4] = { b.x, b.y, b.z, b.w };
#pragma unroll
            for (int i = 0; i < 4; ++i)
#pragma unroll
                for (int j = 0; j < 4; ++j) acc[i][j] += av[i] * bv[j];
        }
        __syncthreads();
    }
#pragma unroll
    for (int i = 0; i < 4; ++i) {
        float4 r;
        r.x = 0.125f * acc[i][0]; r.y = 0.125f * acc[i][1];
        r.z = 0.125f * acc[i][2]; r.w = 0.125f * acc[i][3];
        *(float4*)&Cb[(long)(m0 + ty * 4 + i) * N + n0 + tx * 4] = r;
    }
}

// ---------------------------------------------------------------------------
// Split-K q/k projection for transitions (proven round-9 path).
// ---------------------------------------------------------------------------
__launch_bounds__(256)
__global__ void proj_splitk_kernel(const float* __restrict__ Aq, const float* __restrict__ Ak,
                                   const float* __restrict__ Wq, const float* __restrict__ Wk,
                                   float* __restrict__ part,
                                   int Mq, int Mk, long sAq, long sAk, int Bn)
{
    __shared__ float As[32][68];
    __shared__ float Bs[32][68];
    int mqT = Mq >> 6;
    int xt = blockIdx.x, s = blockIdx.y, b = blockIdx.z;
    const float* A; const float* W; int row0, orow;
    if (xt < mqT) { A = Aq + (long)b * sAq; W = Wq; row0 = xt * 64; orow = row0; }
    else { A = Ak + (long)b * sAk; W = Wk; row0 = (xt - mqT) * 64; orow = Mq + row0; }
    int t = threadIdx.x, tx = t & 15, ty = t >> 4;
    float acc[4][4] = {};
    int kbase = s * 64;

    for (int k0 = kbase; k0 < kbase + 64; k0 += 32) {
        {
            int m = t >> 3;
            int kk = (t & 7) * 4;
#pragma unroll
            for (int h = 0; h < 2; ++h) {
                float4 v = *(const float4*)&A[(long)(row0 + m + 32 * h) * 512 + k0 + kk];
                As[kk + 0][m + 32 * h] = v.x; As[kk + 1][m + 32 * h] = v.y;
                As[kk + 2][m + 32 * h] = v.z; As[kk + 3][m + 32 * h] = v.w;
            }
        }
        {
            int kk = t >> 3;
            int nn = (t & 7) * 8;
            float4 v0 = *(const float4*)&W[(long)(k0 + kk) * 64 + nn];
            float4 v1 = *(const float4*)&W[(long)(k0 + kk) * 64 + nn + 4];
            *(float4*)&Bs[kk][nn] = v0;
            *(float4*)&Bs[kk][nn + 4] = v1;
        }
        __syncthreads();
#pragma unroll 4
        for (int k = 0; k < 32; ++k) {
            float4 a = *(const float4*)&As[k][ty * 4];
            float4 b2 = *(const float4*)&Bs[k][tx * 4];
            float av[4] = { a.x, a.y, a.z, a.w };
            float bv[4] = { b2.x, b2.y, b2.z, b2.w };
#pragma unroll
            for (int i = 0; i < 4; ++i)
#pragma unroll
                for (int j = 0; j < 4; ++j) acc[i][j] += av[i] * bv[j];
        }
        __syncthreads();
    }
    long base = ((long)(s * Bn + b) * (Mq + Mk) + orow) * 64;
#pragma unroll
    for (int i = 0; i < 4; ++i)
        *(float4*)&part[base + (long)(ty * 4 + i) * 64 + tx * 4] =
            make_float4(acc[i][0], acc[i][1], acc[i][2], acc[i][3]);
}

__launch_bounds__(256)
__global__ void proj_reduce_kernel(const float* __restrict__ part,
                                   float* __restrict__ qout, float* __restrict__ kout,
                                   int Mq, int Mk, int Bn)
{
    int idx = blockIdx.x * 256 + threadIdx.x;
    int size4b = (Mq + Mk) * 16;
    int total4 = Bn * size4b;
    if (idx >= total4) return;
    const float4* p4 = (const float4*)part;
    long stride4 = (long)total4;
    float4 s = p4[idx];
#pragma unroll
    for (int ss = 1; ss < 8; ++ss) {
        float4 v = p4[ss * stride4 + idx];
        s.x += v.x; s.y += v.y; s.z += v.z; s.w += v.w;
    }
    int b = idx / size4b;
    int rem = idx - b * size4b;
    int r = rem >> 4;
    int c4 = rem & 15;
    if (r < Mq) ((float4*)qout)[((long)b * Mq + r) * 16 + c4] = s;
    else        ((float4*)kout)[((long)b * Mk + (r - Mq)) * 16 + c4] = s;
}

// ---------------------------------------------------------------------------
// Multi-segment split-K projection (read phase): 6 segments in one launch.
// ---------------------------------------------------------------------------
struct ProjDesc {
    const float* A[6];
    const float* W[6];
    long  sA[6];
    int   tileOff[7];
    int   rowOff[6];
    int   Mtot;
};

__launch_bounds__(256)
__global__ void proj_splitk_multi_kernel(ProjDesc d, float* __restrict__ part, int Bn)
{
    __shared__ float As[32][68];
    __shared__ float Bs[32][68];
    int xt = blockIdx.x, s = blockIdx.y, b = blockIdx.z;
    int seg = 0;
    while (xt >= d.tileOff[seg + 1]) ++seg;
    int row0 = (xt - d.tileOff[seg]) * 64;
    const float* A = d.A[seg] + (long)b * d.sA[seg];
    const float* W = d.W[seg];
    int orow = d.rowOff[seg] + row0;
    int t = threadIdx.x, tx = t & 15, ty = t >> 4;
    float acc[4][4] = {};
    int kbase = s * 64;

    for (int k0 = kbase; k0 < kbase + 64; k0 += 32) {
        {
            int m = t >> 3;
            int kk = (t & 7) * 4;
#pragma unroll
            for (int h = 0; h < 2; ++h) {
                float4 v = *(const float4*)&A[(long)(row0 + m + 32 * h) * 512 + k0 + kk];
                As[kk + 0][m + 32 * h] = v.x; As[kk + 1][m + 32 * h] = v.y;
                As[kk + 2][m + 32 * h] = v.z; As[kk + 3][m + 32 * h] = v.w;
            }
        }
        {
            int kk = t >> 3;
            int nn = (t & 7) * 8;
            float4 v0 = *(const float4*)&W[(long)(k0 + kk) * 64 + nn];
            float4 v1 = *(const float4*)&W[(long)(k0 + kk) * 64 + nn + 4];
            *(float4*)&Bs[kk][nn] = v0;
            *(float4*)&Bs[kk][nn + 4] = v1;
        }
        __syncthreads();
#pragma unroll 4
        for (int k = 0; k < 32; ++k) {
            float4 a = *(const float4*)&As[k][ty * 4];
            float4 b2 = *(const float4*)&Bs[k][tx * 4];
            float av[4] = { a.x, a.y, a.z, a.w };
            float bv[4] = { b2.x, b2.y, b2.z, b2.w };
#pragma unroll
            for (int i = 0; i < 4; ++i)
#pragma unroll
                for (int j = 0; j < 4; ++j) acc[i][j] += av[i] * bv[j];
        }
        __syncthreads();
    }
    long base = ((long)(s * Bn + b) * d.Mtot + orow) * 64;
#pragma unroll
    for (int i = 0; i < 4; ++i)
        *(float4*)&part[base + (long)(ty * 4 + i) * 64 + tx * 4] =
            make_float4(acc[i][0], acc[i][1], acc[i][2], acc[i][3]);
}

__launch_bounds__(256)
__global__ void proj_reduce_flat_kernel(const float* __restrict__ part, float* __restrict__ outp,
                                        int total4)
{
    int idx = blockIdx.x * 256 + threadIdx.x;
    if (idx >= total4) return;
    const float4* p4 = (const float4*)part;
    float4 s = p4[idx];
#pragma unroll
    for (int ss = 1; ss < 8; ++ss) {
        float4 v = p4[(long)ss * total4 + idx];
        s.x += v.x; s.y += v.y; s.z += v.z; s.w += v.w;
    }
    ((float4*)outp)[idx] = s;
}

// ---------------------------------------------------------------------------
// bf16 x bf16 MFMA GEMM, BK=64: C[b](M,N) = A_bf16[b](M,K) x Bt_bf16(N,K)^T + initC.
// ---------------------------------------------------------------------------
__launch_bounds__(256)
__global__ void gemm_mfma_bb_kernel(const unsigned short* __restrict__ A,
                                    const unsigned short* __restrict__ Bt,
                                    float* __restrict__ C, int M, int N, int K,
                                    long sA, long sBt, long sC,
                                    const float* __restrict__ initC)
{
    __shared__ short As[4096];
    __shared__ short Bs[4096];
    const unsigned short* Ab = A + (long)blockIdx.z * sA;
    const unsigned short* Bb = Bt + (long)blockIdx.z * sBt;
    float* Cb = C + (long)blockIdx.z * sC;
    const float* Ib = initC ? initC + (long)blockIdx.z * sC : nullptr;
    int m0 = blockIdx.x * 64, n0 = blockIdx.y * 64;
    int t = threadIdx.x, wave = t >> 6, lane = t & 63;
    int sr = wave * 16 + (lane & 15);
    int sk = (lane >> 4) * 16;
    int mt_s = sr >> 4, rr = sr & 15;
    int kc_s = sk >> 5;
    int q0 = (sk & 31) >> 3;
    int slot0 = kc_s * 256 + mt_s * 64 + q0 * 16 + rr;
    floatx4 acc[4] = {};

    for (int k0 = 0; k0 < K; k0 += 64) {
        const unsigned short* ap = &Ab[(long)(m0 + sr) * K + k0 + sk];
        const unsigned short* bp = &Bb[(long)(n0 + sr) * K + k0 + sk];
        short8 a0 = *(const short8*)ap;
        short8 a1 = *(const short8*)(ap + 8);
        short8 b0 = *(const short8*)bp;
        short8 b1 = *(const short8*)(bp + 8);
        ((short8*)As)[slot0]      = a0;
        ((short8*)As)[slot0 + 16] = a1;
        ((short8*)Bs)[slot0]      = b0;
        ((short8*)Bs)[slot0 + 16] = b1;
        __syncthreads();
#pragma unroll
        for (int kc = 0; kc < 2; ++kc) {
            short8 bf = ((short8*)Bs)[kc * 256 + wave * 64 + lane];
#pragma unroll
            for (int mt = 0; mt < 4; ++mt) {
                short8 af = ((short8*)As)[kc * 256 + mt * 64 + lane];
                acc[mt] = __builtin_amdgcn_mfma_f32_16x16x32_bf16(af, bf, acc[mt], 0, 0, 0);
            }
        }
        __syncthreads();
    }
    int col = n0 + wave * 16 + (lane & 15);
#pragma unroll
    for (int mt = 0; mt < 4; ++mt) {
#pragma unroll
        for (int r = 0; r < 4; ++r) {
            int row = m0 + mt * 16 + (lane >> 4) * 4 + r;
            long off = (long)row * N + col;
            float v = acc[mt][r];
            if (Ib) v += Ib[off];
            Cb[off] = v;
        }
    }
}

// ---------------------------------------------------------------------------
// Segmented attn x mv MFMA (read phase): 3 levels, bf16 output (ldc 1536).
// ---------------------------------------------------------------------------
struct AttnSeg {
    const float* A[3];
    const unsigned short* Bt[3];
    int K[3];
    long sA[3], sBt[3];
};

__launch_bounds__(256)
__global__ void gemm_mfma_attn_seg_kernel(AttnSeg d, unsigned short* __restrict__ rcat, long sC)
{
    __shared__ short As[2048];
    __shared__ short Bs[2048];
    int lvl = blockIdx.x >> 4;
    int m0 = (blockIdx.x & 15) * 64;
    int n0 = blockIdx.y * 64;
    int K = d.K[lvl];
    const float* Ab = d.A[lvl] + (long)blockIdx.z * d.sA[lvl];
    const unsigned short* Bb = d.Bt[lvl] + (long)blockIdx.z * d.sBt[lvl];
    unsigned short* Cb = rcat + (long)blockIdx.z * sC + lvl * 512;
    int t = threadIdx.x, wave = t >> 6, lane = t & 63;
    int sr = wave * 16 + (lane & 15);
    int sk = (lane >> 4) * 8;
    floatx4 acc[4] = {};

    for (int k0 = 0; k0 < K; k0 += 32) {
        const float* ap = &Ab[(long)(m0 + sr) * K + k0 + sk];
        float4 f0 = *(const float4*)ap;
        float4 f1 = *(const float4*)(ap + 4);
        short8 av;
        av[0] = f2bf(f0.x); av[1] = f2bf(f0.y); av[2] = f2bf(f0.z); av[3] = f2bf(f0.w);
        av[4] = f2bf(f1.x); av[5] = f2bf(f1.y); av[6] = f2bf(f1.z); av[7] = f2bf(f1.w);
        short8 bv = *(const short8*)&Bb[(long)(n0 + sr) * K + k0 + sk];
        ((short8*)As)[t] = av;
        ((short8*)Bs)[t] = bv;
        __syncthreads();
        short8 bf = ((short8*)Bs)[wave * 64 + lane];
#pragma unroll
        for (int mt = 0; mt < 4; ++mt) {
            short8 af = ((short8*)As)[mt * 64 + lane];
            acc[mt] = __builtin_amdgcn_mfma_f32_16x16x32_bf16(af, bf, acc[mt], 0, 0, 0);
        }
        __syncthreads();
    }
    int col = n0 + wave * 16 + (lane & 15);
#pragma unroll
    for (int mt = 0; mt < 4; ++mt) {
#pragma unroll
        for (int r = 0; r < 4; ++r) {
            int row = m0 + mt * 16 + (lane >> 4) * 4 + r;
            Cb[(long)row * 1536 + col] = (unsigned short)f2bf(acc[mt][r]);
        }
    }
}

// ---------------------------------------------------------------------------
// Gated concat transpose of read_proj.
// ---------------------------------------------------------------------------
__global__ void transpose_proj_gated_kernel(const float* __restrict__ proj,
                                            const float* __restrict__ gates,
                                            unsigned short* __restrict__ outp)
{
    __shared__ float tile[32][33];
    int l = blockIdx.z;
    float g = 1.f / (1.f + expf(-gates[l]));
    const float* I = proj + (long)l * 512 * 512;
    int n0 = blockIdx.x * 32, d0 = blockIdx.y * 32;
    int tx = threadIdx.x, ty = threadIdx.y;
#pragma unroll
    for (int i = 0; i < 32; i += 8)
        tile[ty + i][tx] = I[(long)(d0 + ty + i) * 512 + n0 + tx];
    __syncthreads();
#pragma unroll
    for (int i = 0; i < 32; i += 8)
        outp[(long)(n0 + ty + i) * 1536 + l * 512 + d0 + tx] =
            (unsigned short)f2bf(g * tile[tx][ty + i]);
}

// Batched transpose of the 3 mv levels in one launch. y-tiles: 32|8|2.
__global__ void transpose_mv_kernel(const float* __restrict__ mv0, const float* __restrict__ mv1,
                                    const float* __restrict__ mv2,
                                    unsigned short* __restrict__ o0, unsigned short* __restrict__ o1,
                                    unsigned short* __restrict__ o2)
{
    __shared__ float tile[32][33];
    int yt = blockIdx.y;
    const float* in; unsigned short* out; int Nd, r0t;
    if (yt < 32)      { in = mv0; out = o0; Nd = 1024; r0t = yt; }
    else if (yt < 40) { in = mv1; out = o1; Nd = 256;  r0t = yt - 32; }
    else              { in = mv2; out = o2; Nd = 64;   r0t = yt - 40; }
    const float* I = in + (long)blockIdx.z * Nd * 512;
    unsigned short* O = out + (long)blockIdx.z * 512 * Nd;
    int c0 = blockIdx.x * 32, r0 = r0t * 32;
    int tx = threadIdx.x, ty = threadIdx.y;
#pragma unroll
    for (int i = 0; i < 32; i += 8)
        tile[ty + i][tx] = I[(long)(r0 + ty + i) * 512 + c0 + tx];
    __syncthreads();
#pragma unroll
    for (int i = 0; i < 32; i += 8)
        O[(long)(c0 + ty + i) * Nd + r0 + tx] = (unsigned short)f2bf(tile[tx][ty + i]);
}

// ---------------------------------------------------------------------------
// Exact top-16 per row + fused CSR count. v3: value-only butterfly + ballot
// lane-resolution (exact lowest-index tie-break: contiguous lane->index map,
// lowest ballot lane = lowest global index), softmax hoisted out of the loop.
// ---------------------------------------------------------------------------
template<int CNT>
__launch_bounds__(256)
__global__ void topk_coeff_kernel(const float* __restrict__ logits,
                                  const float* __restrict__ state,
                                  int* __restrict__ idx_out, float* __restrict__ c_out,
                                  int* __restrict__ cnt, int nsLog, int Nd)
{
    int wave = threadIdx.x >> 6, lane = threadIdx.x & 63;
    long row = (long)blockIdx.x * 4 + wave;
    const float* L = logits + row * Nd;
    float vreg[CNT];
    if (CNT >= 4) {
#pragma unroll
        for (int q = 0; q < CNT / 4; ++q) {
            float4 v = *(const float4*)&L[lane * CNT + q * 4];
            vreg[q * 4 + 0] = v.x; vreg[q * 4 + 1] = v.y;
            vreg[q * 4 + 2] = v.z; vreg[q * 4 + 3] = v.w;
        }
    } else {
#pragma unroll
        for (int tt = 0; tt < CNT; ++tt) vreg[tt] = L[lane * CNT + tt];
    }

    float myv = 0.f; int myi = 0;
#pragma unroll
    for (int it = 0; it < 16; ++it) {
        // in-lane argmax (ascending tt, strict '>' keeps lowest local index)
        float lbest = -INFINITY; int ltt = 0;
#pragma unroll
        for (int tt = 0; tt < CNT; ++tt)
            if (vreg[tt] > lbest) { lbest = vreg[tt]; ltt = tt; }
        // value-only max butterfly
        float best = lbest;
#pragma unroll
        for (int off = 32; off; off >>= 1)
            best = fmaxf(best, __shfl_down(best, off));
        best = __shfl(best, 0);
        // owning lane: lowest lane with lbest == best (== lowest global index)
        unsigned long long bm = __ballot(lbest == best);
        int src = __ffsll(bm) - 1;
        int bidx = __shfl(lane * CNT + ltt, src);
        if (it == lane) { myv = best; myi = bidx; }
        if (lane == src) vreg[ltt] = -INFINITY;
    }
    // softmax over |myv| across lanes 0..15 (xor stages stay within 16-group)
    float av = (lane < 16) ? fabsf(myv) : -INFINITY;
    float mx = av;
#pragma unroll
    for (int off = 8; off; off >>= 1) mx = fmaxf(mx, __shfl_xor(mx, off));
    float ex = (lane < 16) ? expf(av - mx) : 0.f;
    float sm = ex;
#pragma unroll
    for (int off = 8; off; off >>= 1) sm += __shfl_xor(sm, off);
    if (lane < 16) {
        float st = state[row];
        float sp = fmaxf(st, 0.f) + log1pf(expf(-fabsf(st)));
        float sgn = (myv > 0.f) ? 1.f : ((myv < 0.f) ? -1.f : 0.f);
        c_out[row * 16 + lane] = sgn * (ex / sm) * sp;
        idx_out[row * 16 + lane] = myi;
        int b = (int)(row >> nsLog);
        atomicAdd(&cnt[b * Nd + myi], 1);
    }
}

// Single-block exclusive scan; self-zeroes cnt (next Nd <= current Nd).
__launch_bounds__(256)
__global__ void scan_kernel(int* __restrict__ cnt, int* __restrict__ offs, int N)
{
    __shared__ int sums[256];
    int t = threadIdx.x;
    int chunk = N >> 8;
    int base = t * chunk;
    int lc[16];
    int s = 0;
    for (int i = 0; i < chunk; ++i) { lc[i] = cnt[base + i]; s += lc[i]; }
    sums[t] = s;
    __syncthreads();
    for (int off = 1; off < 256; off <<= 1) {
        int v = (t >= off) ? sums[t - off] : 0;
        __syncthreads();
        sums[t] += v;
        __syncthreads();
    }
    int run = sums[t] - s;
    for (int i = 0; i < chunk; ++i) {
        offs[base + i] = run;
        run += lc[i];
        cnt[base + i] = 0;
    }
    if (t == 255) offs[N] = run;
}

__launch_bounds__(256)
__global__ void fill_edges_kernel(const int* __restrict__ idx, const int* __restrict__ offs,
                                  int* __restrict__ cursor, int* __restrict__ elist,
                                  int nsShift, int Nd, int E)
{
    int e = blockIdx.x * 256 + threadIdx.x;
    if (e >= E) return;
    int b = e >> nsShift;
    int d = b * Nd + idx[e];
    int pos = offs[d] + atomicAdd(&cursor[d], 1);
    elist[pos] = e;
}

// ---------------------------------------------------------------------------
// FUSED gather + LayerNorm (proven): ds by-product, cursor self-clean.
// ---------------------------------------------------------------------------
#define ECHUNK 512
__launch_bounds__(256)
__global__ void gather_ln_kernel(const float* __restrict__ src_val, const float* __restrict__ c,
                                 const int* __restrict__ elist, const int* __restrict__ offs,
                                 const float* __restrict__ v_in, float* __restrict__ v_out,
                                 float* __restrict__ ds, int* __restrict__ cursor,
                                 const float* __restrict__ gamma, const float* __restrict__ beta,
                                 const float* __restrict__ gatePtr, int gateIdx, int nsShift)
{
    __shared__ float sc[ECHUNK];
    __shared__ int   srow[ECHUNK];
    __shared__ float part[4][512];
    __shared__ float pcs[4];
    __shared__ float red[4];
    long row = blockIdx.x;
    int t = threadIdx.x, w = t >> 6, lane = t & 63;
    int e0 = offs[row], e1 = offs[row + 1];
    int mask = (1 << nsShift) - 1;
    int cb = lane * 8;
    float a[8] = {};
    float cs = 0.f;
    float gate = 1.f;
    if (gatePtr) gate = 1.f / (1.f + expf(-gatePtr[gateIdx]));

    for (int cstart = e0; cstart < e1; cstart += ECHUNK) {
        int cnt = min(e1 - cstart, ECHUNK);
        for (int i = t; i < cnt; i += 256) {
            int e = elist[cstart + i];
            sc[i] = c[e];
            int b = e >> nsShift;
            int s = (e & mask) >> 4;
            srow[i] = (b << (nsShift - 4)) + s;
        }
        __syncthreads();
        int j = w;
        for (; j + 12 < cnt; j += 16) {
            float c0 = sc[j], c1 = sc[j + 4], c2 = sc[j + 8], c3 = sc[j + 12];
            const float* p0 = src_val + ((long)srow[j]      << 9) + cb;
            const float* p1 = src_val + ((long)srow[j + 4]  << 9) + cb;
            const float* p2 = src_val + ((long)srow[j + 8]  << 9) + cb;
            const float* p3 = src_val + ((long)srow[j + 12] << 9) + cb;
            float4 x00 = *(const float4*)p0,       x01 = *(const float4*)(p0 + 4);
            float4 x10 = *(const float4*)p1,       x11 = *(const float4*)(p1 + 4);
            float4 x20 = *(const float4*)p2,       x21 = *(const float4*)(p2 + 4);
            float4 x30 = *(const float4*)p3,       x31 = *(const float4*)(p3 + 4);
            a[0] += c0 * x00.x + c1 * x10.x + c2 * x20.x + c3 * x30.x;
            a[1] += c0 * x00.y + c1 * x10.y + c2 * x20.y + c3 * x30.y;
            a[2] += c0 * x00.z + c1 * x10.z + c2 * x20.z + c3 * x30.z;
            a[3] += c0 * x00.w + c1 * x10.w + c2 * x20.w + c3 * x30.w;
            a[4] += c0 * x01.x + c1 * x11.x + c2 * x21.x + c3 * x31.x;
            a[5] += c0 * x01.y + c1 * x11.y + c2 * x21.y + c3 * x31.y;
            a[6] += c0 * x01.z + c1 * x11.z + c2 * x21.z + c3 * x31.z;
            a[7] += c0 * x01.w + c1 * x11.w + c2 * x21.w + c3 * x31.w;
            cs += c0 + c1 + c2 + c3;
        }
        for (; j < cnt; j += 4) {
            float cv = sc[j];
            const float* p = src_val + ((long)srow[j] << 9) + cb;
            float4 x0 = *(const float4*)p, x1 = *(const float4*)(p + 4);
            a[0] += cv * x0.x; a[1] += cv * x0.y; a[2] += cv * x0.z; a[3] += cv * x0.w;
            a[4] += cv * x1.x; a[5] += cv * x1.y; a[6] += cv * x1.z; a[7] += cv * x1.w;
            cs += cv;
        }
        __syncthreads();
    }
#pragma unroll
    for (int i = 0; i < 8; ++i) part[w][cb + i] = a[i];
    if (lane == 0) pcs[w] = cs;
    __syncthreads();
    float r0 = part[0][t] + part[1][t] + part[2][t] + part[3][t];
    float r1 = part[0][t + 256] + part[1][t + 256] + part[2][t + 256] + part[3][t + 256];
    if (t == 0) { ds[row] = pcs[0] + pcs[1] + pcs[2] + pcs[3]; cursor[row] = 0; }

    const float* vi = v_in + (row << 9);
    float x0 = vi[t]       + gate * r0;
    float x1 = vi[t + 256] + gate * r1;
    float s = x0 + x1;
    for (int off = 32; off; off >>= 1) s += __shfl_down(s, off);
    if ((t & 63) == 0) red[t >> 6] = s;
    __syncthreads();
    float mean = (red[0] + red[1] + red[2] + red[3]) * (1.f / 512.f);
    float d0 = x0 - mean, d1 = x1 - mean;
    float ss = d0 * d0 + d1 * d1;
    for (int off = 32; off; off >>= 1) ss += __shfl_down(ss, off);
    __syncthreads();
    if ((t & 63) == 0) red[t >> 6] = ss;
    __syncthreads();
    float var = (red[0] + red[1] + red[2] + red[3]) * (1.f / 512.f);
    float rstd = rsqrtf(var + 1e-5f);
    float* vo = v_out + (row << 9);
    vo[t]       = d0 * rstd * gamma[t]       + beta[t];
    vo[t + 256] = d1 * rstd * gamma[t + 256] + beta[t + 256];
}

// ---------------------------------------------------------------------------
// state' = sign(x)*softmax(|x|), x = s + gate*ds. One block per batch.
// ---------------------------------------------------------------------------
__launch_bounds__(256)
__global__ void apply_state_kernel(const float* __restrict__ s_in, const float* __restrict__ ds,
                                   float* __restrict__ s_out, int Nd,
                                   const float* __restrict__ gatePtr, int gateIdx)
{
    __shared__ float sh[1024];
    __shared__ float red[4];
    int b = blockIdx.x, t = threadIdx.x;
    float gate = 1.f;
    if (gatePtr) gate = 1.f / (1.f + expf(-gatePtr[gateIdx]));
    float lmax = 0.f;
    for (int i = t; i < Nd; i += 256) {
        float x = s_in[b * Nd + i] + gate * ds[b * Nd + i];
        sh[i] = x;
        lmax = fmaxf(lmax, fabsf(x));
    }
    for (int off = 32; off; off >>= 1) lmax = fmaxf(lmax, __shfl_down(lmax, off));
    if ((t & 63) == 0) red[t >> 6] = lmax;
    __syncthreads();
    float bmax = fmaxf(fmaxf(red[0], red[1]), fmaxf(red[2], red[3]));
    float lsum = 0.f;
    for (int i = t; i < Nd; i += 256) lsum += expf(fabsf(sh[i]) - bmax);
    for (int off = 32; off; off >>= 1) lsum += __shfl_down(lsum, off);
    __syncthreads();
    if ((t & 63) == 0) red[t >> 6] = lsum;
    __syncthreads();
    float inv = 1.f / (red[0] + red[1] + red[2] + red[3]);
    for (int i = t; i < Nd; i += 256) {
        float x = sh[i];
        float sgn = (x > 0.f) ? 1.f : ((x < 0.f) ? -1.f : 0.f);
        s_out[b * Nd + i] = sgn * expf(fabsf(x) - bmax) * inv;
    }
}

// ---------------------------------------------------------------------------
// Segmented softmax over rows (read phase): grid (Bn*T, 3).
// ---------------------------------------------------------------------------
__launch_bounds__(256)
__global__ void softmax_seg_kernel(float* __restrict__ lb0, float* __restrict__ lb1,
                                   float* __restrict__ lb2)
{
    __shared__ float red[4];
    int lvl = blockIdx.y;
    int Nd = (lvl == 0) ? 1024 : (lvl == 1) ? 256 : 64;
    float* base = (lvl == 0) ? lb0 : (lvl == 1) ? lb1 : lb2;
    long row = blockIdx.x;
    int t = threadIdx.x;
    float* L = base + row * (long)Nd;
    float lmax = -INFINITY;
    for (int i = t; i < Nd; i += 256) lmax = fmaxf(lmax, L[i]);
    for (int off = 32; off; off >>= 1) lmax = fmaxf(lmax, __shfl_down(lmax, off));
    if ((t & 63) == 0) red[t >> 6] = lmax;
    __syncthreads();
    float bmax = fmaxf(fmaxf(red[0], red[1]), fmaxf(red[2], red[3]));
    float lsum = 0.f;
    for (int i = t; i < Nd; i += 256) lsum += expf(L[i] - bmax);
    for (int off = 32; off; off >>= 1) lsum += __shfl_down(lsum, off);
    __syncthreads();
    if ((t & 63) == 0) red[t >> 6] = lsum;
    __syncthreads();
    float inv = 1.f / (red[0] + red[1] + red[2] + red[3]);
    for (int i = t; i < Nd; i += 256) L[i] = expf(L[i] - bmax) * inv;
}

// ---------------------------------------------------------------------------
extern "C" void kernel_launch(void* const* d_in, const int* in_sizes, int n_in,
                              void* d_out, int out_size, void* d_ws, size_t ws_size,
                              hipStream_t stream)
{
    const int Bn = 4, T = 1024, D = 512, R = 64;
    const int S0 = 1024, S1 = 256, S2 = 64;
    const long RT = (long)D * R;
    const int MR = 3 * T + S0 + S1 + S2;   // 4416

    const float* tok_val    = (const float*)d_in[0];
    const float* tok_state  = (const float*)d_in[1];
    const float* mem_state0 = (const float*)d_in[2];
    const float* mem_val0   = (const float*)d_in[3];
    const float* mem_state1 = (const float*)d_in[4];
    const float* mem_val1   = (const float*)d_in[5];
    const float* mem_state2 = (const float*)d_in[6];
    const float* mem_val2   = (const float*)d_in[7];
    const float* write_route= (const float*)d_in[8];
    const float* prop_route = (const float*)d_in[9];
    const float* level_route= (const float*)d_in[10];
    const float* skip_route = (const float*)d_in[11];
    const float* skip_gates = (const float*)d_in[12];
    const float* ln_gamma   = (const float*)d_in[13];
    const float* ln_beta    = (const float*)d_in[14];
    const float* read_route = (const float*)d_in[15];
    const float* read_proj  = (const float*)d_in[16];
    const float* read_gates = (const float*)d_in[17];
    float* out = (float*)d_out;

    // workspace carve
    float* p = (float*)d_ws;
    float* v0  = p; p += (long)Bn * S0 * D;
    float* v0b = p; p += (long)Bn * S0 * D;
    float* s0  = p; p += Bn * S0;
    float* v1  = p; p += (long)Bn * S1 * D;
    float* v1b = p; p += (long)Bn * S1 * D;
    float* s1  = p; p += Bn * S1;
    float* v2  = p; p += (long)Bn * S2 * D;
    float* v2b = p; p += (long)Bn * S2 * D;
    float* s2  = p; p += Bn * S2;
    float* qb  = p; p += (long)Bn * T * R;
    float* kb  = p; p += (long)Bn * S0 * R;
    float* rqk = p; p += (long)Bn * MR * R;
    float* lb0 = p; p += (long)Bn * T * S0;      // also transition lb
    float* lb1 = p; p += (long)Bn * T * S1;
    float* lb2 = p; p += (long)Bn * T * S2;
    float* cbuf= p; p += (long)Bn * T * 16;
    int*   ib  = (int*)p; p += (long)Bn * T * 16;
    float* dsb = p; p += Bn * S0;
    unsigned short* rcat = (unsigned short*)p; p += ((long)Bn * T * 1536) / 2 + 4;
    int* cntb  = (int*)p; p += Bn * S0;
    int* curb  = (int*)p; p += Bn * S0;
    int* offsb = (int*)p; p += Bn * S0 + 1;
    int* elistb= (int*)p; p += (long)Bn * T * 16;
    unsigned short* pcatT = (unsigned short*)p; p += (512L * 1536) / 2 + 4;
    unsigned short* mvT0  = (unsigned short*)p; p += ((long)Bn * D * S0) / 2 + 4;
    unsigned short* mvT1  = (unsigned short*)p; p += ((long)Bn * D * S1) / 2 + 4;
    unsigned short* mvT2  = (unsigned short*)p; p += ((long)Bn * D * S2) / 2 + 4;
    float* partb = p; p += 8L * Bn * MR * R;

    auto proj = [&](const float* Aq, const float* Ak, const float* Wq, const float* Wk,
                    int Mq, int Mk, long sAq, long sAk, float* qout, float* kout) {
        proj_splitk_kernel<<<dim3((Mq + Mk) / 64, 8, Bn), 256, 0, stream>>>(
            Aq, Ak, Wq, Wk, partb, Mq, Mk, sAq, sAk, Bn);
        int total4 = Bn * (Mq + Mk) * 16;
        proj_reduce_kernel<<<(total4 + 255) / 256, 256, 0, stream>>>(
            partb, qout, kout, Mq, Mk, Bn);
    };

    hipMemsetAsync(cntb, 0, (size_t)2 * Bn * S0 * sizeof(int), stream);

    auto trans = [&](const float* sv, const float* ss, const float* dval,
                     const float* W, int Ns, int Nd,
                     const float* v_in, float* v_out, const float* sin, float* sout,
                     int lvl, const float* gptr, int gidx) {
        proj(sv, dval, W, W + RT, Ns, Nd, (long)Ns * D, (long)Nd * D, qb, kb);
        gemm_f32_nt_kernel<<<dim3(Ns / 64, Nd / 64, Bn), 256, 0, stream>>>(
            qb, kb, lb0, Ns, Nd, R, (long)Ns * R, (long)Nd * R, (long)Ns * Nd, 0.125f);
        int nsLog = 31 - __builtin_clz((unsigned)Ns);
        int nsShift = nsLog + 4;
        int rowBlocks = Bn * Ns / 4;
        if (Nd == 1024)
            topk_coeff_kernel<16><<<rowBlocks, 256, 0, stream>>>(lb0, ss, ib, cbuf, cntb, nsLog, Nd);
        else if (Nd == 256)
            topk_coeff_kernel<4><<<rowBlocks, 256, 0, stream>>>(lb0, ss, ib, cbuf, cntb, nsLog, Nd);
        else
            topk_coeff_kernel<1><<<rowBlocks, 256, 0, stream>>>(lb0, ss, ib, cbuf, cntb, nsLog, Nd);
        int E = Bn * Ns * 16;
        scan_kernel<<<1, 256, 0, stream>>>(cntb, offsb, Bn * Nd);
        fill_edges_kernel<<<(E + 255) / 256, 256, 0, stream>>>(ib, offsb, curb, elistb,
                                                               nsShift, Nd, E);
        gather_ln_kernel<<<Bn * Nd, 256, 0, stream>>>(sv, cbuf, elistb, offsb,
                                                      v_in, v_out, dsb, curb,
                                                      ln_gamma + lvl * D, ln_beta + lvl * D,
                                                      gptr, gidx, nsShift);
        apply_state_kernel<<<Bn, 256, 0, stream>>>(sin, dsb, sout, Nd, gptr, gidx);
    };

    // ---- level 0 ----
    trans(tok_val, tok_state, mem_val0, write_route, T, S0,
          mem_val0, v0, mem_state0, s0, 0, nullptr, 0);
    trans(v0, s0, v0, prop_route + 0 * 2 * RT, S0, S0,
          v0, v0b, s0, s0, 0, nullptr, 0);

    // ---- level 1 ----
    trans(v0b, s0, mem_val1, level_route + 0 * 2 * RT, S0, S1,
          mem_val1, v1, mem_state1, s1, 1, nullptr, 0);
    trans(tok_val, tok_state, v1, skip_route + 0 * 2 * RT, T, S1,
          v1, v1, s1, s1, 1, skip_gates, 0);
    trans(v1, s1, v1, prop_route + 1 * 2 * RT, S1, S1,
          v1, v1b, s1, s1, 1, nullptr, 0);

    // ---- level 2 ----
    trans(v1b, s1, mem_val2, level_route + 1 * 2 * RT, S1, S2,
          mem_val2, v2, mem_state2, s2, 2, nullptr, 0);
    trans(v0b, s0, v2, skip_route + 1 * 2 * RT, S0, S2,
          v2, v2, s2, s2, 2, skip_gates, 1);
    trans(v2, s2, v2, prop_route + 2 * 2 * RT, S2, S2,
          v2, v2b, s2, s2, 2, nullptr, 0);

    // ---- read phase (8 launches) ----
    transpose_proj_gated_kernel<<<dim3(D / 32, D / 32, 3), dim3(32, 8), 0, stream>>>(
        read_proj, read_gates, pcatT);
    transpose_mv_kernel<<<dim3(D / 32, (S0 + S1 + S2) / 32, Bn), dim3(32, 8), 0, stream>>>(
        v0b, v1b, v2b, mvT0, mvT1, mvT2);

    {
        ProjDesc d = {};
        const float* mvs[3] = { v0b, v1b, v2b };
        const int nds[3] = { S0, S1, S2 };
        int tiles = 0, roff = 0;
        for (int l = 0; l < 3; ++l) {
            d.A[l] = tok_val; d.W[l] = read_route + (long)l * 2 * RT;
            d.sA[l] = (long)T * D; d.rowOff[l] = roff;
            d.tileOff[l] = tiles; tiles += T / 64; roff += T;
        }
        for (int l = 0; l < 3; ++l) {
            d.A[3 + l] = mvs[l]; d.W[3 + l] = read_route + (long)l * 2 * RT + RT;
            d.sA[3 + l] = (long)nds[l] * D; d.rowOff[3 + l] = roff;
            d.tileOff[3 + l] = tiles; tiles += nds[l] / 64; roff += nds[l];
        }
        d.tileOff[6] = tiles;
        d.Mtot = MR;
        proj_splitk_multi_kernel<<<dim3(tiles, 8, Bn), 256, 0, stream>>>(d, partb, Bn);
        int total4 = Bn * MR * 16;
        proj_reduce_flat_kernel<<<(total4 + 255) / 256, 256, 0, stream>>>(partb, rqk, total4);
    }

    {   // segmented logits GEMM: q_l x k_l^T -> lb_l (one launch)
        LogitsSeg d = {};
        float* lbs[3] = { lb0, lb1, lb2 };
        const int nds[3] = { S0, S1, S2 };
        int koff = 3 * T, yo = 0;
        for (int l = 0; l < 3; ++l) {
            d.A[l] = rqk + (long)l * T * R;
            d.B[l] = rqk + (long)koff * R;
            d.C[l] = lbs[l];
            d.sC[l] = (long)T * nds[l];
            d.Nd[l] = nds[l];
            d.yOff[l] = yo;
            yo += nds[l] / 64;
            koff += nds[l];
        }
        d.yOff[3] = yo;
        d.sAB = (long)MR * R;
        gemm_logits_seg_kernel<<<dim3(T / 64, yo, Bn), 256, 0, stream>>>(d);
    }

    softmax_seg_kernel<<<dim3(Bn * T, 3), 256, 0, stream>>>(lb0, lb1, lb2);

    {   // segmented attn x mv -> r_cat (bf16, one launch)
        AttnSeg d = {};
        float* lbs[3] = { lb0, lb1, lb2 };
        const unsigned short* mvTs[3] = { mvT0, mvT1, mvT2 };
        const int nds[3] = { S0, S1, S2 };
        for (int l = 0; l < 3; ++l) {
            d.A[l] = lbs[l];
            d.Bt[l] = mvTs[l];
            d.K[l] = nds[l];
            d.sA[l] = (long)T * nds[l];
            d.sBt[l] = (long)D * nds[l];
        }
        gemm_mfma_attn_seg_kernel<<<dim3(48, D / 64, Bn), 256, 0, stream>>>(
            d, rcat, (long)T * 1536);
    }

    // out = tok_val + r_cat(T,1536,bf16) x Pcat^T(512,1536,bf16) — BK=64, 24 iters
    gemm_mfma_bb_kernel<<<dim3(T / 64, D / 64, Bn), 256, 0, stream>>>(
        rcat, pcatT, out, T, D, 1536,
        (long)T * 1536, 0, (long)T * D, tok_val);
}